// Round 11
// baseline (509.113 us; speedup 1.0000x reference)
//
#include <hip/hip_runtime.h>
#include <math.h>

// B=128, W=64, L=4096, MODES=32, N_LAYERS=4

typedef _Float16 half8 __attribute__((ext_vector_type(8)));  // 8 fp16 (4 VGPR)
typedef __attribute__((ext_vector_type(4))) float fx4;       // MFMA f32 acc

// fast gelu: tanh/sigmoid form, exp2-folded. Max dev from exact-erf ~5e-4.
__device__ __forceinline__ float gelu_f(float x){
    float u = x*x;
    float a = x * fmaf(-0.1029443f, u, -2.3022083f);   // -2y*log2(e)
    float e = exp2f(a);                                 // e^{-2y}
    float r = __builtin_amdgcn_rcpf(1.0f + e);          // sigmoid(2y)
    return x * r;
}
__device__ __forceinline__ unsigned short f2h(float f){
    union { _Float16 h; unsigned short u; } c;
    c.h = (_Float16)f;
    return c.u;
}
__device__ __forceinline__ float h2f(unsigned short u){
    union { unsigned short u; _Float16 h; } c;
    c.u = u;
    return (float)c.h;
}

// ---------------- workspace layout (float-slot offsets) ----------------
// xh    : fp16 [128][64][4096]  h (channel-major)
// xT    : fp16 [128][4096][64]  normalized x, position-major
// tabB  : fp16 [64][4096]       rows 0-31 cos, 32-63 sin (fwd DFT)
// tabT  : fp16 [4096][64]       transpose, scaled 1/64 (iDFT)
// mah   : fp16 [b][co][64]      iDFT coeffs x64
// pwwh  : fp16 [4][64][64]
// w1h   : fp16 [128][64]
// cond  : f32  [b][64]
// statsr: f32  [b][co][2]       RAW (S, Q) accumulated by pass3 atomics
// dftp  : f32  [b][8][64 ci][64 m2]
// x0    : f32  [b][64 wc][64 pos]  lift output (pre-interp)
static const size_t OFF_XH    = 0;
static const size_t OFF_XT    = 16777216;
static const size_t OFF_TABB  = 33554432;
static const size_t OFF_TABT  = 33685504;
static const size_t OFF_MAH   = 33816576;   // 262,144 slots
static const size_t OFF_PWWH  = 34078720;   // 8,192
static const size_t OFF_W1H   = 34086912;   // 4,096
static const size_t OFF_COND  = 34091008;   // 8,192
static const size_t OFF_STATS = 34099200;   // 16,384
static const size_t OFF_DFTP  = 34115584;   // 4,194,304
static const size_t OFF_X0    = 38309888;   // 524,288
// end = 38,834,176 slots = 155.3 MB (< proven 157.4 MB footprint)

// ---------------- trig tables + weight fp16 conversion ----------------
__global__ void k_tab(unsigned short* __restrict__ tabB, unsigned short* __restrict__ tabT,
                      const float* __restrict__ pww, unsigned short* __restrict__ pwwh,
                      const float* __restrict__ pj1w, unsigned short* __restrict__ w1h){
    int t = blockIdx.x*256 + threadIdx.x;        // 262144
    if (t < 16384) pwwh[t] = f2h(pww[t]);
    if (t < 8192)  w1h[t]  = f2h(pj1w[t]);
    int m2 = t >> 12, n = t & 4095;
    int m = m2 & 31;
    int r = (m*n) & 4095;
    int r2 = (r >= 2048) ? (r - 4096) : r;       // fold to [-pi, pi)
    float a = (float)r2 * 1.5339807878856412e-3f;   // 2*pi/4096
    float v = (m2 >= 32) ? sinf(a) : cosf(a);
    tabB[(size_t)m2*4096 + n] = f2h(v);
    tabT[(size_t)n*64 + m2]   = f2h(v * 0.015625f);
}

// ---------------- conditioning MLP ----------------
__global__ __launch_bounds__(64) void k_cond(const float* __restrict__ instp,
        const float* __restrict__ w1, const float* __restrict__ b1,
        const float* __restrict__ w2, const float* __restrict__ b2,
        float* __restrict__ cond){
    int b = blockIdx.x, tid = threadIdx.x;
    __shared__ float ipl[8];
    __shared__ float tl[64];
    if (tid < 8) ipl[tid] = instp[b*8 + tid];
    __syncthreads();
    float s = b1[tid];
    #pragma unroll
    for (int k = 0; k < 8; ++k) s = fmaf(ipl[k], w1[k*64 + tid], s);
    tl[tid] = gelu_f(s);
    __syncthreads();
    float c = b2[tid];
    #pragma unroll 8
    for (int j = 0; j < 64; ++j) c = fmaf(tl[j], w2[j*64 + tid], c);
    cond[b*64 + tid] = c;
}

// ---------------- lift core: x0 = z @ lift_w + lb + cond (f32, 2 MB) ----------------
// grid (128 b, 4 q), 256 thr.
__global__ __launch_bounds__(256) void k_liftc(const float* __restrict__ z,
        const float* __restrict__ lw, const float* __restrict__ lb,
        const float* __restrict__ cond, float* __restrict__ x0){
    int b = blockIdx.x, q = blockIdx.y;
    int t = threadIdx.x;
    __shared__ float zl[128];
    if (t < 128) zl[t] = z[b*128 + t];
    __syncthreads();
    #pragma unroll
    for (int i = 0; i < 4; ++i){
        int e = q*1024 + i*256 + t;            // e = wc*64 + pos
        float s = lb[e];
        #pragma unroll 8
        for (int d = 0; d < 128; ++d)
            s = fmaf(zl[d], lw[(size_t)d*4096 + e], s);
        x0[(size_t)b*4096 + e] = s + cond[b*64 + (e >> 6)];
    }
}

// ---------------- prep: (interp | norm+gelu) -> x, transpose-store xT, fwd-DFT ----------
// MODE: 1 = norm+gelu from xh; 2 = inline linear-interp from x0 (layer 0).
template<int MODE, int DODFT>
__global__ __launch_bounds__(256) void k_prep(
        const unsigned short* __restrict__ xhp, const float* __restrict__ statsr,
        const unsigned short* __restrict__ tabB, const float* __restrict__ x0,
        unsigned short* __restrict__ xT, float* __restrict__ dftp)
{
    int b = blockIdx.x, ng = blockIdx.y;
    int t = threadIdx.x;
    int w = t >> 6, lane = t & 63;
    int lrow = lane & 15, g = lane >> 4;
    __shared__ __align__(16) unsigned short xl[2][4096];
    __shared__ float xs[(MODE == 2) ? 65*64 : 1];   // [co][64+1 pad]
    int co = t >> 2, nq = t & 3;
    float mu = 0.f, rs = 1.f;
    if (MODE == 1){
        float2 sr = *(const float2*)(statsr + (size_t)(b*64+co)*2);
        mu = sr.x * (1.f/4096.f);
        float var = fmaf(sr.y, 1.f/4096.f, -mu*mu);
        rs = rsqrtf(var + 1e-5f);
    }
    if (MODE == 2){
        const float* xb0 = x0 + (size_t)b*4096;
        #pragma unroll
        for (int i = 0; i < 16; ++i){
            int idx = i*256 + t;
            xs[(idx >> 6)*65 + (idx & 63)] = xb0[idx];
        }
        __syncthreads();
    }
    fx4 acc[4];
    #pragma unroll
    for (int i = 0; i < 4; ++i) acc[i] = (fx4){0.f,0.f,0.f,0.f};

    const unsigned short* hrow = xhp + ((size_t)(b*64+co))*4096 + ng*512 + nq*16;
    unsigned short* xtbase = xT + ((size_t)b*4096 + (size_t)ng*512)*64;

    uint4 cA, cB;
    if (MODE == 1){ cA = *(const uint4*)(hrow); cB = *(const uint4*)(hrow + 8); }
    for (int it = 0; it < 8; ++it){
        int n0 = ng*512 + it*64;
        char* xb = (char*)(&xl[it & 1][0]);
        uint4 nA, nB;
        if (MODE == 1 && it < 7){                 // prefetch next iter's tile
            nA = *(const uint4*)(hrow + (it+1)*64);
            nB = *(const uint4*)(hrow + (it+1)*64 + 8);
        }
        unsigned int pk[8];
        if (MODE == 1){
            unsigned int hu[8] = {cA.x,cA.y,cA.z,cA.w,cB.x,cB.y,cB.z,cB.w};
            #pragma unroll
            for (int i = 0; i < 8; ++i){
                float f0 = h2f((unsigned short)(hu[i] & 0xFFFFu));
                float f1 = h2f((unsigned short)(hu[i] >> 16));
                f0 = gelu_f((f0 - mu)*rs);
                f1 = gelu_f((f1 - mu)*rs);
                pk[i] = (unsigned int)f2h(f0) | ((unsigned int)f2h(f1) << 16);
            }
        } else {                                  // MODE == 2: inline interp from x0
            const float* xr = xs + co*65;
            #pragma unroll
            for (int i = 0; i < 8; ++i){
                float v[2];
                #pragma unroll
                for (int q = 0; q < 2; ++q){
                    int n = n0 + nq*16 + i*2 + q;
                    float src = (n + 0.5f)*0.015625f - 0.5f;
                    src = fminf(fmaxf(src, 0.0f), 63.0f);
                    int i0 = (int)src;
                    int i1 = (i0 + 1 > 63) ? 63 : (i0 + 1);
                    float wt = src - (float)i0;
                    v[q] = xr[i0] + wt*(xr[i1] - xr[i0]);
                }
                pk[i] = (unsigned int)f2h(v[0]) | ((unsigned int)f2h(v[1]) << 16);
            }
        }
        unsigned int base = (unsigned int)co*128 + (unsigned int)nq*32;
        unsigned int sw = (unsigned int)((co & 7) << 4);
        *(uint4*)(xb + ((base +  0) ^ sw)) = make_uint4(pk[0],pk[1],pk[2],pk[3]);
        *(uint4*)(xb + ((base + 16) ^ sw)) = make_uint4(pk[4],pk[5],pk[6],pk[7]);
        __syncthreads();

        if (DODFT){
            int m0 = w*16;
            #pragma unroll
            for (int ks = 0; ks < 2; ++ks){
                int kk = ks*32 + g*8;
                half8 af = *(const half8*)(tabB + (size_t)(m0 + lrow)*4096 + n0 + kk);
                #pragma unroll
                for (int ct = 0; ct < 4; ++ct){
                    int row = ct*16 + lrow;
                    unsigned int ba = ((unsigned int)row*128 + (unsigned int)kk*2)
                                      ^ (unsigned int)((row & 7) << 4);
                    half8 bf = *(const half8*)(xb + ba);
                    acc[ct] = __builtin_amdgcn_mfma_f32_16x16x32_f16(af, bf, acc[ct], 0, 0, 0);
                }
            }
        }
        {   // transpose out: xT[b][n][co]
            int n = t & 63, coq = t >> 6;
            unsigned int opk[8];
            #pragma unroll
            for (int i = 0; i < 8; ++i){
                int r0 = coq*16 + 2*i, r1 = r0 + 1;
                unsigned int a0 = ((unsigned int)r0*128 + (unsigned int)n*2)
                                  ^ (unsigned int)((r0 & 7) << 4);
                unsigned int a1 = ((unsigned int)r1*128 + (unsigned int)n*2)
                                  ^ (unsigned int)((r1 & 7) << 4);
                unsigned short v0 = *(const unsigned short*)(xb + a0);
                unsigned short v1 = *(const unsigned short*)(xb + a1);
                opk[i] = (unsigned int)v0 | ((unsigned int)v1 << 16);
            }
            unsigned short* dst = xtbase + (size_t)(it*64 + n)*64 + coq*16;
            *(uint4*)dst       = make_uint4(opk[0],opk[1],opk[2],opk[3]);
            *(uint4*)(dst + 8) = make_uint4(opk[4],opk[5],opk[6],opk[7]);
        }
        if (MODE == 1 && it < 7){ cA = nA; cB = nB; }
        // no second barrier: next iter writes the other LDS buffer
    }
    if (DODFT){
        // dftp layout [b][ng][ci][m2]: j contiguous -> float4 stores
        int m0 = w*16;
        #pragma unroll
        for (int ct = 0; ct < 4; ++ct){
            float4 v = make_float4(acc[ct][0], acc[ct][1], acc[ct][2], acc[ct][3]);
            *(float4*)(dftp + ((size_t)(b*8+ng)*64 + ct*16 + lrow)*64 + m0 + g*4) = v;
        }
    }
}

// ---------------- spectral mix (fused dftred + stats zero), co-split ----------------
// grid (128 b, 4 coq), 256 thr. Thread = (mq=t&3, ciq=(t>>2)&3, co_l=t>>4).
__global__ __launch_bounds__(256) void k_mix(const float* __restrict__ dftp,
        const float* __restrict__ specw, unsigned short* __restrict__ mah,
        float* __restrict__ statsr, int l){
    int b = blockIdx.x, coq = blockIdx.y, t = threadIdx.x;
    __shared__ float xm[64*64];              // [ci][64]: r | i
    if (t < 128) statsr[b*128 + t] = 0.f;    // all coq blocks write 0 (benign)
    const float* dp = dftp + (size_t)b*8*4096;
    #pragma unroll
    for (int i = 0; i < 4; ++i){
        int e = i*1024 + t*4;                // e = ci*64 + m2, float4-aligned
        float4 s = make_float4(0.f,0.f,0.f,0.f);
        #pragma unroll
        for (int ng = 0; ng < 8; ++ng){
            float4 v = *(const float4*)(dp + (size_t)ng*4096 + e);
            s.x += v.x; s.y += v.y; s.z += v.z; s.w += v.w;
        }
        if (e & 32){ s.x = -s.x; s.y = -s.y; s.z = -s.z; s.w = -s.w; }  // sin half -> Xi
        *(float4*)(xm + e) = s;
    }
    __syncthreads();
    int mq = t & 3, ciq = (t >> 2) & 3, co_l = t >> 4;
    int co = coq*16 + co_l;
    float yr[8] = {0,0,0,0,0,0,0,0}, yi[8] = {0,0,0,0,0,0,0,0};
    const float* wbase = specw + (size_t)l*262144 + (size_t)co*64 + mq*16;
    #pragma unroll 4
    for (int cil = 0; cil < 16; ++cil){
        int ci = ciq*16 + cil;
        const float* wp = wbase + (size_t)ci*4096;
        float4 w0 = *(const float4*)(wp);
        float4 w1v = *(const float4*)(wp + 4);
        float4 w2v = *(const float4*)(wp + 8);
        float4 w3v = *(const float4*)(wp + 12);
        const float* xc = xm + ci*64 + mq*8;
        float4 r0 = *(const float4*)(xc);
        float4 r1 = *(const float4*)(xc + 4);
        float4 i0 = *(const float4*)(xc + 32);
        float4 i1 = *(const float4*)(xc + 36);
        float wr[8] = {w0.x,w0.z,w1v.x,w1v.z,w2v.x,w2v.z,w3v.x,w3v.z};
        float wi[8] = {w0.y,w0.w,w1v.y,w1v.w,w2v.y,w2v.w,w3v.y,w3v.w};
        float xr[8] = {r0.x,r0.y,r0.z,r0.w,r1.x,r1.y,r1.z,r1.w};
        float xi[8] = {i0.x,i0.y,i0.z,i0.w,i1.x,i1.y,i1.z,i1.w};
        #pragma unroll
        for (int mm = 0; mm < 8; ++mm){
            yr[mm] = fmaf(xr[mm], wr[mm], fmaf(-xi[mm], wi[mm], yr[mm]));
            yi[mm] = fmaf(xr[mm], wi[mm], fmaf( xi[mm], wr[mm], yi[mm]));
        }
    }
    #pragma unroll
    for (int mm = 0; mm < 8; ++mm){
        yr[mm] += __shfl_xor(yr[mm], 4); yr[mm] += __shfl_xor(yr[mm], 8);
        yi[mm] += __shfl_xor(yi[mm], 4); yi[mm] += __shfl_xor(yi[mm], 8);
    }
    if (ciq == 0){
        unsigned short* mb = mah + (size_t)(b*64 + co)*64;
        unsigned int pr[4], pi[4];
        #pragma unroll
        for (int p = 0; p < 4; ++p){
            int m0 = mq*8 + 2*p;
            float s0 = (m0 == 0) ? 0.015625f : 0.03125f;   // (1|2)/4096 * 64
            pr[p] = (unsigned int)f2h(s0*yr[2*p]) | ((unsigned int)f2h(0.03125f*yr[2*p+1]) << 16);
            pi[p] = (unsigned int)f2h(-0.03125f*yi[2*p]) | ((unsigned int)f2h(-0.03125f*yi[2*p+1]) << 16);
        }
        *(uint4*)(mb + mq*8)      = make_uint4(pr[0],pr[1],pr[2],pr[3]);
        *(uint4*)(mb + 32 + mq*8) = make_uint4(pi[0],pi[1],pi[2],pi[3]);
    }
}

// ---------------- fused pointwise + iDFT (MFMA, swapped operands, low-reg) --------
// grid (128 b, 8 ntg of 512 n), 256 thr (4 waves). Wave (wc = co-half, wn = n-half):
// 32 co x 256 n as 4 sequential 64-n slabs. Bv held across slabs; A streamed per ks.
__global__ __launch_bounds__(256, 4) void k_pass3(
        const unsigned short* __restrict__ xT, const unsigned short* __restrict__ tabT,
        const unsigned short* __restrict__ pwwh, const float* __restrict__ pwb,
        const unsigned short* __restrict__ mah, unsigned short* __restrict__ xh,
        float* __restrict__ statsr, int lay)
{
    int b = blockIdx.x, ntg = blockIdx.y;
    int t = threadIdx.x, w = t >> 6, lane = t & 63;
    int lrow = lane & 15, g = lane >> 4;
    int wc = w & 1, wn = w >> 1;
    int nwave = ntg*512 + wn*256;            // wave's 256-n range (4 slabs of 64)

    half8 Bv[2][4];                          // [cot][ks], held across slabs
    #pragma unroll
    for (int cot = 0; cot < 2; ++cot){
        int co = wc*32 + cot*16 + lrow;
        #pragma unroll
        for (int ks = 0; ks < 4; ++ks){
            int k = ks*32 + g*8;
            const unsigned short* src = (k < 64)
                ? (pwwh + ((size_t)lay*64 + co)*64 + k)
                : (mah  + ((size_t)b*64 + co)*64 + (k - 64));
            Bv[cot][ks] = *(const half8*)src;
        }
    }
    float pb[2];
    pb[0] = pwb[lay*64 + wc*32 + lrow];
    pb[1] = pwb[lay*64 + wc*32 + 16 + lrow];

    float sS[2] = {0.f, 0.f}, sQ[2] = {0.f, 0.f};

    #pragma unroll
    for (int s = 0; s < 4; ++s){
        int nsl = nwave + s*64;
        fx4 acc[4][2];
        #pragma unroll
        for (int i = 0; i < 4; ++i){
            acc[i][0] = (fx4){0.f,0.f,0.f,0.f};
            acc[i][1] = (fx4){0.f,0.f,0.f,0.f};
        }
        #pragma unroll
        for (int ks = 0; ks < 4; ++ks){
            int k = ks*32 + g*8;
            half8 Af[4];
            #pragma unroll
            for (int nt = 0; nt < 4; ++nt){
                int n = nsl + nt*16 + lrow;
                const unsigned short* src = (k < 64)
                    ? (xT   + ((size_t)b*4096 + n)*64 + k)
                    : (tabT + (size_t)n*64 + (k - 64));
                Af[nt] = *(const half8*)src;
            }
            #pragma unroll
            for (int nt = 0; nt < 4; ++nt){
                acc[nt][0] = __builtin_amdgcn_mfma_f32_16x16x32_f16(Af[nt], Bv[0][ks], acc[nt][0], 0, 0, 0);
                acc[nt][1] = __builtin_amdgcn_mfma_f32_16x16x32_f16(Af[nt], Bv[1][ks], acc[nt][1], 0, 0, 0);
            }
        }
        // slab epilogue: +bias, packed uint2 stores, stats accumulate
        #pragma unroll
        for (int cot = 0; cot < 2; ++cot){
            int co = wc*32 + cot*16 + lrow;
            unsigned short* hr = xh + ((size_t)(b*64+co))*4096;
            #pragma unroll
            for (int nt = 0; nt < 4; ++nt){
                float h0 = acc[nt][cot][0] + pb[cot];
                float h1 = acc[nt][cot][1] + pb[cot];
                float h2 = acc[nt][cot][2] + pb[cot];
                float h3 = acc[nt][cot][3] + pb[cot];
                uint2 pk;
                pk.x = (unsigned int)f2h(h0) | ((unsigned int)f2h(h1) << 16);
                pk.y = (unsigned int)f2h(h2) | ((unsigned int)f2h(h3) << 16);
                *(uint2*)(hr + nsl + nt*16 + g*4) = pk;
                sS[cot] += (h0 + h1) + (h2 + h3);
                float q = h0*h0;
                q = fmaf(h1, h1, q); q = fmaf(h2, h2, q); q = fmaf(h3, h3, q);
                sQ[cot] += q;
            }
        }
    }
    __shared__ float sred[2][4][32];
    #pragma unroll
    for (int cot = 0; cot < 2; ++cot){
        float s = sS[cot], q = sQ[cot];
        s += __shfl_xor(s, 16); q += __shfl_xor(q, 16);
        s += __shfl_xor(s, 32); q += __shfl_xor(q, 32);
        if (g == 0){
            sred[0][w][cot*16 + lrow] = s;
            sred[1][w][cot*16 + lrow] = q;
        }
    }
    __syncthreads();
    if (t < 64){
        int wcx = t >> 5, cl = t & 31;       // co = wcx*32 + cl = t
        float S = sred[0][wcx][cl] + sred[0][2 + wcx][cl];
        float Q = sred[1][wcx][cl] + sred[1][2 + wcx][cl];
        atomicAdd(statsr + (size_t)(b*64+t)*2,     S);
        atomicAdd(statsr + (size_t)(b*64+t)*2 + 1, Q);
    }
}

// ---------------- projection head (8 waves, 8 tiles per wave) ----------------
__global__ __launch_bounds__(512) void k_proj(
        const unsigned short* __restrict__ xT, const unsigned short* __restrict__ w1h,
        const float* __restrict__ b1, const float* __restrict__ w2,
        const float* __restrict__ b2, float* __restrict__ out)
{
    int b = blockIdx.x, ntg = blockIdx.y;
    int t = threadIdx.x, w = t >> 6, lane = t & 63;
    int lrow = lane & 15, g = lane >> 4;
    int o2h = w & 1, nq = w >> 1;
    int nb = ntg*512 + nq*128;

    half8 A[4][2];
    #pragma unroll
    for (int ot = 0; ot < 4; ++ot)
        #pragma unroll
        for (int ks = 0; ks < 2; ++ks)
            A[ot][ks] = *(const half8*)(w1h + (size_t)(o2h*64 + ot*16 + lrow)*64 + ks*32 + g*8);
    float bb[16], wv[16];
    #pragma unroll
    for (int ot = 0; ot < 4; ++ot)
        #pragma unroll
        for (int j = 0; j < 4; ++j){
            int o2 = o2h*64 + ot*16 + g*4 + j;
            bb[ot*4+j] = b1[o2];
            wv[ot*4+j] = w2[o2];
        }
    __shared__ float sred[4][8][2][16];
    for (int tl = 0; tl < 8; ++tl){
        int n = nb + tl*16 + lrow;
        fx4 acc[4];
        #pragma unroll
        for (int i = 0; i < 4; ++i) acc[i] = (fx4){0.f,0.f,0.f,0.f};
        #pragma unroll
        for (int ks = 0; ks < 2; ++ks){
            half8 bf = *(const half8*)(xT + ((size_t)b*4096 + n)*64 + ks*32 + g*8);
            #pragma unroll
            for (int ot = 0; ot < 4; ++ot)
                acc[ot] = __builtin_amdgcn_mfma_f32_16x16x32_f16(A[ot][ks], bf, acc[ot], 0, 0, 0);
        }
        float p = 0.f;
        #pragma unroll
        for (int ot = 0; ot < 4; ++ot)
            #pragma unroll
            for (int j = 0; j < 4; ++j)
                p = fmaf(wv[ot*4+j], gelu_f(acc[ot][j] + bb[ot*4+j]), p);
        p += __shfl_xor(p, 16); p += __shfl_xor(p, 32);
        if (lane < 16) sred[nq][tl][o2h][lane] = p;
    }
    __syncthreads();
    {
        int cl = t & 15, tlf = (t >> 4) & 7, nqf = t >> 7;
        out[(size_t)b*4096 + ntg*512 + t] =
            sred[nqf][tlf][0][cl] + sred[nqf][tlf][1][cl] + b2[0];
    }
}

// ---------------- launch ----------------
extern "C" void kernel_launch(void* const* d_in, const int* in_sizes, int n_in,
                              void* d_out, int out_size, void* d_ws, size_t ws_size,
                              hipStream_t stream) {
    (void)in_sizes; (void)n_in; (void)out_size; (void)ws_size;
    const float* z      = (const float*)d_in[0];
    const float* instp  = (const float*)d_in[1];
    const float* lift_w = (const float*)d_in[2];
    const float* lift_b = (const float*)d_in[3];
    const float* iw1    = (const float*)d_in[4];
    const float* ib1    = (const float*)d_in[5];
    const float* iw2    = (const float*)d_in[6];
    const float* ib2    = (const float*)d_in[7];
    const float* specw  = (const float*)d_in[8];
    const float* pww    = (const float*)d_in[9];
    const float* pwb    = (const float*)d_in[10];
    const float* pj1w   = (const float*)d_in[11];
    const float* pj1b   = (const float*)d_in[12];
    const float* pj2w   = (const float*)d_in[13];
    const float* pj2b   = (const float*)d_in[14];

    float* ws = (float*)d_ws;
    unsigned short* xh    = (unsigned short*)(ws + OFF_XH);
    unsigned short* xT    = (unsigned short*)(ws + OFF_XT);
    unsigned short* tabB  = (unsigned short*)(ws + OFF_TABB);
    unsigned short* tabT  = (unsigned short*)(ws + OFF_TABT);
    unsigned short* mah   = (unsigned short*)(ws + OFF_MAH);
    unsigned short* pwwh  = (unsigned short*)(ws + OFF_PWWH);
    unsigned short* w1h   = (unsigned short*)(ws + OFF_W1H);
    float* cond   = ws + OFF_COND;
    float* statsr = ws + OFF_STATS;
    float* dftp   = ws + OFF_DFTP;
    float* x0     = ws + OFF_X0;
    float* out    = (float*)d_out;

    k_tab  <<<dim3(1024),  dim3(256), 0, stream>>>(tabB, tabT, pww, pwwh, pj1w, w1h);
    k_cond <<<dim3(128),   dim3(64),  0, stream>>>(instp, iw1, ib1, iw2, ib2, cond);
    k_liftc<<<dim3(128,4), dim3(256), 0, stream>>>(z, lift_w, lift_b, cond, x0);

    for (int l = 0; l < 4; ++l){
        if (l == 0)
            k_prep<2,1><<<dim3(128,8), dim3(256), 0, stream>>>(xh, statsr, tabB, x0, xT, dftp);
        else
            k_prep<1,1><<<dim3(128,8), dim3(256), 0, stream>>>(xh, statsr, tabB, x0, xT, dftp);
        k_mix  <<<dim3(128,4), dim3(256), 0, stream>>>(dftp, specw, mah, statsr, l);
        k_pass3<<<dim3(128,8), dim3(256), 0, stream>>>(xT, tabT, pwwh, pwb, mah, xh, statsr, l);
    }
    k_prep<1,0><<<dim3(128,8), dim3(256), 0, stream>>>(xh, statsr, tabB, x0, xT, dftp);
    k_proj    <<<dim3(128,8),  dim3(512), 0, stream>>>(xT, w1h, pj1b, pj2w, pj2b, out);
}

// Round 12
// 469.754 us; speedup vs baseline: 1.0838x; 1.0838x over previous
//
#include <hip/hip_runtime.h>
#include <math.h>

// B=128, W=64, L=4096, MODES=32, N_LAYERS=4

typedef _Float16 half8 __attribute__((ext_vector_type(8)));  // 8 fp16 (4 VGPR)
typedef __attribute__((ext_vector_type(4))) float fx4;       // MFMA f32 acc

// fast gelu: tanh/sigmoid form, exp2-folded. Max dev from exact-erf ~5e-4.
__device__ __forceinline__ float gelu_f(float x){
    float u = x*x;
    float a = x * fmaf(-0.1029443f, u, -2.3022083f);   // -2y*log2(e)
    float e = exp2f(a);                                 // e^{-2y}
    float r = __builtin_amdgcn_rcpf(1.0f + e);          // sigmoid(2y)
    return x * r;
}
__device__ __forceinline__ unsigned short f2h(float f){
    union { _Float16 h; unsigned short u; } c;
    c.h = (_Float16)f;
    return c.u;
}
__device__ __forceinline__ float h2f(unsigned short u){
    union { unsigned short u; _Float16 h; } c;
    c.u = u;
    return (float)c.h;
}

// ---------------- workspace layout (float-slot offsets) ----------------
// xh    : fp16 [128][64][4096]  h (channel-major)
// xT    : fp16 [128][4096][64]  normalized x, position-major
// tabB  : fp16 [64][4096]       rows 0-31 cos, 32-63 sin (fwd DFT)
// tabT  : fp16 [4096][64]       transpose, scaled 1/64 (iDFT)
// mah   : fp16 [b][co][64]      iDFT coeffs x64
// pwwh  : fp16 [4][64][64]
// w1h   : fp16 [128][64]
// cond  : f32  [b][64]
// statsr: f32  [b][co][2]       RAW (S, Q) accumulated by pass3 atomics
// dftp  : f32  [b][8][64 ci][64 m2]
// x0    : f32  [b][64 wc][64 pos]  lift output (pre-interp)
static const size_t OFF_XH    = 0;
static const size_t OFF_XT    = 16777216;
static const size_t OFF_TABB  = 33554432;
static const size_t OFF_TABT  = 33685504;
static const size_t OFF_MAH   = 33816576;   // 262,144 slots
static const size_t OFF_PWWH  = 34078720;   // 8,192
static const size_t OFF_W1H   = 34086912;   // 4,096
static const size_t OFF_COND  = 34091008;   // 8,192
static const size_t OFF_STATS = 34099200;   // 16,384
static const size_t OFF_DFTP  = 34115584;   // 4,194,304
static const size_t OFF_X0    = 38309888;   // 524,288
// end = 38,834,176 slots = 155.3 MB (< proven 157.4 MB footprint)

// ---------------- trig tables + weight fp16 conversion ----------------
__global__ void k_tab(unsigned short* __restrict__ tabB, unsigned short* __restrict__ tabT,
                      const float* __restrict__ pww, unsigned short* __restrict__ pwwh,
                      const float* __restrict__ pj1w, unsigned short* __restrict__ w1h){
    int t = blockIdx.x*256 + threadIdx.x;        // 262144
    if (t < 16384) pwwh[t] = f2h(pww[t]);
    if (t < 8192)  w1h[t]  = f2h(pj1w[t]);
    int m2 = t >> 12, n = t & 4095;
    int m = m2 & 31;
    int r = (m*n) & 4095;
    int r2 = (r >= 2048) ? (r - 4096) : r;       // fold to [-pi, pi)
    float a = (float)r2 * 1.5339807878856412e-3f;   // 2*pi/4096
    float v = (m2 >= 32) ? sinf(a) : cosf(a);
    tabB[(size_t)m2*4096 + n] = f2h(v);
    tabT[(size_t)n*64 + m2]   = f2h(v * 0.015625f);
}

// ---------------- conditioning MLP ----------------
__global__ __launch_bounds__(64) void k_cond(const float* __restrict__ instp,
        const float* __restrict__ w1, const float* __restrict__ b1,
        const float* __restrict__ w2, const float* __restrict__ b2,
        float* __restrict__ cond){
    int b = blockIdx.x, tid = threadIdx.x;
    __shared__ float ipl[8];
    __shared__ float tl[64];
    if (tid < 8) ipl[tid] = instp[b*8 + tid];
    __syncthreads();
    float s = b1[tid];
    #pragma unroll
    for (int k = 0; k < 8; ++k) s = fmaf(ipl[k], w1[k*64 + tid], s);
    tl[tid] = gelu_f(s);
    __syncthreads();
    float c = b2[tid];
    #pragma unroll 8
    for (int j = 0; j < 64; ++j) c = fmaf(tl[j], w2[j*64 + tid], c);
    cond[b*64 + tid] = c;
}

// ---------------- lift core: x0 = z @ lift_w + lb + cond (f32, 2 MB) ----------------
// grid (128 b, 4 q), 256 thr.
__global__ __launch_bounds__(256) void k_liftc(const float* __restrict__ z,
        const float* __restrict__ lw, const float* __restrict__ lb,
        const float* __restrict__ cond, float* __restrict__ x0){
    int b = blockIdx.x, q = blockIdx.y;
    int t = threadIdx.x;
    __shared__ float zl[128];
    if (t < 128) zl[t] = z[b*128 + t];
    __syncthreads();
    #pragma unroll
    for (int i = 0; i < 4; ++i){
        int e = q*1024 + i*256 + t;            // e = wc*64 + pos
        float s = lb[e];
        #pragma unroll 8
        for (int d = 0; d < 128; ++d)
            s = fmaf(zl[d], lw[(size_t)d*4096 + e], s);
        x0[(size_t)b*4096 + e] = s + cond[b*64 + (e >> 6)];
    }
}

// ---------------- prep: (interp | norm+gelu) -> x, transpose-store xT, fwd-DFT ----------
// MODE: 1 = norm+gelu from xh; 2 = inline linear-interp from x0 (layer 0).
template<int MODE, int DODFT>
__global__ __launch_bounds__(256) void k_prep(
        const unsigned short* __restrict__ xhp, const float* __restrict__ statsr,
        const unsigned short* __restrict__ tabB, const float* __restrict__ x0,
        unsigned short* __restrict__ xT, float* __restrict__ dftp)
{
    int b = blockIdx.x, ng = blockIdx.y;
    int t = threadIdx.x;
    int w = t >> 6, lane = t & 63;
    int lrow = lane & 15, g = lane >> 4;
    __shared__ __align__(16) unsigned short xl[2][4096];
    __shared__ float xs[(MODE == 2) ? 65*64 : 1];   // [co][64+1 pad]
    int co = t >> 2, nq = t & 3;
    float mu = 0.f, rs = 1.f;
    if (MODE == 1){
        float2 sr = *(const float2*)(statsr + (size_t)(b*64+co)*2);
        mu = sr.x * (1.f/4096.f);
        float var = fmaf(sr.y, 1.f/4096.f, -mu*mu);
        rs = rsqrtf(var + 1e-5f);
    }
    if (MODE == 2){
        const float* xb0 = x0 + (size_t)b*4096;
        #pragma unroll
        for (int i = 0; i < 16; ++i){
            int idx = i*256 + t;
            xs[(idx >> 6)*65 + (idx & 63)] = xb0[idx];
        }
        __syncthreads();
    }
    fx4 acc[4];
    #pragma unroll
    for (int i = 0; i < 4; ++i) acc[i] = (fx4){0.f,0.f,0.f,0.f};

    const unsigned short* hrow = xhp + ((size_t)(b*64+co))*4096 + ng*512 + nq*16;
    unsigned short* xtbase = xT + ((size_t)b*4096 + (size_t)ng*512)*64;

    uint4 cA, cB;
    if (MODE == 1){ cA = *(const uint4*)(hrow); cB = *(const uint4*)(hrow + 8); }
    for (int it = 0; it < 8; ++it){
        int n0 = ng*512 + it*64;
        char* xb = (char*)(&xl[it & 1][0]);
        uint4 nA, nB;
        if (MODE == 1 && it < 7){                 // prefetch next iter's tile
            nA = *(const uint4*)(hrow + (it+1)*64);
            nB = *(const uint4*)(hrow + (it+1)*64 + 8);
        }
        unsigned int pk[8];
        if (MODE == 1){
            unsigned int hu[8] = {cA.x,cA.y,cA.z,cA.w,cB.x,cB.y,cB.z,cB.w};
            #pragma unroll
            for (int i = 0; i < 8; ++i){
                float f0 = h2f((unsigned short)(hu[i] & 0xFFFFu));
                float f1 = h2f((unsigned short)(hu[i] >> 16));
                f0 = gelu_f((f0 - mu)*rs);
                f1 = gelu_f((f1 - mu)*rs);
                pk[i] = (unsigned int)f2h(f0) | ((unsigned int)f2h(f1) << 16);
            }
        } else {                                  // MODE == 2: inline interp from x0
            const float* xr = xs + co*65;
            #pragma unroll
            for (int i = 0; i < 8; ++i){
                float v[2];
                #pragma unroll
                for (int q = 0; q < 2; ++q){
                    int n = n0 + nq*16 + i*2 + q;
                    float src = (n + 0.5f)*0.015625f - 0.5f;
                    src = fminf(fmaxf(src, 0.0f), 63.0f);
                    int i0 = (int)src;
                    int i1 = (i0 + 1 > 63) ? 63 : (i0 + 1);
                    float wt = src - (float)i0;
                    v[q] = xr[i0] + wt*(xr[i1] - xr[i0]);
                }
                pk[i] = (unsigned int)f2h(v[0]) | ((unsigned int)f2h(v[1]) << 16);
            }
        }
        unsigned int base = (unsigned int)co*128 + (unsigned int)nq*32;
        unsigned int sw = (unsigned int)((co & 7) << 4);
        *(uint4*)(xb + ((base +  0) ^ sw)) = make_uint4(pk[0],pk[1],pk[2],pk[3]);
        *(uint4*)(xb + ((base + 16) ^ sw)) = make_uint4(pk[4],pk[5],pk[6],pk[7]);
        __syncthreads();

        if (DODFT){
            int m0 = w*16;
            #pragma unroll
            for (int ks = 0; ks < 2; ++ks){
                int kk = ks*32 + g*8;
                half8 af = *(const half8*)(tabB + (size_t)(m0 + lrow)*4096 + n0 + kk);
                #pragma unroll
                for (int ct = 0; ct < 4; ++ct){
                    int row = ct*16 + lrow;
                    unsigned int ba = ((unsigned int)row*128 + (unsigned int)kk*2)
                                      ^ (unsigned int)((row & 7) << 4);
                    half8 bf = *(const half8*)(xb + ba);
                    acc[ct] = __builtin_amdgcn_mfma_f32_16x16x32_f16(af, bf, acc[ct], 0, 0, 0);
                }
            }
        }
        {   // transpose out: xT[b][n][co]
            int n = t & 63, coq = t >> 6;
            unsigned int opk[8];
            #pragma unroll
            for (int i = 0; i < 8; ++i){
                int r0 = coq*16 + 2*i, r1 = r0 + 1;
                unsigned int a0 = ((unsigned int)r0*128 + (unsigned int)n*2)
                                  ^ (unsigned int)((r0 & 7) << 4);
                unsigned int a1 = ((unsigned int)r1*128 + (unsigned int)n*2)
                                  ^ (unsigned int)((r1 & 7) << 4);
                unsigned short v0 = *(const unsigned short*)(xb + a0);
                unsigned short v1 = *(const unsigned short*)(xb + a1);
                opk[i] = (unsigned int)v0 | ((unsigned int)v1 << 16);
            }
            unsigned short* dst = xtbase + (size_t)(it*64 + n)*64 + coq*16;
            *(uint4*)dst       = make_uint4(opk[0],opk[1],opk[2],opk[3]);
            *(uint4*)(dst + 8) = make_uint4(opk[4],opk[5],opk[6],opk[7]);
        }
        if (MODE == 1 && it < 7){ cA = nA; cB = nB; }
        // no second barrier: next iter writes the other LDS buffer
    }
    if (DODFT){
        // dftp layout [b][ng][ci][m2]: j contiguous -> float4 stores
        int m0 = w*16;
        #pragma unroll
        for (int ct = 0; ct < 4; ++ct){
            float4 v = make_float4(acc[ct][0], acc[ct][1], acc[ct][2], acc[ct][3]);
            *(float4*)(dftp + ((size_t)(b*8+ng)*64 + ct*16 + lrow)*64 + m0 + g*4) = v;
        }
    }
}

// ---------------- spectral mix (fused dftred + stats zero), co-split ----------------
// grid (128 b, 4 coq), 256 thr. Thread = (mq=t&3, ciq=(t>>2)&3, co_l=t>>4).
__global__ __launch_bounds__(256) void k_mix(const float* __restrict__ dftp,
        const float* __restrict__ specw, unsigned short* __restrict__ mah,
        float* __restrict__ statsr, int l){
    int b = blockIdx.x, coq = blockIdx.y, t = threadIdx.x;
    __shared__ float xm[64*64];              // [ci][64]: r | i
    if (t < 128) statsr[b*128 + t] = 0.f;    // all coq blocks write 0 (benign)
    const float* dp = dftp + (size_t)b*8*4096;
    #pragma unroll
    for (int i = 0; i < 4; ++i){
        int e = i*1024 + t*4;                // e = ci*64 + m2, float4-aligned
        float4 s = make_float4(0.f,0.f,0.f,0.f);
        #pragma unroll
        for (int ng = 0; ng < 8; ++ng){
            float4 v = *(const float4*)(dp + (size_t)ng*4096 + e);
            s.x += v.x; s.y += v.y; s.z += v.z; s.w += v.w;
        }
        if (e & 32){ s.x = -s.x; s.y = -s.y; s.z = -s.z; s.w = -s.w; }  // sin half -> Xi
        *(float4*)(xm + e) = s;
    }
    __syncthreads();
    int mq = t & 3, ciq = (t >> 2) & 3, co_l = t >> 4;
    int co = coq*16 + co_l;
    float yr[8] = {0,0,0,0,0,0,0,0}, yi[8] = {0,0,0,0,0,0,0,0};
    const float* wbase = specw + (size_t)l*262144 + (size_t)co*64 + mq*16;
    #pragma unroll 4
    for (int cil = 0; cil < 16; ++cil){
        int ci = ciq*16 + cil;
        const float* wp = wbase + (size_t)ci*4096;
        float4 w0 = *(const float4*)(wp);
        float4 w1v = *(const float4*)(wp + 4);
        float4 w2v = *(const float4*)(wp + 8);
        float4 w3v = *(const float4*)(wp + 12);
        const float* xc = xm + ci*64 + mq*8;
        float4 r0 = *(const float4*)(xc);
        float4 r1 = *(const float4*)(xc + 4);
        float4 i0 = *(const float4*)(xc + 32);
        float4 i1 = *(const float4*)(xc + 36);
        float wr[8] = {w0.x,w0.z,w1v.x,w1v.z,w2v.x,w2v.z,w3v.x,w3v.z};
        float wi[8] = {w0.y,w0.w,w1v.y,w1v.w,w2v.y,w2v.w,w3v.y,w3v.w};
        float xr[8] = {r0.x,r0.y,r0.z,r0.w,r1.x,r1.y,r1.z,r1.w};
        float xi[8] = {i0.x,i0.y,i0.z,i0.w,i1.x,i1.y,i1.z,i1.w};
        #pragma unroll
        for (int mm = 0; mm < 8; ++mm){
            yr[mm] = fmaf(xr[mm], wr[mm], fmaf(-xi[mm], wi[mm], yr[mm]));
            yi[mm] = fmaf(xr[mm], wi[mm], fmaf( xi[mm], wr[mm], yi[mm]));
        }
    }
    #pragma unroll
    for (int mm = 0; mm < 8; ++mm){
        yr[mm] += __shfl_xor(yr[mm], 4); yr[mm] += __shfl_xor(yr[mm], 8);
        yi[mm] += __shfl_xor(yi[mm], 4); yi[mm] += __shfl_xor(yi[mm], 8);
    }
    if (ciq == 0){
        unsigned short* mb = mah + (size_t)(b*64 + co)*64;
        unsigned int pr[4], pi[4];
        #pragma unroll
        for (int p = 0; p < 4; ++p){
            int m0 = mq*8 + 2*p;
            float s0 = (m0 == 0) ? 0.015625f : 0.03125f;   // (1|2)/4096 * 64
            pr[p] = (unsigned int)f2h(s0*yr[2*p]) | ((unsigned int)f2h(0.03125f*yr[2*p+1]) << 16);
            pi[p] = (unsigned int)f2h(-0.03125f*yi[2*p]) | ((unsigned int)f2h(-0.03125f*yi[2*p+1]) << 16);
        }
        *(uint4*)(mb + mq*8)      = make_uint4(pr[0],pr[1],pr[2],pr[3]);
        *(uint4*)(mb + 32 + mq*8) = make_uint4(pi[0],pi[1],pi[2],pi[3]);
    }
}

// ---------------- fused pointwise + iDFT (MFMA, swapped operands) ----------------
// Round-10 decomposition (wave = 64-n slab x all 64 co, traffic-optimal) +
// sched_barrier(0) pinning ALL 32 fragment loads before the MFMA phase so the
// wave issues them back-to-back (one latency exposure, not 32).
__global__ __launch_bounds__(256, 2) void k_pass3(
        const unsigned short* __restrict__ xT, const unsigned short* __restrict__ tabT,
        const unsigned short* __restrict__ pwwh, const float* __restrict__ pwb,
        const unsigned short* __restrict__ mah, unsigned short* __restrict__ xh,
        float* __restrict__ statsr, int lay)
{
    int b = blockIdx.x, ntg = blockIdx.y;
    int t = threadIdx.x, w = t >> 6, lane = t & 63;
    int lrow = lane & 15, g = lane >> 4;
    int nsl = ntg*256 + w*64;                // this wave's 64-n slab

    half8 A[4][4];                           // [nt][ks]: rows = n
    #pragma unroll
    for (int nt = 0; nt < 4; ++nt){
        int n = nsl + nt*16 + lrow;
        #pragma unroll
        for (int ks = 0; ks < 4; ++ks){
            int k = ks*32 + g*8;
            const unsigned short* src = (k < 64)
                ? (xT   + ((size_t)b*4096 + n)*64 + k)
                : (tabT + (size_t)n*64 + (k - 64));
            A[nt][ks] = *(const half8*)src;
        }
    }
    half8 Bv[4][4];                          // [cot][ks]: cols = co
    #pragma unroll
    for (int cot = 0; cot < 4; ++cot){
        int co = cot*16 + lrow;
        #pragma unroll
        for (int ks = 0; ks < 4; ++ks){
            int k = ks*32 + g*8;
            const unsigned short* src = (k < 64)
                ? (pwwh + ((size_t)lay*64 + co)*64 + k)
                : (mah  + ((size_t)b*64 + co)*64 + (k - 64));
            Bv[cot][ks] = *(const half8*)src;
        }
    }
    __builtin_amdgcn_sched_barrier(0);       // pin: all loads issued before MFMAs

    fx4 acc[4][4];                           // [nt][cot]
    #pragma unroll
    for (int i = 0; i < 4; ++i)
        #pragma unroll
        for (int j = 0; j < 4; ++j) acc[i][j] = (fx4){0.f,0.f,0.f,0.f};

    #pragma unroll
    for (int ks = 0; ks < 4; ++ks)
        #pragma unroll
        for (int nt = 0; nt < 4; ++nt)
            #pragma unroll
            for (int cot = 0; cot < 4; ++cot)
                acc[nt][cot] = __builtin_amdgcn_mfma_f32_16x16x32_f16(A[nt][ks], Bv[cot][ks], acc[nt][cot], 0, 0, 0);

    // epilogue: +bias, packed uint2 stores, per-cot stats
    float sS[4] = {0,0,0,0}, sQ[4] = {0,0,0,0};
    #pragma unroll
    for (int cot = 0; cot < 4; ++cot){
        int co = cot*16 + lrow;
        float pb = pwb[lay*64 + co];
        unsigned short* hr = xh + ((size_t)(b*64+co))*4096;
        #pragma unroll
        for (int nt = 0; nt < 4; ++nt){
            float h0 = acc[nt][cot][0] + pb;
            float h1 = acc[nt][cot][1] + pb;
            float h2 = acc[nt][cot][2] + pb;
            float h3 = acc[nt][cot][3] + pb;
            uint2 pk;
            pk.x = (unsigned int)f2h(h0) | ((unsigned int)f2h(h1) << 16);
            pk.y = (unsigned int)f2h(h2) | ((unsigned int)f2h(h3) << 16);
            *(uint2*)(hr + nsl + nt*16 + g*4) = pk;
            sS[cot] += (h0 + h1) + (h2 + h3);
            float q = h0*h0;
            q = fmaf(h1, h1, q); q = fmaf(h2, h2, q); q = fmaf(h3, h3, q);
            sQ[cot] += q;
        }
    }
    __shared__ float sred[2][4][64];
    #pragma unroll
    for (int cot = 0; cot < 4; ++cot){
        float s = sS[cot], q = sQ[cot];
        s += __shfl_xor(s, 16); q += __shfl_xor(q, 16);
        s += __shfl_xor(s, 32); q += __shfl_xor(q, 32);
        if (g == 0){
            sred[0][w][cot*16 + lrow] = s;
            sred[1][w][cot*16 + lrow] = q;
        }
    }
    __syncthreads();
    if (t < 64){
        float S = 0.f, Q = 0.f;
        #pragma unroll
        for (int ww = 0; ww < 4; ++ww){ S += sred[0][ww][t]; Q += sred[1][ww][t]; }
        atomicAdd(statsr + (size_t)(b*64+t)*2,     S);
        atomicAdd(statsr + (size_t)(b*64+t)*2 + 1, Q);
    }
}

// ---------------- projection head (8 waves, 8 tiles per wave) ----------------
__global__ __launch_bounds__(512) void k_proj(
        const unsigned short* __restrict__ xT, const unsigned short* __restrict__ w1h,
        const float* __restrict__ b1, const float* __restrict__ w2,
        const float* __restrict__ b2, float* __restrict__ out)
{
    int b = blockIdx.x, ntg = blockIdx.y;
    int t = threadIdx.x, w = t >> 6, lane = t & 63;
    int lrow = lane & 15, g = lane >> 4;
    int o2h = w & 1, nq = w >> 1;
    int nb = ntg*512 + nq*128;

    half8 A[4][2];
    #pragma unroll
    for (int ot = 0; ot < 4; ++ot)
        #pragma unroll
        for (int ks = 0; ks < 2; ++ks)
            A[ot][ks] = *(const half8*)(w1h + (size_t)(o2h*64 + ot*16 + lrow)*64 + ks*32 + g*8);
    float bb[16], wv[16];
    #pragma unroll
    for (int ot = 0; ot < 4; ++ot)
        #pragma unroll
        for (int j = 0; j < 4; ++j){
            int o2 = o2h*64 + ot*16 + g*4 + j;
            bb[ot*4+j] = b1[o2];
            wv[ot*4+j] = w2[o2];
        }
    __shared__ float sred[4][8][2][16];
    for (int tl = 0; tl < 8; ++tl){
        int n = nb + tl*16 + lrow;
        fx4 acc[4];
        #pragma unroll
        for (int i = 0; i < 4; ++i) acc[i] = (fx4){0.f,0.f,0.f,0.f};
        #pragma unroll
        for (int ks = 0; ks < 2; ++ks){
            half8 bf = *(const half8*)(xT + ((size_t)b*4096 + n)*64 + ks*32 + g*8);
            #pragma unroll
            for (int ot = 0; ot < 4; ++ot)
                acc[ot] = __builtin_amdgcn_mfma_f32_16x16x32_f16(A[ot][ks], bf, acc[ot], 0, 0, 0);
        }
        float p = 0.f;
        #pragma unroll
        for (int ot = 0; ot < 4; ++ot)
            #pragma unroll
            for (int j = 0; j < 4; ++j)
                p = fmaf(wv[ot*4+j], gelu_f(acc[ot][j] + bb[ot*4+j]), p);
        p += __shfl_xor(p, 16); p += __shfl_xor(p, 32);
        if (lane < 16) sred[nq][tl][o2h][lane] = p;
    }
    __syncthreads();
    {
        int cl = t & 15, tlf = (t >> 4) & 7, nqf = t >> 7;
        out[(size_t)b*4096 + ntg*512 + t] =
            sred[nqf][tlf][0][cl] + sred[nqf][tlf][1][cl] + b2[0];
    }
}

// ---------------- launch ----------------
extern "C" void kernel_launch(void* const* d_in, const int* in_sizes, int n_in,
                              void* d_out, int out_size, void* d_ws, size_t ws_size,
                              hipStream_t stream) {
    (void)in_sizes; (void)n_in; (void)out_size; (void)ws_size;
    const float* z      = (const float*)d_in[0];
    const float* instp  = (const float*)d_in[1];
    const float* lift_w = (const float*)d_in[2];
    const float* lift_b = (const float*)d_in[3];
    const float* iw1    = (const float*)d_in[4];
    const float* ib1    = (const float*)d_in[5];
    const float* iw2    = (const float*)d_in[6];
    const float* ib2    = (const float*)d_in[7];
    const float* specw  = (const float*)d_in[8];
    const float* pww    = (const float*)d_in[9];
    const float* pwb    = (const float*)d_in[10];
    const float* pj1w   = (const float*)d_in[11];
    const float* pj1b   = (const float*)d_in[12];
    const float* pj2w   = (const float*)d_in[13];
    const float* pj2b   = (const float*)d_in[14];

    float* ws = (float*)d_ws;
    unsigned short* xh    = (unsigned short*)(ws + OFF_XH);
    unsigned short* xT    = (unsigned short*)(ws + OFF_XT);
    unsigned short* tabB  = (unsigned short*)(ws + OFF_TABB);
    unsigned short* tabT  = (unsigned short*)(ws + OFF_TABT);
    unsigned short* mah   = (unsigned short*)(ws + OFF_MAH);
    unsigned short* pwwh  = (unsigned short*)(ws + OFF_PWWH);
    unsigned short* w1h   = (unsigned short*)(ws + OFF_W1H);
    float* cond   = ws + OFF_COND;
    float* statsr = ws + OFF_STATS;
    float* dftp   = ws + OFF_DFTP;
    float* x0     = ws + OFF_X0;
    float* out    = (float*)d_out;

    k_tab  <<<dim3(1024),  dim3(256), 0, stream>>>(tabB, tabT, pww, pwwh, pj1w, w1h);
    k_cond <<<dim3(128),   dim3(64),  0, stream>>>(instp, iw1, ib1, iw2, ib2, cond);
    k_liftc<<<dim3(128,4), dim3(256), 0, stream>>>(z, lift_w, lift_b, cond, x0);

    for (int l = 0; l < 4; ++l){
        if (l == 0)
            k_prep<2,1><<<dim3(128,8), dim3(256), 0, stream>>>(xh, statsr, tabB, x0, xT, dftp);
        else
            k_prep<1,1><<<dim3(128,8), dim3(256), 0, stream>>>(xh, statsr, tabB, x0, xT, dftp);
        k_mix  <<<dim3(128,4),  dim3(256), 0, stream>>>(dftp, specw, mah, statsr, l);
        k_pass3<<<dim3(128,16), dim3(256), 0, stream>>>(xT, tabT, pwwh, pwb, mah, xh, statsr, l);
    }
    k_prep<1,0><<<dim3(128,8), dim3(256), 0, stream>>>(xh, statsr, tabB, x0, xT, dftp);
    k_proj    <<<dim3(128,8),  dim3(512), 0, stream>>>(xT, w1h, pj1b, pj2w, pj2b, out);
}

// Round 13
// 456.452 us; speedup vs baseline: 1.1154x; 1.0291x over previous
//
#include <hip/hip_runtime.h>
#include <math.h>

// B=128, W=64, L=4096, MODES=32, N_LAYERS=4

typedef _Float16 half8 __attribute__((ext_vector_type(8)));  // 8 fp16 (4 VGPR)
typedef __attribute__((ext_vector_type(4))) float fx4;       // MFMA f32 acc

// fast gelu: tanh/sigmoid form, exp2-folded. Max dev from exact-erf ~5e-4.
__device__ __forceinline__ float gelu_f(float x){
    float u = x*x;
    float a = x * fmaf(-0.1029443f, u, -2.3022083f);   // -2y*log2(e)
    float e = exp2f(a);                                 // e^{-2y}
    float r = __builtin_amdgcn_rcpf(1.0f + e);          // sigmoid(2y)
    return x * r;
}
__device__ __forceinline__ unsigned short f2h(float f){
    union { _Float16 h; unsigned short u; } c;
    c.h = (_Float16)f;
    return c.u;
}
__device__ __forceinline__ float h2f(unsigned short u){
    union { unsigned short u; _Float16 h; } c;
    c.u = u;
    return (float)c.h;
}

// ---------------- workspace layout (float-slot offsets) ----------------
// xh    : fp16 [128][64][4096]  h (channel-major)
// xT    : fp16 [128][4096][64]  normalized x, position-major
// tabB  : fp16 [64][4096]       rows 0-31 cos, 32-63 sin (fwd DFT)
// tabT  : fp16 [4096][64]       transpose, scaled 1/64 (iDFT)
// mah   : fp16 [b][co][64]      iDFT coeffs x64
// pwwh  : fp16 [4][64][64]
// w1h   : fp16 [128][64]
// cond  : f32  [b][64]
// statsr: f32  [b][co][2]       RAW (S, Q) accumulated by pass3 atomics
// dftp  : f32  [b][8][64 ci][64 m2]
// x0    : f32  [b][64 wc][64 pos]  lift output (pre-interp)
static const size_t OFF_XH    = 0;
static const size_t OFF_XT    = 16777216;
static const size_t OFF_TABB  = 33554432;
static const size_t OFF_TABT  = 33685504;
static const size_t OFF_MAH   = 33816576;   // 262,144 slots
static const size_t OFF_PWWH  = 34078720;   // 8,192
static const size_t OFF_W1H   = 34086912;   // 4,096
static const size_t OFF_COND  = 34091008;   // 8,192
static const size_t OFF_STATS = 34099200;   // 16,384
static const size_t OFF_DFTP  = 34115584;   // 4,194,304
static const size_t OFF_X0    = 38309888;   // 524,288
// end = 38,834,176 slots = 155.3 MB (< proven 157.4 MB footprint)

// ---------------- trig tables + weight fp16 conversion ----------------
__global__ void k_tab(unsigned short* __restrict__ tabB, unsigned short* __restrict__ tabT,
                      const float* __restrict__ pww, unsigned short* __restrict__ pwwh,
                      const float* __restrict__ pj1w, unsigned short* __restrict__ w1h){
    int t = blockIdx.x*256 + threadIdx.x;        // 262144
    if (t < 16384) pwwh[t] = f2h(pww[t]);
    if (t < 8192)  w1h[t]  = f2h(pj1w[t]);
    int m2 = t >> 12, n = t & 4095;
    int m = m2 & 31;
    int r = (m*n) & 4095;
    int r2 = (r >= 2048) ? (r - 4096) : r;       // fold to [-pi, pi)
    float a = (float)r2 * 1.5339807878856412e-3f;   // 2*pi/4096
    float v = (m2 >= 32) ? sinf(a) : cosf(a);
    tabB[(size_t)m2*4096 + n] = f2h(v);
    tabT[(size_t)n*64 + m2]   = f2h(v * 0.015625f);
}

// ---------------- conditioning MLP ----------------
__global__ __launch_bounds__(64) void k_cond(const float* __restrict__ instp,
        const float* __restrict__ w1, const float* __restrict__ b1,
        const float* __restrict__ w2, const float* __restrict__ b2,
        float* __restrict__ cond){
    int b = blockIdx.x, tid = threadIdx.x;
    __shared__ float ipl[8];
    __shared__ float tl[64];
    if (tid < 8) ipl[tid] = instp[b*8 + tid];
    __syncthreads();
    float s = b1[tid];
    #pragma unroll
    for (int k = 0; k < 8; ++k) s = fmaf(ipl[k], w1[k*64 + tid], s);
    tl[tid] = gelu_f(s);
    __syncthreads();
    float c = b2[tid];
    #pragma unroll 8
    for (int j = 0; j < 64; ++j) c = fmaf(tl[j], w2[j*64 + tid], c);
    cond[b*64 + tid] = c;
}

// ---------------- lift core: x0 = z @ lift_w + lb + cond (f32, 2 MB) ----------------
// grid (128 b, 4 q), 256 thr.
__global__ __launch_bounds__(256) void k_liftc(const float* __restrict__ z,
        const float* __restrict__ lw, const float* __restrict__ lb,
        const float* __restrict__ cond, float* __restrict__ x0){
    int b = blockIdx.x, q = blockIdx.y;
    int t = threadIdx.x;
    __shared__ float zl[128];
    if (t < 128) zl[t] = z[b*128 + t];
    __syncthreads();
    #pragma unroll
    for (int i = 0; i < 4; ++i){
        int e = q*1024 + i*256 + t;            // e = wc*64 + pos
        float s = lb[e];
        #pragma unroll 8
        for (int d = 0; d < 128; ++d)
            s = fmaf(zl[d], lw[(size_t)d*4096 + e], s);
        x0[(size_t)b*4096 + e] = s + cond[b*64 + (e >> 6)];
    }
}

// ---------------- prep: (interp | norm+gelu) -> x, transpose-store xT, fwd-DFT ----------
// MODE: 1 = norm+gelu from xh; 2 = inline linear-interp from x0 (layer 0).
template<int MODE, int DODFT>
__global__ __launch_bounds__(256) void k_prep(
        const unsigned short* __restrict__ xhp, const float* __restrict__ statsr,
        const unsigned short* __restrict__ tabB, const float* __restrict__ x0,
        unsigned short* __restrict__ xT, float* __restrict__ dftp)
{
    int b = blockIdx.x, ng = blockIdx.y;
    int t = threadIdx.x;
    int w = t >> 6, lane = t & 63;
    int lrow = lane & 15, g = lane >> 4;
    __shared__ __align__(16) unsigned short xl[2][4096];
    __shared__ float xs[(MODE == 2) ? 65*64 : 1];   // [co][64+1 pad]
    int co = t >> 2, nq = t & 3;
    float mu = 0.f, rs = 1.f;
    if (MODE == 1){
        float2 sr = *(const float2*)(statsr + (size_t)(b*64+co)*2);
        mu = sr.x * (1.f/4096.f);
        float var = fmaf(sr.y, 1.f/4096.f, -mu*mu);
        rs = rsqrtf(var + 1e-5f);
    }
    if (MODE == 2){
        const float* xb0 = x0 + (size_t)b*4096;
        #pragma unroll
        for (int i = 0; i < 16; ++i){
            int idx = i*256 + t;
            xs[(idx >> 6)*65 + (idx & 63)] = xb0[idx];
        }
        __syncthreads();
    }
    fx4 acc[4];
    #pragma unroll
    for (int i = 0; i < 4; ++i) acc[i] = (fx4){0.f,0.f,0.f,0.f};

    const unsigned short* hrow = xhp + ((size_t)(b*64+co))*4096 + ng*512 + nq*16;
    unsigned short* xtbase = xT + ((size_t)b*4096 + (size_t)ng*512)*64;

    uint4 cA, cB;
    if (MODE == 1){ cA = *(const uint4*)(hrow); cB = *(const uint4*)(hrow + 8); }
    for (int it = 0; it < 8; ++it){
        int n0 = ng*512 + it*64;
        char* xb = (char*)(&xl[it & 1][0]);
        uint4 nA, nB;
        if (MODE == 1 && it < 7){                 // prefetch next iter's tile
            nA = *(const uint4*)(hrow + (it+1)*64);
            nB = *(const uint4*)(hrow + (it+1)*64 + 8);
        }
        unsigned int pk[8];
        if (MODE == 1){
            unsigned int hu[8] = {cA.x,cA.y,cA.z,cA.w,cB.x,cB.y,cB.z,cB.w};
            #pragma unroll
            for (int i = 0; i < 8; ++i){
                float f0 = h2f((unsigned short)(hu[i] & 0xFFFFu));
                float f1 = h2f((unsigned short)(hu[i] >> 16));
                f0 = gelu_f((f0 - mu)*rs);
                f1 = gelu_f((f1 - mu)*rs);
                pk[i] = (unsigned int)f2h(f0) | ((unsigned int)f2h(f1) << 16);
            }
        } else {                                  // MODE == 2: inline interp from x0
            const float* xr = xs + co*65;
            #pragma unroll
            for (int i = 0; i < 8; ++i){
                float v[2];
                #pragma unroll
                for (int q = 0; q < 2; ++q){
                    int n = n0 + nq*16 + i*2 + q;
                    float src = (n + 0.5f)*0.015625f - 0.5f;
                    src = fminf(fmaxf(src, 0.0f), 63.0f);
                    int i0 = (int)src;
                    int i1 = (i0 + 1 > 63) ? 63 : (i0 + 1);
                    float wt = src - (float)i0;
                    v[q] = xr[i0] + wt*(xr[i1] - xr[i0]);
                }
                pk[i] = (unsigned int)f2h(v[0]) | ((unsigned int)f2h(v[1]) << 16);
            }
        }
        unsigned int base = (unsigned int)co*128 + (unsigned int)nq*32;
        unsigned int sw = (unsigned int)((co & 7) << 4);
        *(uint4*)(xb + ((base +  0) ^ sw)) = make_uint4(pk[0],pk[1],pk[2],pk[3]);
        *(uint4*)(xb + ((base + 16) ^ sw)) = make_uint4(pk[4],pk[5],pk[6],pk[7]);
        __syncthreads();

        if (DODFT){
            int m0 = w*16;
            #pragma unroll
            for (int ks = 0; ks < 2; ++ks){
                int kk = ks*32 + g*8;
                half8 af = *(const half8*)(tabB + (size_t)(m0 + lrow)*4096 + n0 + kk);
                #pragma unroll
                for (int ct = 0; ct < 4; ++ct){
                    int row = ct*16 + lrow;
                    unsigned int ba = ((unsigned int)row*128 + (unsigned int)kk*2)
                                      ^ (unsigned int)((row & 7) << 4);
                    half8 bf = *(const half8*)(xb + ba);
                    acc[ct] = __builtin_amdgcn_mfma_f32_16x16x32_f16(af, bf, acc[ct], 0, 0, 0);
                }
            }
        }
        {   // transpose out: xT[b][n][co]
            int n = t & 63, coq = t >> 6;
            unsigned int opk[8];
            #pragma unroll
            for (int i = 0; i < 8; ++i){
                int r0 = coq*16 + 2*i, r1 = r0 + 1;
                unsigned int a0 = ((unsigned int)r0*128 + (unsigned int)n*2)
                                  ^ (unsigned int)((r0 & 7) << 4);
                unsigned int a1 = ((unsigned int)r1*128 + (unsigned int)n*2)
                                  ^ (unsigned int)((r1 & 7) << 4);
                unsigned short v0 = *(const unsigned short*)(xb + a0);
                unsigned short v1 = *(const unsigned short*)(xb + a1);
                opk[i] = (unsigned int)v0 | ((unsigned int)v1 << 16);
            }
            unsigned short* dst = xtbase + (size_t)(it*64 + n)*64 + coq*16;
            *(uint4*)dst       = make_uint4(opk[0],opk[1],opk[2],opk[3]);
            *(uint4*)(dst + 8) = make_uint4(opk[4],opk[5],opk[6],opk[7]);
        }
        if (MODE == 1 && it < 7){ cA = nA; cB = nB; }
        // no second barrier: next iter writes the other LDS buffer
    }
    if (DODFT){
        // dftp layout [b][ng][ci][m2]: j contiguous -> float4 stores
        int m0 = w*16;
        #pragma unroll
        for (int ct = 0; ct < 4; ++ct){
            float4 v = make_float4(acc[ct][0], acc[ct][1], acc[ct][2], acc[ct][3]);
            *(float4*)(dftp + ((size_t)(b*8+ng)*64 + ct*16 + lrow)*64 + m0 + g*4) = v;
        }
    }
}

// ---------------- spectral mix (fused dftred + stats zero), co-split ----------------
// grid (128 b, 4 coq), 256 thr. Thread = (mq=t&3, ciq=(t>>2)&3, co_l=t>>4).
__global__ __launch_bounds__(256) void k_mix(const float* __restrict__ dftp,
        const float* __restrict__ specw, unsigned short* __restrict__ mah,
        float* __restrict__ statsr, int l){
    int b = blockIdx.x, coq = blockIdx.y, t = threadIdx.x;
    __shared__ float xm[64*64];              // [ci][64]: r | i
    if (t < 128) statsr[b*128 + t] = 0.f;    // all coq blocks write 0 (benign)
    const float* dp = dftp + (size_t)b*8*4096;
    #pragma unroll
    for (int i = 0; i < 4; ++i){
        int e = i*1024 + t*4;                // e = ci*64 + m2, float4-aligned
        float4 s = make_float4(0.f,0.f,0.f,0.f);
        #pragma unroll
        for (int ng = 0; ng < 8; ++ng){
            float4 v = *(const float4*)(dp + (size_t)ng*4096 + e);
            s.x += v.x; s.y += v.y; s.z += v.z; s.w += v.w;
        }
        if (e & 32){ s.x = -s.x; s.y = -s.y; s.z = -s.z; s.w = -s.w; }  // sin half -> Xi
        *(float4*)(xm + e) = s;
    }
    __syncthreads();
    int mq = t & 3, ciq = (t >> 2) & 3, co_l = t >> 4;
    int co = coq*16 + co_l;
    float yr[8] = {0,0,0,0,0,0,0,0}, yi[8] = {0,0,0,0,0,0,0,0};
    const float* wbase = specw + (size_t)l*262144 + (size_t)co*64 + mq*16;
    #pragma unroll 4
    for (int cil = 0; cil < 16; ++cil){
        int ci = ciq*16 + cil;
        const float* wp = wbase + (size_t)ci*4096;
        float4 w0 = *(const float4*)(wp);
        float4 w1v = *(const float4*)(wp + 4);
        float4 w2v = *(const float4*)(wp + 8);
        float4 w3v = *(const float4*)(wp + 12);
        const float* xc = xm + ci*64 + mq*8;
        float4 r0 = *(const float4*)(xc);
        float4 r1 = *(const float4*)(xc + 4);
        float4 i0 = *(const float4*)(xc + 32);
        float4 i1 = *(const float4*)(xc + 36);
        float wr[8] = {w0.x,w0.z,w1v.x,w1v.z,w2v.x,w2v.z,w3v.x,w3v.z};
        float wi[8] = {w0.y,w0.w,w1v.y,w1v.w,w2v.y,w2v.w,w3v.y,w3v.w};
        float xr[8] = {r0.x,r0.y,r0.z,r0.w,r1.x,r1.y,r1.z,r1.w};
        float xi[8] = {i0.x,i0.y,i0.z,i0.w,i1.x,i1.y,i1.z,i1.w};
        #pragma unroll
        for (int mm = 0; mm < 8; ++mm){
            yr[mm] = fmaf(xr[mm], wr[mm], fmaf(-xi[mm], wi[mm], yr[mm]));
            yi[mm] = fmaf(xr[mm], wi[mm], fmaf( xi[mm], wr[mm], yi[mm]));
        }
    }
    #pragma unroll
    for (int mm = 0; mm < 8; ++mm){
        yr[mm] += __shfl_xor(yr[mm], 4); yr[mm] += __shfl_xor(yr[mm], 8);
        yi[mm] += __shfl_xor(yi[mm], 4); yi[mm] += __shfl_xor(yi[mm], 8);
    }
    if (ciq == 0){
        unsigned short* mb = mah + (size_t)(b*64 + co)*64;
        unsigned int pr[4], pi[4];
        #pragma unroll
        for (int p = 0; p < 4; ++p){
            int m0 = mq*8 + 2*p;
            float s0 = (m0 == 0) ? 0.015625f : 0.03125f;   // (1|2)/4096 * 64
            pr[p] = (unsigned int)f2h(s0*yr[2*p]) | ((unsigned int)f2h(0.03125f*yr[2*p+1]) << 16);
            pi[p] = (unsigned int)f2h(-0.03125f*yi[2*p]) | ((unsigned int)f2h(-0.03125f*yi[2*p+1]) << 16);
        }
        *(uint4*)(mb + mq*8)      = make_uint4(pr[0],pr[1],pr[2],pr[3]);
        *(uint4*)(mb + 32 + mq*8) = make_uint4(pi[0],pi[1],pi[2],pi[3]);
    }
}

// ---------------- fused pointwise + iDFT (MFMA, swapped operands, cot-loop) -------
// Wave = 64-n slab x all 64 co (traffic-optimal, A read once). cot is a SEQUENTIAL
// loop: per cot load Bv[4] (L2-resident pwwh/mah, re-reads cheap), 16 MFMAs,
// epilogue. Peak live regs ~115 -> launch_bounds(256,4) => 4 blocks/CU.
__global__ __launch_bounds__(256, 4) void k_pass3(
        const unsigned short* __restrict__ xT, const unsigned short* __restrict__ tabT,
        const unsigned short* __restrict__ pwwh, const float* __restrict__ pwb,
        const unsigned short* __restrict__ mah, unsigned short* __restrict__ xh,
        float* __restrict__ statsr, int lay)
{
    int b = blockIdx.x, ntg = blockIdx.y;
    int t = threadIdx.x, w = t >> 6, lane = t & 63;
    int lrow = lane & 15, g = lane >> 4;
    int nsl = ntg*256 + w*64;                // this wave's 64-n slab

    half8 A[4][4];                           // [nt][ks]: rows = n (held across cot loop)
    #pragma unroll
    for (int nt = 0; nt < 4; ++nt){
        int n = nsl + nt*16 + lrow;
        #pragma unroll
        for (int ks = 0; ks < 4; ++ks){
            int k = ks*32 + g*8;
            const unsigned short* src = (k < 64)
                ? (xT   + ((size_t)b*4096 + n)*64 + k)
                : (tabT + (size_t)n*64 + (k - 64));
            A[nt][ks] = *(const half8*)src;
        }
    }
    __shared__ float sred[2][4][64];
    #pragma unroll
    for (int cot = 0; cot < 4; ++cot){
        int co = cot*16 + lrow;
        half8 Bv[4];
        #pragma unroll
        for (int ks = 0; ks < 4; ++ks){
            int k = ks*32 + g*8;
            const unsigned short* src = (k < 64)
                ? (pwwh + ((size_t)lay*64 + co)*64 + k)
                : (mah  + ((size_t)b*64 + co)*64 + (k - 64));
            Bv[ks] = *(const half8*)src;
        }
        fx4 acc[4];
        #pragma unroll
        for (int i = 0; i < 4; ++i) acc[i] = (fx4){0.f,0.f,0.f,0.f};
        #pragma unroll
        for (int ks = 0; ks < 4; ++ks)
            #pragma unroll
            for (int nt = 0; nt < 4; ++nt)
                acc[nt] = __builtin_amdgcn_mfma_f32_16x16x32_f16(A[nt][ks], Bv[ks], acc[nt], 0, 0, 0);

        // epilogue for this cot: +bias, packed uint2 stores, stats
        float pb = pwb[lay*64 + co];
        unsigned short* hr = xh + ((size_t)(b*64+co))*4096;
        float sS = 0.f, sQ = 0.f;
        #pragma unroll
        for (int nt = 0; nt < 4; ++nt){
            float h0 = acc[nt][0] + pb;
            float h1 = acc[nt][1] + pb;
            float h2 = acc[nt][2] + pb;
            float h3 = acc[nt][3] + pb;
            uint2 pk;
            pk.x = (unsigned int)f2h(h0) | ((unsigned int)f2h(h1) << 16);
            pk.y = (unsigned int)f2h(h2) | ((unsigned int)f2h(h3) << 16);
            *(uint2*)(hr + nsl + nt*16 + g*4) = pk;
            sS += (h0 + h1) + (h2 + h3);
            float q = h0*h0;
            q = fmaf(h1, h1, q); q = fmaf(h2, h2, q); q = fmaf(h3, h3, q);
            sQ += q;
        }
        sS += __shfl_xor(sS, 16); sQ += __shfl_xor(sQ, 16);
        sS += __shfl_xor(sS, 32); sQ += __shfl_xor(sQ, 32);
        if (g == 0){
            sred[0][w][cot*16 + lrow] = sS;
            sred[1][w][cot*16 + lrow] = sQ;
        }
    }
    __syncthreads();
    if (t < 64){
        float S = 0.f, Q = 0.f;
        #pragma unroll
        for (int ww = 0; ww < 4; ++ww){ S += sred[0][ww][t]; Q += sred[1][ww][t]; }
        atomicAdd(statsr + (size_t)(b*64+t)*2,     S);
        atomicAdd(statsr + (size_t)(b*64+t)*2 + 1, Q);
    }
}

// ---------------- projection head (8 waves, 8 tiles per wave) ----------------
__global__ __launch_bounds__(512) void k_proj(
        const unsigned short* __restrict__ xT, const unsigned short* __restrict__ w1h,
        const float* __restrict__ b1, const float* __restrict__ w2,
        const float* __restrict__ b2, float* __restrict__ out)
{
    int b = blockIdx.x, ntg = blockIdx.y;
    int t = threadIdx.x, w = t >> 6, lane = t & 63;
    int lrow = lane & 15, g = lane >> 4;
    int o2h = w & 1, nq = w >> 1;
    int nb = ntg*512 + nq*128;

    half8 A[4][2];
    #pragma unroll
    for (int ot = 0; ot < 4; ++ot)
        #pragma unroll
        for (int ks = 0; ks < 2; ++ks)
            A[ot][ks] = *(const half8*)(w1h + (size_t)(o2h*64 + ot*16 + lrow)*64 + ks*32 + g*8);
    float bb[16], wv[16];
    #pragma unroll
    for (int ot = 0; ot < 4; ++ot)
        #pragma unroll
        for (int j = 0; j < 4; ++j){
            int o2 = o2h*64 + ot*16 + g*4 + j;
            bb[ot*4+j] = b1[o2];
            wv[ot*4+j] = w2[o2];
        }
    __shared__ float sred[4][8][2][16];
    for (int tl = 0; tl < 8; ++tl){
        int n = nb + tl*16 + lrow;
        fx4 acc[4];
        #pragma unroll
        for (int i = 0; i < 4; ++i) acc[i] = (fx4){0.f,0.f,0.f,0.f};
        #pragma unroll
        for (int ks = 0; ks < 2; ++ks){
            half8 bf = *(const half8*)(xT + ((size_t)b*4096 + n)*64 + ks*32 + g*8);
            #pragma unroll
            for (int ot = 0; ot < 4; ++ot)
                acc[ot] = __builtin_amdgcn_mfma_f32_16x16x32_f16(A[ot][ks], bf, acc[ot], 0, 0, 0);
        }
        float p = 0.f;
        #pragma unroll
        for (int ot = 0; ot < 4; ++ot)
            #pragma unroll
            for (int j = 0; j < 4; ++j)
                p = fmaf(wv[ot*4+j], gelu_f(acc[ot][j] + bb[ot*4+j]), p);
        p += __shfl_xor(p, 16); p += __shfl_xor(p, 32);
        if (lane < 16) sred[nq][tl][o2h][lane] = p;
    }
    __syncthreads();
    {
        int cl = t & 15, tlf = (t >> 4) & 7, nqf = t >> 7;
        out[(size_t)b*4096 + ntg*512 + t] =
            sred[nqf][tlf][0][cl] + sred[nqf][tlf][1][cl] + b2[0];
    }
}

// ---------------- launch ----------------
extern "C" void kernel_launch(void* const* d_in, const int* in_sizes, int n_in,
                              void* d_out, int out_size, void* d_ws, size_t ws_size,
                              hipStream_t stream) {
    (void)in_sizes; (void)n_in; (void)out_size; (void)ws_size;
    const float* z      = (const float*)d_in[0];
    const float* instp  = (const float*)d_in[1];
    const float* lift_w = (const float*)d_in[2];
    const float* lift_b = (const float*)d_in[3];
    const float* iw1    = (const float*)d_in[4];
    const float* ib1    = (const float*)d_in[5];
    const float* iw2    = (const float*)d_in[6];
    const float* ib2    = (const float*)d_in[7];
    const float* specw  = (const float*)d_in[8];
    const float* pww    = (const float*)d_in[9];
    const float* pwb    = (const float*)d_in[10];
    const float* pj1w   = (const float*)d_in[11];
    const float* pj1b   = (const float*)d_in[12];
    const float* pj2w   = (const float*)d_in[13];
    const float* pj2b   = (const float*)d_in[14];

    float* ws = (float*)d_ws;
    unsigned short* xh    = (unsigned short*)(ws + OFF_XH);
    unsigned short* xT    = (unsigned short*)(ws + OFF_XT);
    unsigned short* tabB  = (unsigned short*)(ws + OFF_TABB);
    unsigned short* tabT  = (unsigned short*)(ws + OFF_TABT);
    unsigned short* mah   = (unsigned short*)(ws + OFF_MAH);
    unsigned short* pwwh  = (unsigned short*)(ws + OFF_PWWH);
    unsigned short* w1h   = (unsigned short*)(ws + OFF_W1H);
    float* cond   = ws + OFF_COND;
    float* statsr = ws + OFF_STATS;
    float* dftp   = ws + OFF_DFTP;
    float* x0     = ws + OFF_X0;
    float* out    = (float*)d_out;

    k_tab  <<<dim3(1024),  dim3(256), 0, stream>>>(tabB, tabT, pww, pwwh, pj1w, w1h);
    k_cond <<<dim3(128),   dim3(64),  0, stream>>>(instp, iw1, ib1, iw2, ib2, cond);
    k_liftc<<<dim3(128,4), dim3(256), 0, stream>>>(z, lift_w, lift_b, cond, x0);

    for (int l = 0; l < 4; ++l){
        if (l == 0)
            k_prep<2,1><<<dim3(128,8), dim3(256), 0, stream>>>(xh, statsr, tabB, x0, xT, dftp);
        else
            k_prep<1,1><<<dim3(128,8), dim3(256), 0, stream>>>(xh, statsr, tabB, x0, xT, dftp);
        k_mix  <<<dim3(128,4),  dim3(256), 0, stream>>>(dftp, specw, mah, statsr, l);
        k_pass3<<<dim3(128,16), dim3(256), 0, stream>>>(xT, tabT, pwwh, pwb, mah, xh, statsr, l);
    }
    k_prep<1,0><<<dim3(128,8), dim3(256), 0, stream>>>(xh, statsr, tabB, x0, xT, dftp);
    k_proj    <<<dim3(128,8),  dim3(512), 0, stream>>>(xT, w1h, pj1b, pj2w, pj2b, out);
}

// Round 14
// 442.257 us; speedup vs baseline: 1.1512x; 1.0321x over previous
//
#include <hip/hip_runtime.h>
#include <math.h>

// B=128, W=64, L=4096, MODES=32, N_LAYERS=4

typedef _Float16 half8 __attribute__((ext_vector_type(8)));  // 8 fp16 (4 VGPR)
typedef __attribute__((ext_vector_type(4))) float fx4;       // MFMA f32 acc

// fast gelu: tanh/sigmoid form, exp2-folded. Max dev from exact-erf ~5e-4.
__device__ __forceinline__ float gelu_f(float x){
    float u = x*x;
    float a = x * fmaf(-0.1029443f, u, -2.3022083f);   // -2y*log2(e)
    float e = exp2f(a);                                 // e^{-2y}
    float r = __builtin_amdgcn_rcpf(1.0f + e);          // sigmoid(2y)
    return x * r;
}
__device__ __forceinline__ unsigned short f2h(float f){
    union { _Float16 h; unsigned short u; } c;
    c.h = (_Float16)f;
    return c.u;
}
__device__ __forceinline__ float h2f(unsigned short u){
    union { unsigned short u; _Float16 h; } c;
    c.u = u;
    return (float)c.h;
}

// ---------------- workspace layout (float-slot offsets) ----------------
static const size_t OFF_XH    = 0;
static const size_t OFF_XT    = 16777216;
static const size_t OFF_TABB  = 33554432;
static const size_t OFF_TABT  = 33685504;
static const size_t OFF_MAH   = 33816576;   // 262,144 slots
static const size_t OFF_PWWH  = 34078720;   // 8,192
static const size_t OFF_W1H   = 34086912;   // 4,096
static const size_t OFF_COND  = 34091008;   // 8,192
static const size_t OFF_STATS = 34099200;   // 16,384
static const size_t OFF_DFTP  = 34115584;   // 4,194,304
static const size_t OFF_X0    = 38309888;   // 524,288
// end = 38,834,176 slots = 155.3 MB (< proven 157.4 MB footprint)

// ---------------- trig tables + weight fp16 conversion ----------------
__global__ void k_tab(unsigned short* __restrict__ tabB, unsigned short* __restrict__ tabT,
                      const float* __restrict__ pww, unsigned short* __restrict__ pwwh,
                      const float* __restrict__ pj1w, unsigned short* __restrict__ w1h){
    int t = blockIdx.x*256 + threadIdx.x;        // 262144
    if (t < 16384) pwwh[t] = f2h(pww[t]);
    if (t < 8192)  w1h[t]  = f2h(pj1w[t]);
    int m2 = t >> 12, n = t & 4095;
    int m = m2 & 31;
    int r = (m*n) & 4095;
    int r2 = (r >= 2048) ? (r - 4096) : r;       // fold to [-pi, pi)
    float a = (float)r2 * 1.5339807878856412e-3f;   // 2*pi/4096
    float v = (m2 >= 32) ? sinf(a) : cosf(a);
    tabB[(size_t)m2*4096 + n] = f2h(v);
    tabT[(size_t)n*64 + m2]   = f2h(v * 0.015625f);
}

// ---------------- conditioning MLP ----------------
__global__ __launch_bounds__(64) void k_cond(const float* __restrict__ instp,
        const float* __restrict__ w1, const float* __restrict__ b1,
        const float* __restrict__ w2, const float* __restrict__ b2,
        float* __restrict__ cond){
    int b = blockIdx.x, tid = threadIdx.x;
    __shared__ float ipl[8];
    __shared__ float tl[64];
    if (tid < 8) ipl[tid] = instp[b*8 + tid];
    __syncthreads();
    float s = b1[tid];
    #pragma unroll
    for (int k = 0; k < 8; ++k) s = fmaf(ipl[k], w1[k*64 + tid], s);
    tl[tid] = gelu_f(s);
    __syncthreads();
    float c = b2[tid];
    #pragma unroll 8
    for (int j = 0; j < 64; ++j) c = fmaf(tl[j], w2[j*64 + tid], c);
    cond[b*64 + tid] = c;
}

// ---------------- lift core: x0 = z @ lift_w + lb + cond (f32, 2 MB) ----------------
__global__ __launch_bounds__(256) void k_liftc(const float* __restrict__ z,
        const float* __restrict__ lw, const float* __restrict__ lb,
        const float* __restrict__ cond, float* __restrict__ x0){
    int b = blockIdx.x, q = blockIdx.y;
    int t = threadIdx.x;
    __shared__ float zl[128];
    if (t < 128) zl[t] = z[b*128 + t];
    __syncthreads();
    #pragma unroll
    for (int i = 0; i < 4; ++i){
        int e = q*1024 + i*256 + t;            // e = wc*64 + pos
        float s = lb[e];
        #pragma unroll 8
        for (int d = 0; d < 128; ++d)
            s = fmaf(zl[d], lw[(size_t)d*4096 + e], s);
        x0[(size_t)b*4096 + e] = s + cond[b*64 + (e >> 6)];
    }
}

// ---------------- prep: (interp | norm+gelu) -> x, transpose-store xT, fwd-DFT ----------
// MODE: 1 = norm+gelu from xh; 2 = inline linear-interp from x0 (layer 0).
template<int MODE, int DODFT>
__global__ __launch_bounds__(256) void k_prep(
        const unsigned short* __restrict__ xhp, const float* __restrict__ statsr,
        const unsigned short* __restrict__ tabB, const float* __restrict__ x0,
        unsigned short* __restrict__ xT, float* __restrict__ dftp)
{
    int b = blockIdx.x, ng = blockIdx.y;
    int t = threadIdx.x;
    int w = t >> 6, lane = t & 63;
    int lrow = lane & 15, g = lane >> 4;
    __shared__ __align__(16) unsigned short xl[2][4096];
    __shared__ float xs[(MODE == 2) ? 65*64 : 1];   // [co][64+1 pad]
    int co = t >> 2, nq = t & 3;
    float mu = 0.f, rs = 1.f;
    if (MODE == 1){
        float2 sr = *(const float2*)(statsr + (size_t)(b*64+co)*2);
        mu = sr.x * (1.f/4096.f);
        float var = fmaf(sr.y, 1.f/4096.f, -mu*mu);
        rs = rsqrtf(var + 1e-5f);
    }
    if (MODE == 2){
        const float* xb0 = x0 + (size_t)b*4096;
        #pragma unroll
        for (int i = 0; i < 16; ++i){
            int idx = i*256 + t;
            xs[(idx >> 6)*65 + (idx & 63)] = xb0[idx];
        }
        __syncthreads();
    }
    fx4 acc[4];
    #pragma unroll
    for (int i = 0; i < 4; ++i) acc[i] = (fx4){0.f,0.f,0.f,0.f};

    const unsigned short* hrow = xhp + ((size_t)(b*64+co))*4096 + ng*512 + nq*16;
    unsigned short* xtbase = xT + ((size_t)b*4096 + (size_t)ng*512)*64;

    uint4 cA, cB;
    if (MODE == 1){ cA = *(const uint4*)(hrow); cB = *(const uint4*)(hrow + 8); }
    for (int it = 0; it < 8; ++it){
        int n0 = ng*512 + it*64;
        char* xb = (char*)(&xl[it & 1][0]);
        uint4 nA, nB;
        if (MODE == 1 && it < 7){                 // prefetch next iter's tile
            nA = *(const uint4*)(hrow + (it+1)*64);
            nB = *(const uint4*)(hrow + (it+1)*64 + 8);
        }
        unsigned int pk[8];
        if (MODE == 1){
            unsigned int hu[8] = {cA.x,cA.y,cA.z,cA.w,cB.x,cB.y,cB.z,cB.w};
            #pragma unroll
            for (int i = 0; i < 8; ++i){
                float f0 = h2f((unsigned short)(hu[i] & 0xFFFFu));
                float f1 = h2f((unsigned short)(hu[i] >> 16));
                f0 = gelu_f((f0 - mu)*rs);
                f1 = gelu_f((f1 - mu)*rs);
                pk[i] = (unsigned int)f2h(f0) | ((unsigned int)f2h(f1) << 16);
            }
        } else {                                  // MODE == 2: inline interp from x0
            const float* xr = xs + co*65;
            #pragma unroll
            for (int i = 0; i < 8; ++i){
                float v[2];
                #pragma unroll
                for (int q = 0; q < 2; ++q){
                    int n = n0 + nq*16 + i*2 + q;
                    float src = (n + 0.5f)*0.015625f - 0.5f;
                    src = fminf(fmaxf(src, 0.0f), 63.0f);
                    int i0 = (int)src;
                    int i1 = (i0 + 1 > 63) ? 63 : (i0 + 1);
                    float wt = src - (float)i0;
                    v[q] = xr[i0] + wt*(xr[i1] - xr[i0]);
                }
                pk[i] = (unsigned int)f2h(v[0]) | ((unsigned int)f2h(v[1]) << 16);
            }
        }
        unsigned int base = (unsigned int)co*128 + (unsigned int)nq*32;
        unsigned int sw = (unsigned int)((co & 7) << 4);
        *(uint4*)(xb + ((base +  0) ^ sw)) = make_uint4(pk[0],pk[1],pk[2],pk[3]);
        *(uint4*)(xb + ((base + 16) ^ sw)) = make_uint4(pk[4],pk[5],pk[6],pk[7]);
        __syncthreads();

        if (DODFT){
            int m0 = w*16;
            #pragma unroll
            for (int ks = 0; ks < 2; ++ks){
                int kk = ks*32 + g*8;
                half8 af = *(const half8*)(tabB + (size_t)(m0 + lrow)*4096 + n0 + kk);
                #pragma unroll
                for (int ct = 0; ct < 4; ++ct){
                    int row = ct*16 + lrow;
                    unsigned int ba = ((unsigned int)row*128 + (unsigned int)kk*2)
                                      ^ (unsigned int)((row & 7) << 4);
                    half8 bf = *(const half8*)(xb + ba);
                    acc[ct] = __builtin_amdgcn_mfma_f32_16x16x32_f16(af, bf, acc[ct], 0, 0, 0);
                }
            }
        }
        {   // transpose out: xT[b][n][co]
            int n = t & 63, coq = t >> 6;
            unsigned int opk[8];
            #pragma unroll
            for (int i = 0; i < 8; ++i){
                int r0 = coq*16 + 2*i, r1 = r0 + 1;
                unsigned int a0 = ((unsigned int)r0*128 + (unsigned int)n*2)
                                  ^ (unsigned int)((r0 & 7) << 4);
                unsigned int a1 = ((unsigned int)r1*128 + (unsigned int)n*2)
                                  ^ (unsigned int)((r1 & 7) << 4);
                unsigned short v0 = *(const unsigned short*)(xb + a0);
                unsigned short v1 = *(const unsigned short*)(xb + a1);
                opk[i] = (unsigned int)v0 | ((unsigned int)v1 << 16);
            }
            unsigned short* dst = xtbase + (size_t)(it*64 + n)*64 + coq*16;
            *(uint4*)dst       = make_uint4(opk[0],opk[1],opk[2],opk[3]);
            *(uint4*)(dst + 8) = make_uint4(opk[4],opk[5],opk[6],opk[7]);
        }
        if (MODE == 1 && it < 7){ cA = nA; cB = nB; }
    }
    if (DODFT){
        int m0 = w*16;
        #pragma unroll
        for (int ct = 0; ct < 4; ++ct){
            float4 v = make_float4(acc[ct][0], acc[ct][1], acc[ct][2], acc[ct][3]);
            *(float4*)(dftp + ((size_t)(b*8+ng)*64 + ct*16 + lrow)*64 + m0 + g*4) = v;
        }
    }
}

// ---------------- spectral mix (fused dftred + stats zero), co-split ----------------
__global__ __launch_bounds__(256) void k_mix(const float* __restrict__ dftp,
        const float* __restrict__ specw, unsigned short* __restrict__ mah,
        float* __restrict__ statsr, int l){
    int b = blockIdx.x, coq = blockIdx.y, t = threadIdx.x;
    __shared__ float xm[64*64];              // [ci][64]: r | i
    if (t < 128) statsr[b*128 + t] = 0.f;
    const float* dp = dftp + (size_t)b*8*4096;
    #pragma unroll
    for (int i = 0; i < 4; ++i){
        int e = i*1024 + t*4;
        float4 s = make_float4(0.f,0.f,0.f,0.f);
        #pragma unroll
        for (int ng = 0; ng < 8; ++ng){
            float4 v = *(const float4*)(dp + (size_t)ng*4096 + e);
            s.x += v.x; s.y += v.y; s.z += v.z; s.w += v.w;
        }
        if (e & 32){ s.x = -s.x; s.y = -s.y; s.z = -s.z; s.w = -s.w; }
        *(float4*)(xm + e) = s;
    }
    __syncthreads();
    int mq = t & 3, ciq = (t >> 2) & 3, co_l = t >> 4;
    int co = coq*16 + co_l;
    float yr[8] = {0,0,0,0,0,0,0,0}, yi[8] = {0,0,0,0,0,0,0,0};
    const float* wbase = specw + (size_t)l*262144 + (size_t)co*64 + mq*16;
    #pragma unroll 4
    for (int cil = 0; cil < 16; ++cil){
        int ci = ciq*16 + cil;
        const float* wp = wbase + (size_t)ci*4096;
        float4 w0 = *(const float4*)(wp);
        float4 w1v = *(const float4*)(wp + 4);
        float4 w2v = *(const float4*)(wp + 8);
        float4 w3v = *(const float4*)(wp + 12);
        const float* xc = xm + ci*64 + mq*8;
        float4 r0 = *(const float4*)(xc);
        float4 r1 = *(const float4*)(xc + 4);
        float4 i0 = *(const float4*)(xc + 32);
        float4 i1 = *(const float4*)(xc + 36);
        float wr[8] = {w0.x,w0.z,w1v.x,w1v.z,w2v.x,w2v.z,w3v.x,w3v.z};
        float wi[8] = {w0.y,w0.w,w1v.y,w1v.w,w2v.y,w2v.w,w3v.y,w3v.w};
        float xr[8] = {r0.x,r0.y,r0.z,r0.w,r1.x,r1.y,r1.z,r1.w};
        float xi[8] = {i0.x,i0.y,i0.z,i0.w,i1.x,i1.y,i1.z,i1.w};
        #pragma unroll
        for (int mm = 0; mm < 8; ++mm){
            yr[mm] = fmaf(xr[mm], wr[mm], fmaf(-xi[mm], wi[mm], yr[mm]));
            yi[mm] = fmaf(xr[mm], wi[mm], fmaf( xi[mm], wr[mm], yi[mm]));
        }
    }
    #pragma unroll
    for (int mm = 0; mm < 8; ++mm){
        yr[mm] += __shfl_xor(yr[mm], 4); yr[mm] += __shfl_xor(yr[mm], 8);
        yi[mm] += __shfl_xor(yi[mm], 4); yi[mm] += __shfl_xor(yi[mm], 8);
    }
    if (ciq == 0){
        unsigned short* mb = mah + (size_t)(b*64 + co)*64;
        unsigned int pr[4], pi[4];
        #pragma unroll
        for (int p = 0; p < 4; ++p){
            int m0 = mq*8 + 2*p;
            float s0 = (m0 == 0) ? 0.015625f : 0.03125f;
            pr[p] = (unsigned int)f2h(s0*yr[2*p]) | ((unsigned int)f2h(0.03125f*yr[2*p+1]) << 16);
            pi[p] = (unsigned int)f2h(-0.03125f*yi[2*p]) | ((unsigned int)f2h(-0.03125f*yi[2*p+1]) << 16);
        }
        *(uint4*)(mb + mq*8)      = make_uint4(pr[0],pr[1],pr[2],pr[3]);
        *(uint4*)(mb + 32 + mq*8) = make_uint4(pi[0],pi[1],pi[2],pi[3]);
    }
}

// ---------------- fused pointwise + iDFT (MFMA, swapped operands, cot-loop) -------
__global__ __launch_bounds__(256, 4) void k_pass3(
        const unsigned short* __restrict__ xT, const unsigned short* __restrict__ tabT,
        const unsigned short* __restrict__ pwwh, const float* __restrict__ pwb,
        const unsigned short* __restrict__ mah, unsigned short* __restrict__ xh,
        float* __restrict__ statsr, int lay)
{
    int b = blockIdx.x, ntg = blockIdx.y;
    int t = threadIdx.x, w = t >> 6, lane = t & 63;
    int lrow = lane & 15, g = lane >> 4;
    int nsl = ntg*256 + w*64;                // this wave's 64-n slab

    half8 A[4][4];                           // [nt][ks]: rows = n (held across cot loop)
    #pragma unroll
    for (int nt = 0; nt < 4; ++nt){
        int n = nsl + nt*16 + lrow;
        #pragma unroll
        for (int ks = 0; ks < 4; ++ks){
            int k = ks*32 + g*8;
            const unsigned short* src = (k < 64)
                ? (xT   + ((size_t)b*4096 + n)*64 + k)
                : (tabT + (size_t)n*64 + (k - 64));
            A[nt][ks] = *(const half8*)src;
        }
    }
    __shared__ float sred[2][4][64];
    #pragma unroll
    for (int cot = 0; cot < 4; ++cot){
        int co = cot*16 + lrow;
        half8 Bv[4];
        #pragma unroll
        for (int ks = 0; ks < 4; ++ks){
            int k = ks*32 + g*8;
            const unsigned short* src = (k < 64)
                ? (pwwh + ((size_t)lay*64 + co)*64 + k)
                : (mah  + ((size_t)b*64 + co)*64 + (k - 64));
            Bv[ks] = *(const half8*)src;
        }
        fx4 acc[4];
        #pragma unroll
        for (int i = 0; i < 4; ++i) acc[i] = (fx4){0.f,0.f,0.f,0.f};
        #pragma unroll
        for (int ks = 0; ks < 4; ++ks)
            #pragma unroll
            for (int nt = 0; nt < 4; ++nt)
                acc[nt] = __builtin_amdgcn_mfma_f32_16x16x32_f16(A[nt][ks], Bv[ks], acc[nt], 0, 0, 0);

        float pb = pwb[lay*64 + co];
        unsigned short* hr = xh + ((size_t)(b*64+co))*4096;
        float sS = 0.f, sQ = 0.f;
        #pragma unroll
        for (int nt = 0; nt < 4; ++nt){
            float h0 = acc[nt][0] + pb;
            float h1 = acc[nt][1] + pb;
            float h2 = acc[nt][2] + pb;
            float h3 = acc[nt][3] + pb;
            uint2 pk;
            pk.x = (unsigned int)f2h(h0) | ((unsigned int)f2h(h1) << 16);
            pk.y = (unsigned int)f2h(h2) | ((unsigned int)f2h(h3) << 16);
            *(uint2*)(hr + nsl + nt*16 + g*4) = pk;
            sS += (h0 + h1) + (h2 + h3);
            float q = h0*h0;
            q = fmaf(h1, h1, q); q = fmaf(h2, h2, q); q = fmaf(h3, h3, q);
            sQ += q;
        }
        sS += __shfl_xor(sS, 16); sQ += __shfl_xor(sQ, 16);
        sS += __shfl_xor(sS, 32); sQ += __shfl_xor(sQ, 32);
        if (g == 0){
            sred[0][w][cot*16 + lrow] = sS;
            sred[1][w][cot*16 + lrow] = sQ;
        }
    }
    __syncthreads();
    if (t < 64){
        float S = 0.f, Q = 0.f;
        #pragma unroll
        for (int ww = 0; ww < 4; ++ww){ S += sred[0][ww][t]; Q += sred[1][ww][t]; }
        atomicAdd(statsr + (size_t)(b*64+t)*2,     S);
        atomicAdd(statsr + (size_t)(b*64+t)*2 + 1, Q);
    }
}

// ---------------- fused norm+gelu+projection head (reads xh directly) -------------
// grid (128 b, 8 ng), 256 thr (4 waves). Per iter (64-n tile): stage xh -> norm+gelu
// -> swizzled LDS (prep's exact pattern) -> MFMA (A = w1h rows, B = LDS column reads)
// -> gelu + w2 reduce -> sred; out-store of previous iter overlapped post-barrier.
__global__ __launch_bounds__(256) void k_proj2(
        const unsigned short* __restrict__ xhp, const float* __restrict__ statsr,
        const unsigned short* __restrict__ w1h, const float* __restrict__ b1,
        const float* __restrict__ w2, const float* __restrict__ b2,
        float* __restrict__ out)
{
    int b = blockIdx.x, ng = blockIdx.y;
    int t = threadIdx.x, w = t >> 6, lane = t & 63;
    int lrow = lane & 15, g = lane >> 4;
    int o2h = w & 1, nhalf = w >> 1;
    __shared__ __align__(16) unsigned short xl[2][4096];
    __shared__ float sred[2][2][2][2][16];   // [buf][nhalf][nt][o2h][lrow]

    // staging role (prep MODE1 pattern)
    int ci = t >> 2, nq = t & 3;
    float2 sr = *(const float2*)(statsr + (size_t)(b*64+ci)*2);
    float mu = sr.x * (1.f/4096.f);
    float var = fmaf(sr.y, 1.f/4096.f, -mu*mu);
    float rs = rsqrtf(var + 1e-5f);
    const unsigned short* hrow = xhp + ((size_t)(b*64+ci))*4096 + ng*512 + nq*16;

    // A-frags (held): o2 = o2h*64 + ot*16 + lrow, k octets
    half8 A[4][2];
    #pragma unroll
    for (int ot = 0; ot < 4; ++ot)
        #pragma unroll
        for (int ks = 0; ks < 2; ++ks)
            A[ot][ks] = *(const half8*)(w1h + (size_t)(o2h*64 + ot*16 + lrow)*64 + ks*32 + g*8);
    float bb[16], wv[16];
    #pragma unroll
    for (int ot = 0; ot < 4; ++ot)
        #pragma unroll
        for (int j = 0; j < 4; ++j){
            int o2 = o2h*64 + ot*16 + g*4 + j;
            bb[ot*4+j] = b1[o2];
            wv[ot*4+j] = w2[o2];
        }
    float bias2 = b2[0];

    uint4 cA = *(const uint4*)(hrow);
    uint4 cB = *(const uint4*)(hrow + 8);
    for (int it = 0; it < 8; ++it){
        char* xb = (char*)(&xl[it & 1][0]);
        uint4 nA, nB;
        if (it < 7){
            nA = *(const uint4*)(hrow + (it+1)*64);
            nB = *(const uint4*)(hrow + (it+1)*64 + 8);
        }
        unsigned int pk[8];
        {
            unsigned int hu[8] = {cA.x,cA.y,cA.z,cA.w,cB.x,cB.y,cB.z,cB.w};
            #pragma unroll
            for (int i = 0; i < 8; ++i){
                float f0 = h2f((unsigned short)(hu[i] & 0xFFFFu));
                float f1 = h2f((unsigned short)(hu[i] >> 16));
                f0 = gelu_f((f0 - mu)*rs);
                f1 = gelu_f((f1 - mu)*rs);
                pk[i] = (unsigned int)f2h(f0) | ((unsigned int)f2h(f1) << 16);
            }
        }
        unsigned int base = (unsigned int)ci*128 + (unsigned int)nq*32;
        unsigned int sw = (unsigned int)((ci & 7) << 4);
        *(uint4*)(xb + ((base +  0) ^ sw)) = make_uint4(pk[0],pk[1],pk[2],pk[3]);
        *(uint4*)(xb + ((base + 16) ^ sw)) = make_uint4(pk[4],pk[5],pk[6],pk[7]);
        __syncthreads();

        // out-store for previous iter (reads sred[(it-1)&1], disjoint from this iter's writes)
        if (it > 0 && t < 64){
            int nh = t >> 5, rem = t & 31, ntf = rem >> 4, cl = rem & 15;
            out[(size_t)b*4096 + ng*512 + (it-1)*64 + t] =
                sred[(it-1)&1][nh][ntf][0][cl] + sred[(it-1)&1][nh][ntf][1][cl] + bias2;
        }

        // MFMA phase: H1 for this wave's (o2-half, n-half)
        #pragma unroll
        for (int nt = 0; nt < 2; ++nt){
            int n_l = nhalf*32 + nt*16 + lrow;     // n within 64-tile (B col = lrow)
            half8 Bf[2];
            #pragma unroll
            for (int ks = 0; ks < 2; ++ks){
                union { unsigned short u[8]; half8 v; } bu;
                #pragma unroll
                for (int e = 0; e < 8; ++e){
                    int cie = ks*32 + g*8 + e;
                    unsigned int ba = ((unsigned int)cie*128 + (unsigned int)n_l*2)
                                      ^ (unsigned int)((cie & 7) << 4);
                    bu.u[e] = *(const unsigned short*)(xb + ba);
                }
                Bf[ks] = bu.v;
            }
            fx4 acc[4];
            #pragma unroll
            for (int i = 0; i < 4; ++i) acc[i] = (fx4){0.f,0.f,0.f,0.f};
            #pragma unroll
            for (int ks = 0; ks < 2; ++ks)
                #pragma unroll
                for (int ot = 0; ot < 4; ++ot)
                    acc[ot] = __builtin_amdgcn_mfma_f32_16x16x32_f16(A[ot][ks], Bf[ks], acc[ot], 0, 0, 0);
            float p = 0.f;
            #pragma unroll
            for (int ot = 0; ot < 4; ++ot)
                #pragma unroll
                for (int j = 0; j < 4; ++j)
                    p = fmaf(wv[ot*4+j], gelu_f(acc[ot][j] + bb[ot*4+j]), p);
            p += __shfl_xor(p, 16); p += __shfl_xor(p, 32);
            if (lane < 16) sred[it & 1][nhalf][nt][o2h][lane] = p;
        }
        if (it < 7){ cA = nA; cB = nB; }
    }
    __syncthreads();
    if (t < 64){
        int nh = t >> 5, rem = t & 31, ntf = rem >> 4, cl = rem & 15;
        out[(size_t)b*4096 + ng*512 + 7*64 + t] =
            sred[1][nh][ntf][0][cl] + sred[1][nh][ntf][1][cl] + bias2;
    }
}

// ---------------- launch ----------------
extern "C" void kernel_launch(void* const* d_in, const int* in_sizes, int n_in,
                              void* d_out, int out_size, void* d_ws, size_t ws_size,
                              hipStream_t stream) {
    (void)in_sizes; (void)n_in; (void)out_size; (void)ws_size;
    const float* z      = (const float*)d_in[0];
    const float* instp  = (const float*)d_in[1];
    const float* lift_w = (const float*)d_in[2];
    const float* lift_b = (const float*)d_in[3];
    const float* iw1    = (const float*)d_in[4];
    const float* ib1    = (const float*)d_in[5];
    const float* iw2    = (const float*)d_in[6];
    const float* ib2    = (const float*)d_in[7];
    const float* specw  = (const float*)d_in[8];
    const float* pww    = (const float*)d_in[9];
    const float* pwb    = (const float*)d_in[10];
    const float* pj1w   = (const float*)d_in[11];
    const float* pj1b   = (const float*)d_in[12];
    const float* pj2w   = (const float*)d_in[13];
    const float* pj2b   = (const float*)d_in[14];

    float* ws = (float*)d_ws;
    unsigned short* xh    = (unsigned short*)(ws + OFF_XH);
    unsigned short* xT    = (unsigned short*)(ws + OFF_XT);
    unsigned short* tabB  = (unsigned short*)(ws + OFF_TABB);
    unsigned short* tabT  = (unsigned short*)(ws + OFF_TABT);
    unsigned short* mah   = (unsigned short*)(ws + OFF_MAH);
    unsigned short* pwwh  = (unsigned short*)(ws + OFF_PWWH);
    unsigned short* w1h   = (unsigned short*)(ws + OFF_W1H);
    float* cond   = ws + OFF_COND;
    float* statsr = ws + OFF_STATS;
    float* dftp   = ws + OFF_DFTP;
    float* x0     = ws + OFF_X0;
    float* out    = (float*)d_out;

    k_tab  <<<dim3(1024),  dim3(256), 0, stream>>>(tabB, tabT, pww, pwwh, pj1w, w1h);
    k_cond <<<dim3(128),   dim3(64),  0, stream>>>(instp, iw1, ib1, iw2, ib2, cond);
    k_liftc<<<dim3(128,4), dim3(256), 0, stream>>>(z, lift_w, lift_b, cond, x0);

    for (int l = 0; l < 4; ++l){
        if (l == 0)
            k_prep<2,1><<<dim3(128,8), dim3(256), 0, stream>>>(xh, statsr, tabB, x0, xT, dftp);
        else
            k_prep<1,1><<<dim3(128,8), dim3(256), 0, stream>>>(xh, statsr, tabB, x0, xT, dftp);
        k_mix  <<<dim3(128,4),  dim3(256), 0, stream>>>(dftp, specw, mah, statsr, l);
        k_pass3<<<dim3(128,16), dim3(256), 0, stream>>>(xT, tabT, pwwh, pwb, mah, xh, statsr, l);
    }
    k_proj2<<<dim3(128,8), dim3(256), 0, stream>>>(xh, statsr, w1h, pj1b, pj2w, pj2b, out);
}

// Round 15
// 420.309 us; speedup vs baseline: 1.2113x; 1.0522x over previous
//
#include <hip/hip_runtime.h>
#include <math.h>

// B=128, W=64, L=4096, MODES=32, N_LAYERS=4

typedef _Float16 half8 __attribute__((ext_vector_type(8)));  // 8 fp16 (4 VGPR)
typedef __attribute__((ext_vector_type(4))) float fx4;       // MFMA f32 acc

// fast gelu: tanh/sigmoid form, exp2-folded. Max dev from exact-erf ~5e-4.
__device__ __forceinline__ float gelu_f(float x){
    float u = x*x;
    float a = x * fmaf(-0.1029443f, u, -2.3022083f);   // -2y*log2(e)
    float e = exp2f(a);                                 // e^{-2y}
    float r = __builtin_amdgcn_rcpf(1.0f + e);          // sigmoid(2y)
    return x * r;
}
__device__ __forceinline__ unsigned short f2h(float f){
    union { _Float16 h; unsigned short u; } c;
    c.h = (_Float16)f;
    return c.u;
}
__device__ __forceinline__ float h2f(unsigned short u){
    union { unsigned short u; _Float16 h; } c;
    c.u = u;
    return (float)c.h;
}

// ---------------- workspace layout (float-slot offsets) ----------------
// xh, tabB, tabT, mah, pwwh, w1h, cond, statsA/B, dftp, x0 — xT eliminated.
static const size_t OFF_XH     = 0;            // fp16 [128][64][4096]
static const size_t OFF_TABB   = 33554432;     // fp16 [64][4096]
static const size_t OFF_TABT   = 33685504;     // fp16 [4096][64] (x 1/64)
static const size_t OFF_MAH    = 33816576;     // fp16 [b][co][64]
static const size_t OFF_PWWH   = 34078720;
static const size_t OFF_W1H    = 34086912;
static const size_t OFF_COND   = 34091008;
static const size_t OFF_STATS  = 34099200;     // 16,384 (A)
static const size_t OFF_DFTP   = 34115584;     // 4,194,304
static const size_t OFF_X0     = 38309888;     // 524,288
static const size_t OFF_STATS2 = 38834176;     // 16,384 (B)
// end = 38,850,560 slots = 155.4 MB (< proven 157.4 MB footprint)

// ---------------- trig tables + weight fp16 conversion ----------------
__global__ void k_tab(unsigned short* __restrict__ tabB, unsigned short* __restrict__ tabT,
                      const float* __restrict__ pww, unsigned short* __restrict__ pwwh,
                      const float* __restrict__ pj1w, unsigned short* __restrict__ w1h){
    int t = blockIdx.x*256 + threadIdx.x;        // 262144
    if (t < 16384) pwwh[t] = f2h(pww[t]);
    if (t < 8192)  w1h[t]  = f2h(pj1w[t]);
    int m2 = t >> 12, n = t & 4095;
    int m = m2 & 31;
    int r = (m*n) & 4095;
    int r2 = (r >= 2048) ? (r - 4096) : r;       // fold to [-pi, pi)
    float a = (float)r2 * 1.5339807878856412e-3f;   // 2*pi/4096
    float v = (m2 >= 32) ? sinf(a) : cosf(a);
    tabB[(size_t)m2*4096 + n] = f2h(v);
    tabT[(size_t)n*64 + m2]   = f2h(v * 0.015625f);
}

// ---------------- conditioning MLP ----------------
__global__ __launch_bounds__(64) void k_cond(const float* __restrict__ instp,
        const float* __restrict__ w1, const float* __restrict__ b1,
        const float* __restrict__ w2, const float* __restrict__ b2,
        float* __restrict__ cond){
    int b = blockIdx.x, tid = threadIdx.x;
    __shared__ float ipl[8];
    __shared__ float tl[64];
    if (tid < 8) ipl[tid] = instp[b*8 + tid];
    __syncthreads();
    float s = b1[tid];
    #pragma unroll
    for (int k = 0; k < 8; ++k) s = fmaf(ipl[k], w1[k*64 + tid], s);
    tl[tid] = gelu_f(s);
    __syncthreads();
    float c = b2[tid];
    #pragma unroll 8
    for (int j = 0; j < 64; ++j) c = fmaf(tl[j], w2[j*64 + tid], c);
    cond[b*64 + tid] = c;
}

// ---------------- lift core: x0 = z @ lift_w + lb + cond (f32, 2 MB) ----------------
__global__ __launch_bounds__(256) void k_liftc(const float* __restrict__ z,
        const float* __restrict__ lw, const float* __restrict__ lb,
        const float* __restrict__ cond, float* __restrict__ x0){
    int b = blockIdx.x, q = blockIdx.y;
    int t = threadIdx.x;
    __shared__ float zl[128];
    if (t < 128) zl[t] = z[b*128 + t];
    __syncthreads();
    #pragma unroll
    for (int i = 0; i < 4; ++i){
        int e = q*1024 + i*256 + t;            // e = wc*64 + pos
        float s = lb[e];
        #pragma unroll 8
        for (int d = 0; d < 128; ++d)
            s = fmaf(zl[d], lw[(size_t)d*4096 + e], s);
        x0[(size_t)b*4096 + e] = s + cond[b*64 + (e >> 6)];
    }
}

// ---------------- prep: (interp | norm+gelu) -> x (LDS), fwd-DFT -> dftp --------
// MODE: 1 = norm+gelu from xh; 2 = inline linear-interp from x0 (layer 0).
// NO xT write anymore (pass3 rebuilds x itself).
template<int MODE>
__global__ __launch_bounds__(256) void k_prep(
        const unsigned short* __restrict__ xhp, const float* __restrict__ statsIn,
        const unsigned short* __restrict__ tabB, const float* __restrict__ x0,
        float* __restrict__ dftp)
{
    int b = blockIdx.x, ng = blockIdx.y;
    int t = threadIdx.x;
    int w = t >> 6, lane = t & 63;
    int lrow = lane & 15, g = lane >> 4;
    __shared__ __align__(16) unsigned short xl[2][4096];
    __shared__ float xs[(MODE == 2) ? 65*64 : 1];   // [ci][64+1 pad]
    int ci = t >> 2, nq = t & 3;
    float mu = 0.f, rs = 1.f;
    if (MODE == 1){
        float2 sr = *(const float2*)(statsIn + (size_t)(b*64+ci)*2);
        mu = sr.x * (1.f/4096.f);
        float var = fmaf(sr.y, 1.f/4096.f, -mu*mu);
        rs = rsqrtf(var + 1e-5f);
    }
    if (MODE == 2){
        const float* xb0 = x0 + (size_t)b*4096;
        #pragma unroll
        for (int i = 0; i < 16; ++i){
            int idx = i*256 + t;
            xs[(idx >> 6)*65 + (idx & 63)] = xb0[idx];
        }
        __syncthreads();
    }
    fx4 acc[4];
    #pragma unroll
    for (int i = 0; i < 4; ++i) acc[i] = (fx4){0.f,0.f,0.f,0.f};

    const unsigned short* hrow = xhp + ((size_t)(b*64+ci))*4096 + ng*512 + nq*16;

    uint4 cA, cB;
    if (MODE == 1){ cA = *(const uint4*)(hrow); cB = *(const uint4*)(hrow + 8); }
    for (int it = 0; it < 8; ++it){
        int n0 = ng*512 + it*64;
        char* xb = (char*)(&xl[it & 1][0]);
        uint4 nA, nB;
        if (MODE == 1 && it < 7){
            nA = *(const uint4*)(hrow + (it+1)*64);
            nB = *(const uint4*)(hrow + (it+1)*64 + 8);
        }
        unsigned int pk[8];
        if (MODE == 1){
            unsigned int hu[8] = {cA.x,cA.y,cA.z,cA.w,cB.x,cB.y,cB.z,cB.w};
            #pragma unroll
            for (int i = 0; i < 8; ++i){
                float f0 = h2f((unsigned short)(hu[i] & 0xFFFFu));
                float f1 = h2f((unsigned short)(hu[i] >> 16));
                f0 = gelu_f((f0 - mu)*rs);
                f1 = gelu_f((f1 - mu)*rs);
                pk[i] = (unsigned int)f2h(f0) | ((unsigned int)f2h(f1) << 16);
            }
        } else {
            const float* xr = xs + ci*65;
            #pragma unroll
            for (int i = 0; i < 8; ++i){
                float v[2];
                #pragma unroll
                for (int q = 0; q < 2; ++q){
                    int n = n0 + nq*16 + i*2 + q;
                    float src = (n + 0.5f)*0.015625f - 0.5f;
                    src = fminf(fmaxf(src, 0.0f), 63.0f);
                    int i0 = (int)src;
                    int i1 = (i0 + 1 > 63) ? 63 : (i0 + 1);
                    float wt = src - (float)i0;
                    v[q] = xr[i0] + wt*(xr[i1] - xr[i0]);
                }
                pk[i] = (unsigned int)f2h(v[0]) | ((unsigned int)f2h(v[1]) << 16);
            }
        }
        unsigned int base = (unsigned int)ci*128 + (unsigned int)nq*32;
        unsigned int sw = (unsigned int)((ci & 7) << 4);
        *(uint4*)(xb + ((base +  0) ^ sw)) = make_uint4(pk[0],pk[1],pk[2],pk[3]);
        *(uint4*)(xb + ((base + 16) ^ sw)) = make_uint4(pk[4],pk[5],pk[6],pk[7]);
        __syncthreads();

        {   // forward DFT MFMAs
            int m0 = w*16;
            #pragma unroll
            for (int ks = 0; ks < 2; ++ks){
                int kk = ks*32 + g*8;
                half8 af = *(const half8*)(tabB + (size_t)(m0 + lrow)*4096 + n0 + kk);
                #pragma unroll
                for (int ct = 0; ct < 4; ++ct){
                    int row = ct*16 + lrow;
                    unsigned int ba = ((unsigned int)row*128 + (unsigned int)kk*2)
                                      ^ (unsigned int)((row & 7) << 4);
                    half8 bf = *(const half8*)(xb + ba);
                    acc[ct] = __builtin_amdgcn_mfma_f32_16x16x32_f16(af, bf, acc[ct], 0, 0, 0);
                }
            }
        }
        if (MODE == 1 && it < 7){ cA = nA; cB = nB; }
    }
    {   // dftp [b][ng][ci][m2], float4 stores
        int m0 = w*16;
        #pragma unroll
        for (int ct = 0; ct < 4; ++ct){
            float4 v = make_float4(acc[ct][0], acc[ct][1], acc[ct][2], acc[ct][3]);
            *(float4*)(dftp + ((size_t)(b*8+ng)*64 + ct*16 + lrow)*64 + m0 + g*4) = v;
        }
    }
}

// ---------------- spectral mix (fused dftred + stats-target zero), co-split -------
__global__ __launch_bounds__(256) void k_mix(const float* __restrict__ dftp,
        const float* __restrict__ specw, unsigned short* __restrict__ mah,
        float* __restrict__ statsZero, int l){
    int b = blockIdx.x, coq = blockIdx.y, t = threadIdx.x;
    __shared__ float xm[64*64];              // [ci][64]: r | i
    if (t < 128) statsZero[b*128 + t] = 0.f;
    const float* dp = dftp + (size_t)b*8*4096;
    #pragma unroll
    for (int i = 0; i < 4; ++i){
        int e = i*1024 + t*4;
        float4 s = make_float4(0.f,0.f,0.f,0.f);
        #pragma unroll
        for (int ng = 0; ng < 8; ++ng){
            float4 v = *(const float4*)(dp + (size_t)ng*4096 + e);
            s.x += v.x; s.y += v.y; s.z += v.z; s.w += v.w;
        }
        if (e & 32){ s.x = -s.x; s.y = -s.y; s.z = -s.z; s.w = -s.w; }
        *(float4*)(xm + e) = s;
    }
    __syncthreads();
    int mq = t & 3, ciq = (t >> 2) & 3, co_l = t >> 4;
    int co = coq*16 + co_l;
    float yr[8] = {0,0,0,0,0,0,0,0}, yi[8] = {0,0,0,0,0,0,0,0};
    const float* wbase = specw + (size_t)l*262144 + (size_t)co*64 + mq*16;
    #pragma unroll 4
    for (int cil = 0; cil < 16; ++cil){
        int ci = ciq*16 + cil;
        const float* wp = wbase + (size_t)ci*4096;
        float4 w0 = *(const float4*)(wp);
        float4 w1v = *(const float4*)(wp + 4);
        float4 w2v = *(const float4*)(wp + 8);
        float4 w3v = *(const float4*)(wp + 12);
        const float* xc = xm + ci*64 + mq*8;
        float4 r0 = *(const float4*)(xc);
        float4 r1 = *(const float4*)(xc + 4);
        float4 i0 = *(const float4*)(xc + 32);
        float4 i1 = *(const float4*)(xc + 36);
        float wr[8] = {w0.x,w0.z,w1v.x,w1v.z,w2v.x,w2v.z,w3v.x,w3v.z};
        float wi[8] = {w0.y,w0.w,w1v.y,w1v.w,w2v.y,w2v.w,w3v.y,w3v.w};
        float xr[8] = {r0.x,r0.y,r0.z,r0.w,r1.x,r1.y,r1.z,r1.w};
        float xi[8] = {i0.x,i0.y,i0.z,i0.w,i1.x,i1.y,i1.z,i1.w};
        #pragma unroll
        for (int mm = 0; mm < 8; ++mm){
            yr[mm] = fmaf(xr[mm], wr[mm], fmaf(-xi[mm], wi[mm], yr[mm]));
            yi[mm] = fmaf(xr[mm], wi[mm], fmaf( xi[mm], wr[mm], yi[mm]));
        }
    }
    #pragma unroll
    for (int mm = 0; mm < 8; ++mm){
        yr[mm] += __shfl_xor(yr[mm], 4); yr[mm] += __shfl_xor(yr[mm], 8);
        yi[mm] += __shfl_xor(yi[mm], 4); yi[mm] += __shfl_xor(yi[mm], 8);
    }
    if (ciq == 0){
        unsigned short* mb = mah + (size_t)(b*64 + co)*64;
        unsigned int pr[4], pi[4];
        #pragma unroll
        for (int p = 0; p < 4; ++p){
            int m0 = mq*8 + 2*p;
            float s0 = (m0 == 0) ? 0.015625f : 0.03125f;
            pr[p] = (unsigned int)f2h(s0*yr[2*p]) | ((unsigned int)f2h(0.03125f*yr[2*p+1]) << 16);
            pi[p] = (unsigned int)f2h(-0.03125f*yi[2*p]) | ((unsigned int)f2h(-0.03125f*yi[2*p+1]) << 16);
        }
        *(uint4*)(mb + mq*8)      = make_uint4(pr[0],pr[1],pr[2],pr[3]);
        *(uint4*)(mb + 32 + mq*8) = make_uint4(pi[0],pi[1],pi[2],pi[3]);
    }
}

// ---------------- pass3: x rebuilt from xh inline, pw+iDFT MFMA -> h (in place) ----
// Per 64-n tile: stage(norm+gelu|interp) -> LDS1 [ci][n] swz -> transpose -> LDS2
// [n][ci] swz -> vector A-frags. Bv (weights/mah) held across tiles. In-place xh.
template<int MODE>
__global__ __launch_bounds__(256, 2) void k_pass3(
        const unsigned short* __restrict__ xhp, const float* __restrict__ statsIn,
        const float* __restrict__ x0, const unsigned short* __restrict__ tabT,
        const unsigned short* __restrict__ pwwh, const float* __restrict__ pwb,
        const unsigned short* __restrict__ mah, unsigned short* __restrict__ xh,
        float* __restrict__ statsOut, int lay)
{
    int b = blockIdx.x, ng = blockIdx.y;
    int t = threadIdx.x, w = t >> 6, lane = t & 63;
    int lrow = lane & 15, g = lane >> 4;
    __shared__ __align__(16) unsigned short xl1[4096];   // [ci][n] swizzled
    __shared__ __align__(16) unsigned short xl2[4096];   // [n][ci] swizzled
    __shared__ float xs[(MODE == 2) ? 65*64 : 1];
    __shared__ float sred[2][4][64];

    int ci = t >> 2, nq = t & 3;
    float mu = 0.f, rs = 1.f;
    if (MODE == 1){
        float2 sr = *(const float2*)(statsIn + (size_t)(b*64+ci)*2);
        mu = sr.x * (1.f/4096.f);
        float var = fmaf(sr.y, 1.f/4096.f, -mu*mu);
        rs = rsqrtf(var + 1e-5f);
    }
    if (MODE == 2){
        const float* xb0 = x0 + (size_t)b*4096;
        #pragma unroll
        for (int i = 0; i < 16; ++i){
            int idx = i*256 + t;
            xs[(idx >> 6)*65 + (idx & 63)] = xb0[idx];
        }
        __syncthreads();
    }
    half8 Bv[4][4];                          // [cot][ks], held
    #pragma unroll
    for (int cot = 0; cot < 4; ++cot){
        int co = cot*16 + lrow;
        #pragma unroll
        for (int ks = 0; ks < 4; ++ks){
            int k = ks*32 + g*8;
            const unsigned short* src = (k < 64)
                ? (pwwh + ((size_t)lay*64 + co)*64 + k)
                : (mah  + ((size_t)b*64 + co)*64 + (k - 64));
            Bv[cot][ks] = *(const half8*)src;
        }
    }
    float pb[4];
    #pragma unroll
    for (int cot = 0; cot < 4; ++cot) pb[cot] = pwb[lay*64 + cot*16 + lrow];
    float sS[4] = {0,0,0,0}, sQ[4] = {0,0,0,0};

    const unsigned short* hrow = xhp + ((size_t)(b*64+ci))*4096 + ng*512 + nq*16;
    uint4 cA, cB;
    if (MODE == 1){ cA = *(const uint4*)(hrow); cB = *(const uint4*)(hrow + 8); }

    for (int it = 0; it < 8; ++it){
        int n0 = ng*512 + it*64;
        uint4 nA, nB;
        if (MODE == 1 && it < 7){
            nA = *(const uint4*)(hrow + (it+1)*64);
            nB = *(const uint4*)(hrow + (it+1)*64 + 8);
        }
        unsigned int pk[8];
        if (MODE == 1){
            unsigned int hu[8] = {cA.x,cA.y,cA.z,cA.w,cB.x,cB.y,cB.z,cB.w};
            #pragma unroll
            for (int i = 0; i < 8; ++i){
                float f0 = h2f((unsigned short)(hu[i] & 0xFFFFu));
                float f1 = h2f((unsigned short)(hu[i] >> 16));
                f0 = gelu_f((f0 - mu)*rs);
                f1 = gelu_f((f1 - mu)*rs);
                pk[i] = (unsigned int)f2h(f0) | ((unsigned int)f2h(f1) << 16);
            }
        } else {
            const float* xr = xs + ci*65;
            #pragma unroll
            for (int i = 0; i < 8; ++i){
                float v[2];
                #pragma unroll
                for (int q = 0; q < 2; ++q){
                    int n = n0 + nq*16 + i*2 + q;
                    float src = (n + 0.5f)*0.015625f - 0.5f;
                    src = fminf(fmaxf(src, 0.0f), 63.0f);
                    int i0 = (int)src;
                    int i1 = (i0 + 1 > 63) ? 63 : (i0 + 1);
                    float wt = src - (float)i0;
                    v[q] = xr[i0] + wt*(xr[i1] - xr[i0]);
                }
                pk[i] = (unsigned int)f2h(v[0]) | ((unsigned int)f2h(v[1]) << 16);
            }
        }
        unsigned int base = (unsigned int)ci*128 + (unsigned int)nq*32;
        unsigned int sw = (unsigned int)((ci & 7) << 4);
        *(uint4*)((char*)xl1 + ((base +  0) ^ sw)) = make_uint4(pk[0],pk[1],pk[2],pk[3]);
        *(uint4*)((char*)xl1 + ((base + 16) ^ sw)) = make_uint4(pk[4],pk[5],pk[6],pk[7]);
        __syncthreads();

        {   // transpose LDS1 [ci][n] -> LDS2 [n][ci] (both swizzled)
            int n = t & 63, coq = t >> 6;
            unsigned int opk[8];
            #pragma unroll
            for (int i = 0; i < 8; ++i){
                int r0 = coq*16 + 2*i, r1 = r0 + 1;
                unsigned int a0 = ((unsigned int)r0*128 + (unsigned int)n*2)
                                  ^ (unsigned int)((r0 & 7) << 4);
                unsigned int a1 = ((unsigned int)r1*128 + (unsigned int)n*2)
                                  ^ (unsigned int)((r1 & 7) << 4);
                unsigned short v0 = *(const unsigned short*)((const char*)xl1 + a0);
                unsigned short v1 = *(const unsigned short*)((const char*)xl1 + a1);
                opk[i] = (unsigned int)v0 | ((unsigned int)v1 << 16);
            }
            unsigned int b0 = (unsigned int)n*128 + (unsigned int)coq*32;
            unsigned int swn = (unsigned int)((n & 7) << 4);
            *(uint4*)((char*)xl2 + ((b0 +  0) ^ swn)) = make_uint4(opk[0],opk[1],opk[2],opk[3]);
            *(uint4*)((char*)xl2 + ((b0 + 16) ^ swn)) = make_uint4(opk[4],opk[5],opk[6],opk[7]);
        }
        __syncthreads();

        // MFMA: wave w owns n rows [w*16, w*16+16) of this 64-tile
        int nl = w*16 + lrow;
        unsigned int swa = (unsigned int)((nl & 7) << 4);
        half8 Af[4];
        Af[0] = *(const half8*)((const char*)xl2 + (((unsigned int)nl*128 +  0 + g*16) ^ swa));
        Af[1] = *(const half8*)((const char*)xl2 + (((unsigned int)nl*128 + 64 + g*16) ^ swa));
        {
            const unsigned short* tb = tabT + (size_t)(n0 + nl)*64 + g*8;
            Af[2] = *(const half8*)(tb);
            Af[3] = *(const half8*)(tb + 32);
        }
        fx4 acc[4];
        #pragma unroll
        for (int i = 0; i < 4; ++i) acc[i] = (fx4){0.f,0.f,0.f,0.f};
        #pragma unroll
        for (int ks = 0; ks < 4; ++ks)
            #pragma unroll
            for (int cot = 0; cot < 4; ++cot)
                acc[cot] = __builtin_amdgcn_mfma_f32_16x16x32_f16(Af[ks], Bv[cot][ks], acc[cot], 0, 0, 0);

        // epilogue: h = acc + bias; packed uint2 store; stats accumulate
        #pragma unroll
        for (int cot = 0; cot < 4; ++cot){
            int co = cot*16 + lrow;
            unsigned short* hr = xh + ((size_t)(b*64+co))*4096;
            float h0 = acc[cot][0] + pb[cot];
            float h1 = acc[cot][1] + pb[cot];
            float h2 = acc[cot][2] + pb[cot];
            float h3 = acc[cot][3] + pb[cot];
            uint2 pk2;
            pk2.x = (unsigned int)f2h(h0) | ((unsigned int)f2h(h1) << 16);
            pk2.y = (unsigned int)f2h(h2) | ((unsigned int)f2h(h3) << 16);
            *(uint2*)(hr + n0 + w*16 + g*4) = pk2;
            sS[cot] += (h0 + h1) + (h2 + h3);
            float q = h0*h0;
            q = fmaf(h1, h1, q); q = fmaf(h2, h2, q); q = fmaf(h3, h3, q);
            sQ[cot] += q;
        }
        if (MODE == 1 && it < 7){ cA = nA; cB = nB; }
    }
    #pragma unroll
    for (int cot = 0; cot < 4; ++cot){
        float s = sS[cot], q = sQ[cot];
        s += __shfl_xor(s, 16); q += __shfl_xor(q, 16);
        s += __shfl_xor(s, 32); q += __shfl_xor(q, 32);
        if (g == 0){
            sred[0][w][cot*16 + lrow] = s;
            sred[1][w][cot*16 + lrow] = q;
        }
    }
    __syncthreads();
    if (t < 64){
        float S = 0.f, Q = 0.f;
        #pragma unroll
        for (int ww = 0; ww < 4; ++ww){ S += sred[0][ww][t]; Q += sred[1][ww][t]; }
        atomicAdd(statsOut + (size_t)(b*64+t)*2,     S);
        atomicAdd(statsOut + (size_t)(b*64+t)*2 + 1, Q);
    }
}

// ---------------- fused norm+gelu+projection head (LDS2 transpose, vector B) -----
__global__ __launch_bounds__(256) void k_proj2(
        const unsigned short* __restrict__ xhp, const float* __restrict__ statsIn,
        const unsigned short* __restrict__ w1h, const float* __restrict__ b1,
        const float* __restrict__ w2, const float* __restrict__ b2,
        float* __restrict__ out)
{
    int b = blockIdx.x, ng = blockIdx.y;
    int t = threadIdx.x, w = t >> 6, lane = t & 63;
    int lrow = lane & 15, g = lane >> 4;
    int o2h = w & 1, nhalf = w >> 1;
    __shared__ __align__(16) unsigned short xl1[4096];
    __shared__ __align__(16) unsigned short xl2[4096];
    __shared__ float sred[2][2][2][2][16];   // [buf][nhalf][nt][o2h][lrow]

    int ci = t >> 2, nq = t & 3;
    float2 sr = *(const float2*)(statsIn + (size_t)(b*64+ci)*2);
    float mu = sr.x * (1.f/4096.f);
    float var = fmaf(sr.y, 1.f/4096.f, -mu*mu);
    float rs = rsqrtf(var + 1e-5f);
    const unsigned short* hrow = xhp + ((size_t)(b*64+ci))*4096 + ng*512 + nq*16;

    half8 A[4][2];
    #pragma unroll
    for (int ot = 0; ot < 4; ++ot)
        #pragma unroll
        for (int ks = 0; ks < 2; ++ks)
            A[ot][ks] = *(const half8*)(w1h + (size_t)(o2h*64 + ot*16 + lrow)*64 + ks*32 + g*8);
    float bb[16], wv[16];
    #pragma unroll
    for (int ot = 0; ot < 4; ++ot)
        #pragma unroll
        for (int j = 0; j < 4; ++j){
            int o2 = o2h*64 + ot*16 + g*4 + j;
            bb[ot*4+j] = b1[o2];
            wv[ot*4+j] = w2[o2];
        }
    float bias2 = b2[0];

    uint4 cA = *(const uint4*)(hrow);
    uint4 cB = *(const uint4*)(hrow + 8);
    for (int it = 0; it < 8; ++it){
        uint4 nA, nB;
        if (it < 7){
            nA = *(const uint4*)(hrow + (it+1)*64);
            nB = *(const uint4*)(hrow + (it+1)*64 + 8);
        }
        unsigned int pk[8];
        {
            unsigned int hu[8] = {cA.x,cA.y,cA.z,cA.w,cB.x,cB.y,cB.z,cB.w};
            #pragma unroll
            for (int i = 0; i < 8; ++i){
                float f0 = h2f((unsigned short)(hu[i] & 0xFFFFu));
                float f1 = h2f((unsigned short)(hu[i] >> 16));
                f0 = gelu_f((f0 - mu)*rs);
                f1 = gelu_f((f1 - mu)*rs);
                pk[i] = (unsigned int)f2h(f0) | ((unsigned int)f2h(f1) << 16);
            }
        }
        unsigned int base = (unsigned int)ci*128 + (unsigned int)nq*32;
        unsigned int sw = (unsigned int)((ci & 7) << 4);
        *(uint4*)((char*)xl1 + ((base +  0) ^ sw)) = make_uint4(pk[0],pk[1],pk[2],pk[3]);
        *(uint4*)((char*)xl1 + ((base + 16) ^ sw)) = make_uint4(pk[4],pk[5],pk[6],pk[7]);
        __syncthreads();

        {   // transpose LDS1 -> LDS2
            int n = t & 63, coq = t >> 6;
            unsigned int opk[8];
            #pragma unroll
            for (int i = 0; i < 8; ++i){
                int r0 = coq*16 + 2*i, r1 = r0 + 1;
                unsigned int a0 = ((unsigned int)r0*128 + (unsigned int)n*2)
                                  ^ (unsigned int)((r0 & 7) << 4);
                unsigned int a1 = ((unsigned int)r1*128 + (unsigned int)n*2)
                                  ^ (unsigned int)((r1 & 7) << 4);
                unsigned short v0 = *(const unsigned short*)((const char*)xl1 + a0);
                unsigned short v1 = *(const unsigned short*)((const char*)xl1 + a1);
                opk[i] = (unsigned int)v0 | ((unsigned int)v1 << 16);
            }
            unsigned int b0 = (unsigned int)n*128 + (unsigned int)coq*32;
            unsigned int swn = (unsigned int)((n & 7) << 4);
            *(uint4*)((char*)xl2 + ((b0 +  0) ^ swn)) = make_uint4(opk[0],opk[1],opk[2],opk[3]);
            *(uint4*)((char*)xl2 + ((b0 + 16) ^ swn)) = make_uint4(opk[4],opk[5],opk[6],opk[7]);
        }
        __syncthreads();

        // out-store for previous iter
        if (it > 0 && t < 64){
            int nh = t >> 5, rem = t & 31, ntf = rem >> 4, cl = rem & 15;
            out[(size_t)b*4096 + ng*512 + (it-1)*64 + t] =
                sred[(it-1)&1][nh][ntf][0][cl] + sred[(it-1)&1][nh][ntf][1][cl] + bias2;
        }

        // MFMA: vector B-frags from LDS2
        #pragma unroll
        for (int nt = 0; nt < 2; ++nt){
            int n_l = nhalf*32 + nt*16 + lrow;
            unsigned int swa = (unsigned int)((n_l & 7) << 4);
            half8 Bf[2];
            Bf[0] = *(const half8*)((const char*)xl2 + (((unsigned int)n_l*128 +  0 + g*16) ^ swa));
            Bf[1] = *(const half8*)((const char*)xl2 + (((unsigned int)n_l*128 + 64 + g*16) ^ swa));
            fx4 acc[4];
            #pragma unroll
            for (int i = 0; i < 4; ++i) acc[i] = (fx4){0.f,0.f,0.f,0.f};
            #pragma unroll
            for (int ks = 0; ks < 2; ++ks)
                #pragma unroll
                for (int ot = 0; ot < 4; ++ot)
                    acc[ot] = __builtin_amdgcn_mfma_f32_16x16x32_f16(A[ot][ks], Bf[ks], acc[ot], 0, 0, 0);
            float p = 0.f;
            #pragma unroll
            for (int ot = 0; ot < 4; ++ot)
                #pragma unroll
                for (int j = 0; j < 4; ++j)
                    p = fmaf(wv[ot*4+j], gelu_f(acc[ot][j] + bb[ot*4+j]), p);
            p += __shfl_xor(p, 16); p += __shfl_xor(p, 32);
            if (lane < 16) sred[it & 1][nhalf][nt][o2h][lane] = p;
        }
        if (it < 7){ cA = nA; cB = nB; }
    }
    __syncthreads();
    if (t < 64){
        int nh = t >> 5, rem = t & 31, ntf = rem >> 4, cl = rem & 15;
        out[(size_t)b*4096 + ng*512 + 7*64 + t] =
            sred[1][nh][ntf][0][cl] + sred[1][nh][ntf][1][cl] + bias2;
    }
}

// ---------------- launch ----------------
extern "C" void kernel_launch(void* const* d_in, const int* in_sizes, int n_in,
                              void* d_out, int out_size, void* d_ws, size_t ws_size,
                              hipStream_t stream) {
    (void)in_sizes; (void)n_in; (void)out_size; (void)ws_size;
    const float* z      = (const float*)d_in[0];
    const float* instp  = (const float*)d_in[1];
    const float* lift_w = (const float*)d_in[2];
    const float* lift_b = (const float*)d_in[3];
    const float* iw1    = (const float*)d_in[4];
    const float* ib1    = (const float*)d_in[5];
    const float* iw2    = (const float*)d_in[6];
    const float* ib2    = (const float*)d_in[7];
    const float* specw  = (const float*)d_in[8];
    const float* pww    = (const float*)d_in[9];
    const float* pwb    = (const float*)d_in[10];
    const float* pj1w   = (const float*)d_in[11];
    const float* pj1b   = (const float*)d_in[12];
    const float* pj2w   = (const float*)d_in[13];
    const float* pj2b   = (const float*)d_in[14];

    float* ws = (float*)d_ws;
    unsigned short* xh    = (unsigned short*)(ws + OFF_XH);
    unsigned short* tabB  = (unsigned short*)(ws + OFF_TABB);
    unsigned short* tabT  = (unsigned short*)(ws + OFF_TABT);
    unsigned short* mah   = (unsigned short*)(ws + OFF_MAH);
    unsigned short* pwwh  = (unsigned short*)(ws + OFF_PWWH);
    unsigned short* w1h   = (unsigned short*)(ws + OFF_W1H);
    float* cond   = ws + OFF_COND;
    float* dftp   = ws + OFF_DFTP;
    float* x0     = ws + OFF_X0;
    float* sbuf[2] = { ws + OFF_STATS, ws + OFF_STATS2 };
    float* out    = (float*)d_out;

    k_tab  <<<dim3(1024),  dim3(256), 0, stream>>>(tabB, tabT, pww, pwwh, pj1w, w1h);
    k_cond <<<dim3(128),   dim3(64),  0, stream>>>(instp, iw1, ib1, iw2, ib2, cond);
    k_liftc<<<dim3(128,4), dim3(256), 0, stream>>>(z, lift_w, lift_b, cond, x0);

    for (int l = 0; l < 4; ++l){
        float* sIn  = sbuf[l & 1];
        float* sOut = sbuf[(l + 1) & 1];
        if (l == 0)
            k_prep<2><<<dim3(128,8), dim3(256), 0, stream>>>(xh, sIn, tabB, x0, dftp);
        else
            k_prep<1><<<dim3(128,8), dim3(256), 0, stream>>>(xh, sIn, tabB, x0, dftp);
        k_mix<<<dim3(128,4), dim3(256), 0, stream>>>(dftp, specw, mah, sOut, l);
        if (l == 0)
            k_pass3<2><<<dim3(128,8), dim3(256), 0, stream>>>(xh, sIn, x0, tabT, pwwh, pwb, mah, xh, sOut, l);
        else
            k_pass3<1><<<dim3(128,8), dim3(256), 0, stream>>>(xh, sIn, x0, tabT, pwwh, pwb, mah, xh, sOut, l);
    }
    k_proj2<<<dim3(128,8), dim3(256), 0, stream>>>(xh, sbuf[0], w1h, pj1b, pj2w, pj2b, out);
}

// Round 16
// 419.837 us; speedup vs baseline: 1.2126x; 1.0011x over previous
//
#include <hip/hip_runtime.h>
#include <math.h>

// B=128, W=64, L=4096, MODES=32, N_LAYERS=4

typedef _Float16 half8 __attribute__((ext_vector_type(8)));  // 8 fp16 (4 VGPR)
typedef __attribute__((ext_vector_type(4))) float fx4;       // MFMA f32 acc

// fast gelu: tanh/sigmoid form, exp2-folded. Max dev from exact-erf ~5e-4.
__device__ __forceinline__ float gelu_f(float x){
    float u = x*x;
    float a = x * fmaf(-0.1029443f, u, -2.3022083f);   // -2y*log2(e)
    float e = exp2f(a);                                 // e^{-2y}
    float r = __builtin_amdgcn_rcpf(1.0f + e);          // sigmoid(2y)
    return x * r;
}
__device__ __forceinline__ unsigned short f2h(float f){
    union { _Float16 h; unsigned short u; } c;
    c.h = (_Float16)f;
    return c.u;
}
__device__ __forceinline__ float h2f(unsigned short u){
    union { unsigned short u; _Float16 h; } c;
    c.u = u;
    return (float)c.h;
}

// ---------------- workspace layout (float-slot offsets) ----------------
// xh, tabB, tabT, mah, pwwh, w1h, cond, statsA/B, dftp, x0 — xT eliminated.
static const size_t OFF_XH     = 0;            // fp16 [128][64][4096]
static const size_t OFF_TABB   = 33554432;     // fp16 [64][4096]
static const size_t OFF_TABT   = 33685504;     // fp16 [4096][64] (x 1/64)
static const size_t OFF_MAH    = 33816576;     // fp16 [b][co][64]
static const size_t OFF_PWWH   = 34078720;
static const size_t OFF_W1H    = 34086912;
static const size_t OFF_COND   = 34091008;
static const size_t OFF_STATS  = 34099200;     // 16,384 (A)
static const size_t OFF_DFTP   = 34115584;     // 4,194,304
static const size_t OFF_X0     = 38309888;     // 524,288
static const size_t OFF_STATS2 = 38834176;     // 16,384 (B)
// end = 38,850,560 slots = 155.4 MB (< proven 157.4 MB footprint)

// ---------------- trig tables + weight fp16 conversion ----------------
__global__ void k_tab(unsigned short* __restrict__ tabB, unsigned short* __restrict__ tabT,
                      const float* __restrict__ pww, unsigned short* __restrict__ pwwh,
                      const float* __restrict__ pj1w, unsigned short* __restrict__ w1h){
    int t = blockIdx.x*256 + threadIdx.x;        // 262144
    if (t < 16384) pwwh[t] = f2h(pww[t]);
    if (t < 8192)  w1h[t]  = f2h(pj1w[t]);
    int m2 = t >> 12, n = t & 4095;
    int m = m2 & 31;
    int r = (m*n) & 4095;
    int r2 = (r >= 2048) ? (r - 4096) : r;       // fold to [-pi, pi)
    float a = (float)r2 * 1.5339807878856412e-3f;   // 2*pi/4096
    float v = (m2 >= 32) ? sinf(a) : cosf(a);
    tabB[(size_t)m2*4096 + n] = f2h(v);
    tabT[(size_t)n*64 + m2]   = f2h(v * 0.015625f);
}

// ---------------- conditioning MLP ----------------
__global__ __launch_bounds__(64) void k_cond(const float* __restrict__ instp,
        const float* __restrict__ w1, const float* __restrict__ b1,
        const float* __restrict__ w2, const float* __restrict__ b2,
        float* __restrict__ cond){
    int b = blockIdx.x, tid = threadIdx.x;
    __shared__ float ipl[8];
    __shared__ float tl[64];
    if (tid < 8) ipl[tid] = instp[b*8 + tid];
    __syncthreads();
    float s = b1[tid];
    #pragma unroll
    for (int k = 0; k < 8; ++k) s = fmaf(ipl[k], w1[k*64 + tid], s);
    tl[tid] = gelu_f(s);
    __syncthreads();
    float c = b2[tid];
    #pragma unroll 8
    for (int j = 0; j < 64; ++j) c = fmaf(tl[j], w2[j*64 + tid], c);
    cond[b*64 + tid] = c;
}

// ---------------- lift core: x0 = z @ lift_w + lb + cond (f32, 2 MB) ----------------
__global__ __launch_bounds__(256) void k_liftc(const float* __restrict__ z,
        const float* __restrict__ lw, const float* __restrict__ lb,
        const float* __restrict__ cond, float* __restrict__ x0){
    int b = blockIdx.x, q = blockIdx.y;
    int t = threadIdx.x;
    __shared__ float zl[128];
    if (t < 128) zl[t] = z[b*128 + t];
    __syncthreads();
    #pragma unroll
    for (int i = 0; i < 4; ++i){
        int e = q*1024 + i*256 + t;            // e = wc*64 + pos
        float s = lb[e];
        #pragma unroll 8
        for (int d = 0; d < 128; ++d)
            s = fmaf(zl[d], lw[(size_t)d*4096 + e], s);
        x0[(size_t)b*4096 + e] = s + cond[b*64 + (e >> 6)];
    }
}

// ---------------- prep: (interp | norm+gelu) -> x (LDS), fwd-DFT -> dftp --------
// MODE: 1 = norm+gelu from xh; 2 = inline linear-interp from x0 (layer 0).
// NO xT write anymore (pass3 rebuilds x itself).
template<int MODE>
__global__ __launch_bounds__(256) void k_prep(
        const unsigned short* __restrict__ xhp, const float* __restrict__ statsIn,
        const unsigned short* __restrict__ tabB, const float* __restrict__ x0,
        float* __restrict__ dftp)
{
    int b = blockIdx.x, ng = blockIdx.y;
    int t = threadIdx.x;
    int w = t >> 6, lane = t & 63;
    int lrow = lane & 15, g = lane >> 4;
    __shared__ __align__(16) unsigned short xl[2][4096];
    __shared__ float xs[(MODE == 2) ? 65*64 : 1];   // [ci][64+1 pad]
    int ci = t >> 2, nq = t & 3;
    float mu = 0.f, rs = 1.f;
    if (MODE == 1){
        float2 sr = *(const float2*)(statsIn + (size_t)(b*64+ci)*2);
        mu = sr.x * (1.f/4096.f);
        float var = fmaf(sr.y, 1.f/4096.f, -mu*mu);
        rs = rsqrtf(var + 1e-5f);
    }
    if (MODE == 2){
        const float* xb0 = x0 + (size_t)b*4096;
        #pragma unroll
        for (int i = 0; i < 16; ++i){
            int idx = i*256 + t;
            xs[(idx >> 6)*65 + (idx & 63)] = xb0[idx];
        }
        __syncthreads();
    }
    fx4 acc[4];
    #pragma unroll
    for (int i = 0; i < 4; ++i) acc[i] = (fx4){0.f,0.f,0.f,0.f};

    const unsigned short* hrow = xhp + ((size_t)(b*64+ci))*4096 + ng*512 + nq*16;

    uint4 cA, cB;
    if (MODE == 1){ cA = *(const uint4*)(hrow); cB = *(const uint4*)(hrow + 8); }
    for (int it = 0; it < 8; ++it){
        int n0 = ng*512 + it*64;
        char* xb = (char*)(&xl[it & 1][0]);
        uint4 nA, nB;
        if (MODE == 1 && it < 7){
            nA = *(const uint4*)(hrow + (it+1)*64);
            nB = *(const uint4*)(hrow + (it+1)*64 + 8);
        }
        unsigned int pk[8];
        if (MODE == 1){
            unsigned int hu[8] = {cA.x,cA.y,cA.z,cA.w,cB.x,cB.y,cB.z,cB.w};
            #pragma unroll
            for (int i = 0; i < 8; ++i){
                float f0 = h2f((unsigned short)(hu[i] & 0xFFFFu));
                float f1 = h2f((unsigned short)(hu[i] >> 16));
                f0 = gelu_f((f0 - mu)*rs);
                f1 = gelu_f((f1 - mu)*rs);
                pk[i] = (unsigned int)f2h(f0) | ((unsigned int)f2h(f1) << 16);
            }
        } else {
            const float* xr = xs + ci*65;
            #pragma unroll
            for (int i = 0; i < 8; ++i){
                float v[2];
                #pragma unroll
                for (int q = 0; q < 2; ++q){
                    int n = n0 + nq*16 + i*2 + q;
                    float src = (n + 0.5f)*0.015625f - 0.5f;
                    src = fminf(fmaxf(src, 0.0f), 63.0f);
                    int i0 = (int)src;
                    int i1 = (i0 + 1 > 63) ? 63 : (i0 + 1);
                    float wt = src - (float)i0;
                    v[q] = xr[i0] + wt*(xr[i1] - xr[i0]);
                }
                pk[i] = (unsigned int)f2h(v[0]) | ((unsigned int)f2h(v[1]) << 16);
            }
        }
        unsigned int base = (unsigned int)ci*128 + (unsigned int)nq*32;
        unsigned int sw = (unsigned int)((ci & 7) << 4);
        *(uint4*)(xb + ((base +  0) ^ sw)) = make_uint4(pk[0],pk[1],pk[2],pk[3]);
        *(uint4*)(xb + ((base + 16) ^ sw)) = make_uint4(pk[4],pk[5],pk[6],pk[7]);
        __syncthreads();

        {   // forward DFT MFMAs
            int m0 = w*16;
            #pragma unroll
            for (int ks = 0; ks < 2; ++ks){
                int kk = ks*32 + g*8;
                half8 af = *(const half8*)(tabB + (size_t)(m0 + lrow)*4096 + n0 + kk);
                #pragma unroll
                for (int ct = 0; ct < 4; ++ct){
                    int row = ct*16 + lrow;
                    unsigned int ba = ((unsigned int)row*128 + (unsigned int)kk*2)
                                      ^ (unsigned int)((row & 7) << 4);
                    half8 bf = *(const half8*)(xb + ba);
                    acc[ct] = __builtin_amdgcn_mfma_f32_16x16x32_f16(af, bf, acc[ct], 0, 0, 0);
                }
            }
        }
        if (MODE == 1 && it < 7){ cA = nA; cB = nB; }
    }
    {   // dftp [b][ng][ci][m2], float4 stores
        int m0 = w*16;
        #pragma unroll
        for (int ct = 0; ct < 4; ++ct){
            float4 v = make_float4(acc[ct][0], acc[ct][1], acc[ct][2], acc[ct][3]);
            *(float4*)(dftp + ((size_t)(b*8+ng)*64 + ct*16 + lrow)*64 + m0 + g*4) = v;
        }
    }
}

// ---------------- spectral mix (fused dftred + stats-target zero), co-split -------
__global__ __launch_bounds__(256) void k_mix(const float* __restrict__ dftp,
        const float* __restrict__ specw, unsigned short* __restrict__ mah,
        float* __restrict__ statsZero, int l){
    int b = blockIdx.x, coq = blockIdx.y, t = threadIdx.x;
    __shared__ float xm[64*64];              // [ci][64]: r | i
    if (t < 128) statsZero[b*128 + t] = 0.f;
    const float* dp = dftp + (size_t)b*8*4096;
    #pragma unroll
    for (int i = 0; i < 4; ++i){
        int e = i*1024 + t*4;
        float4 s = make_float4(0.f,0.f,0.f,0.f);
        #pragma unroll
        for (int ng = 0; ng < 8; ++ng){
            float4 v = *(const float4*)(dp + (size_t)ng*4096 + e);
            s.x += v.x; s.y += v.y; s.z += v.z; s.w += v.w;
        }
        if (e & 32){ s.x = -s.x; s.y = -s.y; s.z = -s.z; s.w = -s.w; }
        *(float4*)(xm + e) = s;
    }
    __syncthreads();
    int mq = t & 3, ciq = (t >> 2) & 3, co_l = t >> 4;
    int co = coq*16 + co_l;
    float yr[8] = {0,0,0,0,0,0,0,0}, yi[8] = {0,0,0,0,0,0,0,0};
    const float* wbase = specw + (size_t)l*262144 + (size_t)co*64 + mq*16;
    #pragma unroll 4
    for (int cil = 0; cil < 16; ++cil){
        int ci = ciq*16 + cil;
        const float* wp = wbase + (size_t)ci*4096;
        float4 w0 = *(const float4*)(wp);
        float4 w1v = *(const float4*)(wp + 4);
        float4 w2v = *(const float4*)(wp + 8);
        float4 w3v = *(const float4*)(wp + 12);
        const float* xc = xm + ci*64 + mq*8;
        float4 r0 = *(const float4*)(xc);
        float4 r1 = *(const float4*)(xc + 4);
        float4 i0 = *(const float4*)(xc + 32);
        float4 i1 = *(const float4*)(xc + 36);
        float wr[8] = {w0.x,w0.z,w1v.x,w1v.z,w2v.x,w2v.z,w3v.x,w3v.z};
        float wi[8] = {w0.y,w0.w,w1v.y,w1v.w,w2v.y,w2v.w,w3v.y,w3v.w};
        float xr[8] = {r0.x,r0.y,r0.z,r0.w,r1.x,r1.y,r1.z,r1.w};
        float xi[8] = {i0.x,i0.y,i0.z,i0.w,i1.x,i1.y,i1.z,i1.w};
        #pragma unroll
        for (int mm = 0; mm < 8; ++mm){
            yr[mm] = fmaf(xr[mm], wr[mm], fmaf(-xi[mm], wi[mm], yr[mm]));
            yi[mm] = fmaf(xr[mm], wi[mm], fmaf( xi[mm], wr[mm], yi[mm]));
        }
    }
    #pragma unroll
    for (int mm = 0; mm < 8; ++mm){
        yr[mm] += __shfl_xor(yr[mm], 4); yr[mm] += __shfl_xor(yr[mm], 8);
        yi[mm] += __shfl_xor(yi[mm], 4); yi[mm] += __shfl_xor(yi[mm], 8);
    }
    if (ciq == 0){
        unsigned short* mb = mah + (size_t)(b*64 + co)*64;
        unsigned int pr[4], pi[4];
        #pragma unroll
        for (int p = 0; p < 4; ++p){
            int m0 = mq*8 + 2*p;
            float s0 = (m0 == 0) ? 0.015625f : 0.03125f;
            pr[p] = (unsigned int)f2h(s0*yr[2*p]) | ((unsigned int)f2h(0.03125f*yr[2*p+1]) << 16);
            pi[p] = (unsigned int)f2h(-0.03125f*yi[2*p]) | ((unsigned int)f2h(-0.03125f*yi[2*p+1]) << 16);
        }
        *(uint4*)(mb + mq*8)      = make_uint4(pr[0],pr[1],pr[2],pr[3]);
        *(uint4*)(mb + 32 + mq*8) = make_uint4(pi[0],pi[1],pi[2],pi[3]);
    }
}

// ---------------- pass3: x rebuilt from xh inline, pw+iDFT MFMA -> h (in place) ----
// Per 64-n tile: stage(norm+gelu|interp) -> LDS1 [ci][n] swz -> transpose -> LDS2
// [n][ci] swz -> vector A-frags. Bv (weights/mah) held across tiles. In-place xh.
template<int MODE>
__global__ __launch_bounds__(256, 2) void k_pass3(
        const unsigned short* __restrict__ xhp, const float* __restrict__ statsIn,
        const float* __restrict__ x0, const unsigned short* __restrict__ tabT,
        const unsigned short* __restrict__ pwwh, const float* __restrict__ pwb,
        const unsigned short* __restrict__ mah, unsigned short* __restrict__ xh,
        float* __restrict__ statsOut, int lay)
{
    int b = blockIdx.x, ng = blockIdx.y;
    int t = threadIdx.x, w = t >> 6, lane = t & 63;
    int lrow = lane & 15, g = lane >> 4;
    __shared__ __align__(16) unsigned short xl1[4096];   // [ci][n] swizzled
    __shared__ __align__(16) unsigned short xl2[4096];   // [n][ci] swizzled
    __shared__ float xs[(MODE == 2) ? 65*64 : 1];
    __shared__ float sred[2][4][64];

    int ci = t >> 2, nq = t & 3;
    float mu = 0.f, rs = 1.f;
    if (MODE == 1){
        float2 sr = *(const float2*)(statsIn + (size_t)(b*64+ci)*2);
        mu = sr.x * (1.f/4096.f);
        float var = fmaf(sr.y, 1.f/4096.f, -mu*mu);
        rs = rsqrtf(var + 1e-5f);
    }
    if (MODE == 2){
        const float* xb0 = x0 + (size_t)b*4096;
        #pragma unroll
        for (int i = 0; i < 16; ++i){
            int idx = i*256 + t;
            xs[(idx >> 6)*65 + (idx & 63)] = xb0[idx];
        }
        __syncthreads();
    }
    half8 Bv[4][4];                          // [cot][ks], held
    #pragma unroll
    for (int cot = 0; cot < 4; ++cot){
        int co = cot*16 + lrow;
        #pragma unroll
        for (int ks = 0; ks < 4; ++ks){
            int k = ks*32 + g*8;
            const unsigned short* src = (k < 64)
                ? (pwwh + ((size_t)lay*64 + co)*64 + k)
                : (mah  + ((size_t)b*64 + co)*64 + (k - 64));
            Bv[cot][ks] = *(const half8*)src;
        }
    }
    float pb[4];
    #pragma unroll
    for (int cot = 0; cot < 4; ++cot) pb[cot] = pwb[lay*64 + cot*16 + lrow];
    float sS[4] = {0,0,0,0}, sQ[4] = {0,0,0,0};

    const unsigned short* hrow = xhp + ((size_t)(b*64+ci))*4096 + ng*512 + nq*16;
    uint4 cA, cB;
    if (MODE == 1){ cA = *(const uint4*)(hrow); cB = *(const uint4*)(hrow + 8); }

    for (int it = 0; it < 8; ++it){
        int n0 = ng*512 + it*64;
        uint4 nA, nB;
        if (MODE == 1 && it < 7){
            nA = *(const uint4*)(hrow + (it+1)*64);
            nB = *(const uint4*)(hrow + (it+1)*64 + 8);
        }
        unsigned int pk[8];
        if (MODE == 1){
            unsigned int hu[8] = {cA.x,cA.y,cA.z,cA.w,cB.x,cB.y,cB.z,cB.w};
            #pragma unroll
            for (int i = 0; i < 8; ++i){
                float f0 = h2f((unsigned short)(hu[i] & 0xFFFFu));
                float f1 = h2f((unsigned short)(hu[i] >> 16));
                f0 = gelu_f((f0 - mu)*rs);
                f1 = gelu_f((f1 - mu)*rs);
                pk[i] = (unsigned int)f2h(f0) | ((unsigned int)f2h(f1) << 16);
            }
        } else {
            const float* xr = xs + ci*65;
            #pragma unroll
            for (int i = 0; i < 8; ++i){
                float v[2];
                #pragma unroll
                for (int q = 0; q < 2; ++q){
                    int n = n0 + nq*16 + i*2 + q;
                    float src = (n + 0.5f)*0.015625f - 0.5f;
                    src = fminf(fmaxf(src, 0.0f), 63.0f);
                    int i0 = (int)src;
                    int i1 = (i0 + 1 > 63) ? 63 : (i0 + 1);
                    float wt = src - (float)i0;
                    v[q] = xr[i0] + wt*(xr[i1] - xr[i0]);
                }
                pk[i] = (unsigned int)f2h(v[0]) | ((unsigned int)f2h(v[1]) << 16);
            }
        }
        unsigned int base = (unsigned int)ci*128 + (unsigned int)nq*32;
        unsigned int sw = (unsigned int)((ci & 7) << 4);
        *(uint4*)((char*)xl1 + ((base +  0) ^ sw)) = make_uint4(pk[0],pk[1],pk[2],pk[3]);
        *(uint4*)((char*)xl1 + ((base + 16) ^ sw)) = make_uint4(pk[4],pk[5],pk[6],pk[7]);
        __syncthreads();

        {   // transpose LDS1 [ci][n] -> LDS2 [n][ci] (both swizzled)
            int n = t & 63, coq = t >> 6;
            unsigned int opk[8];
            #pragma unroll
            for (int i = 0; i < 8; ++i){
                int r0 = coq*16 + 2*i, r1 = r0 + 1;
                unsigned int a0 = ((unsigned int)r0*128 + (unsigned int)n*2)
                                  ^ (unsigned int)((r0 & 7) << 4);
                unsigned int a1 = ((unsigned int)r1*128 + (unsigned int)n*2)
                                  ^ (unsigned int)((r1 & 7) << 4);
                unsigned short v0 = *(const unsigned short*)((const char*)xl1 + a0);
                unsigned short v1 = *(const unsigned short*)((const char*)xl1 + a1);
                opk[i] = (unsigned int)v0 | ((unsigned int)v1 << 16);
            }
            unsigned int b0 = (unsigned int)n*128 + (unsigned int)coq*32;
            unsigned int swn = (unsigned int)((n & 7) << 4);
            *(uint4*)((char*)xl2 + ((b0 +  0) ^ swn)) = make_uint4(opk[0],opk[1],opk[2],opk[3]);
            *(uint4*)((char*)xl2 + ((b0 + 16) ^ swn)) = make_uint4(opk[4],opk[5],opk[6],opk[7]);
        }
        __syncthreads();

        // MFMA: wave w owns n rows [w*16, w*16+16) of this 64-tile
        int nl = w*16 + lrow;
        unsigned int swa = (unsigned int)((nl & 7) << 4);
        half8 Af[4];
        Af[0] = *(const half8*)((const char*)xl2 + (((unsigned int)nl*128 +  0 + g*16) ^ swa));
        Af[1] = *(const half8*)((const char*)xl2 + (((unsigned int)nl*128 + 64 + g*16) ^ swa));
        {
            const unsigned short* tb = tabT + (size_t)(n0 + nl)*64 + g*8;
            Af[2] = *(const half8*)(tb);
            Af[3] = *(const half8*)(tb + 32);
        }
        fx4 acc[4];
        #pragma unroll
        for (int i = 0; i < 4; ++i) acc[i] = (fx4){0.f,0.f,0.f,0.f};
        #pragma unroll
        for (int ks = 0; ks < 4; ++ks)
            #pragma unroll
            for (int cot = 0; cot < 4; ++cot)
                acc[cot] = __builtin_amdgcn_mfma_f32_16x16x32_f16(Af[ks], Bv[cot][ks], acc[cot], 0, 0, 0);

        // epilogue: h = acc + bias; packed uint2 store; stats accumulate
        #pragma unroll
        for (int cot = 0; cot < 4; ++cot){
            int co = cot*16 + lrow;
            unsigned short* hr = xh + ((size_t)(b*64+co))*4096;
            float h0 = acc[cot][0] + pb[cot];
            float h1 = acc[cot][1] + pb[cot];
            float h2 = acc[cot][2] + pb[cot];
            float h3 = acc[cot][3] + pb[cot];
            uint2 pk2;
            pk2.x = (unsigned int)f2h(h0) | ((unsigned int)f2h(h1) << 16);
            pk2.y = (unsigned int)f2h(h2) | ((unsigned int)f2h(h3) << 16);
            *(uint2*)(hr + n0 + w*16 + g*4) = pk2;
            sS[cot] += (h0 + h1) + (h2 + h3);
            float q = h0*h0;
            q = fmaf(h1, h1, q); q = fmaf(h2, h2, q); q = fmaf(h3, h3, q);
            sQ[cot] += q;
        }
        if (MODE == 1 && it < 7){ cA = nA; cB = nB; }
    }
    #pragma unroll
    for (int cot = 0; cot < 4; ++cot){
        float s = sS[cot], q = sQ[cot];
        s += __shfl_xor(s, 16); q += __shfl_xor(q, 16);
        s += __shfl_xor(s, 32); q += __shfl_xor(q, 32);
        if (g == 0){
            sred[0][w][cot*16 + lrow] = s;
            sred[1][w][cot*16 + lrow] = q;
        }
    }
    __syncthreads();
    if (t < 64){
        float S = 0.f, Q = 0.f;
        #pragma unroll
        for (int ww = 0; ww < 4; ++ww){ S += sred[0][ww][t]; Q += sred[1][ww][t]; }
        atomicAdd(statsOut + (size_t)(b*64+t)*2,     S);
        atomicAdd(statsOut + (size_t)(b*64+t)*2 + 1, Q);
    }
}

// ---------------- fused norm+gelu+projection head (LDS2 transpose, vector B) -----
__global__ __launch_bounds__(256) void k_proj2(
        const unsigned short* __restrict__ xhp, const float* __restrict__ statsIn,
        const unsigned short* __restrict__ w1h, const float* __restrict__ b1,
        const float* __restrict__ w2, const float* __restrict__ b2,
        float* __restrict__ out)
{
    int b = blockIdx.x, ng = blockIdx.y;
    int t = threadIdx.x, w = t >> 6, lane = t & 63;
    int lrow = lane & 15, g = lane >> 4;
    int o2h = w & 1, nhalf = w >> 1;
    __shared__ __align__(16) unsigned short xl1[4096];
    __shared__ __align__(16) unsigned short xl2[4096];
    __shared__ float sred[2][2][2][2][16];   // [buf][nhalf][nt][o2h][lrow]

    int ci = t >> 2, nq = t & 3;
    float2 sr = *(const float2*)(statsIn + (size_t)(b*64+ci)*2);
    float mu = sr.x * (1.f/4096.f);
    float var = fmaf(sr.y, 1.f/4096.f, -mu*mu);
    float rs = rsqrtf(var + 1e-5f);
    const unsigned short* hrow = xhp + ((size_t)(b*64+ci))*4096 + ng*512 + nq*16;

    half8 A[4][2];
    #pragma unroll
    for (int ot = 0; ot < 4; ++ot)
        #pragma unroll
        for (int ks = 0; ks < 2; ++ks)
            A[ot][ks] = *(const half8*)(w1h + (size_t)(o2h*64 + ot*16 + lrow)*64 + ks*32 + g*8);
    float bb[16], wv[16];
    #pragma unroll
    for (int ot = 0; ot < 4; ++ot)
        #pragma unroll
        for (int j = 0; j < 4; ++j){
            int o2 = o2h*64 + ot*16 + g*4 + j;
            bb[ot*4+j] = b1[o2];
            wv[ot*4+j] = w2[o2];
        }
    float bias2 = b2[0];

    uint4 cA = *(const uint4*)(hrow);
    uint4 cB = *(const uint4*)(hrow + 8);
    for (int it = 0; it < 8; ++it){
        uint4 nA, nB;
        if (it < 7){
            nA = *(const uint4*)(hrow + (it+1)*64);
            nB = *(const uint4*)(hrow + (it+1)*64 + 8);
        }
        unsigned int pk[8];
        {
            unsigned int hu[8] = {cA.x,cA.y,cA.z,cA.w,cB.x,cB.y,cB.z,cB.w};
            #pragma unroll
            for (int i = 0; i < 8; ++i){
                float f0 = h2f((unsigned short)(hu[i] & 0xFFFFu));
                float f1 = h2f((unsigned short)(hu[i] >> 16));
                f0 = gelu_f((f0 - mu)*rs);
                f1 = gelu_f((f1 - mu)*rs);
                pk[i] = (unsigned int)f2h(f0) | ((unsigned int)f2h(f1) << 16);
            }
        }
        unsigned int base = (unsigned int)ci*128 + (unsigned int)nq*32;
        unsigned int sw = (unsigned int)((ci & 7) << 4);
        *(uint4*)((char*)xl1 + ((base +  0) ^ sw)) = make_uint4(pk[0],pk[1],pk[2],pk[3]);
        *(uint4*)((char*)xl1 + ((base + 16) ^ sw)) = make_uint4(pk[4],pk[5],pk[6],pk[7]);
        __syncthreads();

        {   // transpose LDS1 -> LDS2
            int n = t & 63, coq = t >> 6;
            unsigned int opk[8];
            #pragma unroll
            for (int i = 0; i < 8; ++i){
                int r0 = coq*16 + 2*i, r1 = r0 + 1;
                unsigned int a0 = ((unsigned int)r0*128 + (unsigned int)n*2)
                                  ^ (unsigned int)((r0 & 7) << 4);
                unsigned int a1 = ((unsigned int)r1*128 + (unsigned int)n*2)
                                  ^ (unsigned int)((r1 & 7) << 4);
                unsigned short v0 = *(const unsigned short*)((const char*)xl1 + a0);
                unsigned short v1 = *(const unsigned short*)((const char*)xl1 + a1);
                opk[i] = (unsigned int)v0 | ((unsigned int)v1 << 16);
            }
            unsigned int b0 = (unsigned int)n*128 + (unsigned int)coq*32;
            unsigned int swn = (unsigned int)((n & 7) << 4);
            *(uint4*)((char*)xl2 + ((b0 +  0) ^ swn)) = make_uint4(opk[0],opk[1],opk[2],opk[3]);
            *(uint4*)((char*)xl2 + ((b0 + 16) ^ swn)) = make_uint4(opk[4],opk[5],opk[6],opk[7]);
        }
        __syncthreads();

        // out-store for previous iter
        if (it > 0 && t < 64){
            int nh = t >> 5, rem = t & 31, ntf = rem >> 4, cl = rem & 15;
            out[(size_t)b*4096 + ng*512 + (it-1)*64 + t] =
                sred[(it-1)&1][nh][ntf][0][cl] + sred[(it-1)&1][nh][ntf][1][cl] + bias2;
        }

        // MFMA: vector B-frags from LDS2
        #pragma unroll
        for (int nt = 0; nt < 2; ++nt){
            int n_l = nhalf*32 + nt*16 + lrow;
            unsigned int swa = (unsigned int)((n_l & 7) << 4);
            half8 Bf[2];
            Bf[0] = *(const half8*)((const char*)xl2 + (((unsigned int)n_l*128 +  0 + g*16) ^ swa));
            Bf[1] = *(const half8*)((const char*)xl2 + (((unsigned int)n_l*128 + 64 + g*16) ^ swa));
            fx4 acc[4];
            #pragma unroll
            for (int i = 0; i < 4; ++i) acc[i] = (fx4){0.f,0.f,0.f,0.f};
            #pragma unroll
            for (int ks = 0; ks < 2; ++ks)
                #pragma unroll
                for (int ot = 0; ot < 4; ++ot)
                    acc[ot] = __builtin_amdgcn_mfma_f32_16x16x32_f16(A[ot][ks], Bf[ks], acc[ot], 0, 0, 0);
            float p = 0.f;
            #pragma unroll
            for (int ot = 0; ot < 4; ++ot)
                #pragma unroll
                for (int j = 0; j < 4; ++j)
                    p = fmaf(wv[ot*4+j], gelu_f(acc[ot][j] + bb[ot*4+j]), p);
            p += __shfl_xor(p, 16); p += __shfl_xor(p, 32);
            if (lane < 16) sred[it & 1][nhalf][nt][o2h][lane] = p;
        }
        if (it < 7){ cA = nA; cB = nB; }
    }
    __syncthreads();
    if (t < 64){
        int nh = t >> 5, rem = t & 31, ntf = rem >> 4, cl = rem & 15;
        out[(size_t)b*4096 + ng*512 + 7*64 + t] =
            sred[1][nh][ntf][0][cl] + sred[1][nh][ntf][1][cl] + bias2;
    }
}

// ---------------- launch ----------------
extern "C" void kernel_launch(void* const* d_in, const int* in_sizes, int n_in,
                              void* d_out, int out_size, void* d_ws, size_t ws_size,
                              hipStream_t stream) {
    (void)in_sizes; (void)n_in; (void)out_size; (void)ws_size;
    const float* z      = (const float*)d_in[0];
    const float* instp  = (const float*)d_in[1];
    const float* lift_w = (const float*)d_in[2];
    const float* lift_b = (const float*)d_in[3];
    const float* iw1    = (const float*)d_in[4];
    const float* ib1    = (const float*)d_in[5];
    const float* iw2    = (const float*)d_in[6];
    const float* ib2    = (const float*)d_in[7];
    const float* specw  = (const float*)d_in[8];
    const float* pww    = (const float*)d_in[9];
    const float* pwb    = (const float*)d_in[10];
    const float* pj1w   = (const float*)d_in[11];
    const float* pj1b   = (const float*)d_in[12];
    const float* pj2w   = (const float*)d_in[13];
    const float* pj2b   = (const float*)d_in[14];

    float* ws = (float*)d_ws;
    unsigned short* xh    = (unsigned short*)(ws + OFF_XH);
    unsigned short* tabB  = (unsigned short*)(ws + OFF_TABB);
    unsigned short* tabT  = (unsigned short*)(ws + OFF_TABT);
    unsigned short* mah   = (unsigned short*)(ws + OFF_MAH);
    unsigned short* pwwh  = (unsigned short*)(ws + OFF_PWWH);
    unsigned short* w1h   = (unsigned short*)(ws + OFF_W1H);
    float* cond   = ws + OFF_COND;
    float* dftp   = ws + OFF_DFTP;
    float* x0     = ws + OFF_X0;
    float* sbuf[2] = { ws + OFF_STATS, ws + OFF_STATS2 };
    float* out    = (float*)d_out;

    k_tab  <<<dim3(1024),  dim3(256), 0, stream>>>(tabB, tabT, pww, pwwh, pj1w, w1h);
    k_cond <<<dim3(128),   dim3(64),  0, stream>>>(instp, iw1, ib1, iw2, ib2, cond);
    k_liftc<<<dim3(128,4), dim3(256), 0, stream>>>(z, lift_w, lift_b, cond, x0);

    for (int l = 0; l < 4; ++l){
        float* sIn  = sbuf[l & 1];
        float* sOut = sbuf[(l + 1) & 1];
        if (l == 0)
            k_prep<2><<<dim3(128,8), dim3(256), 0, stream>>>(xh, sIn, tabB, x0, dftp);
        else
            k_prep<1><<<dim3(128,8), dim3(256), 0, stream>>>(xh, sIn, tabB, x0, dftp);
        k_mix<<<dim3(128,4), dim3(256), 0, stream>>>(dftp, specw, mah, sOut, l);
        if (l == 0)
            k_pass3<2><<<dim3(128,8), dim3(256), 0, stream>>>(xh, sIn, x0, tabT, pwwh, pwb, mah, xh, sOut, l);
        else
            k_pass3<1><<<dim3(128,8), dim3(256), 0, stream>>>(xh, sIn, x0, tabT, pwwh, pwb, mah, xh, sOut, l);
    }
    k_proj2<<<dim3(128,8), dim3(256), 0, stream>>>(xh, sbuf[0], w1h, pj1b, pj2w, pj2b, out);
}

// Round 17
// 417.158 us; speedup vs baseline: 1.2204x; 1.0064x over previous
//
#include <hip/hip_runtime.h>
#include <math.h>

// B=128, W=64, L=4096, MODES=32, N_LAYERS=4

typedef _Float16 half8 __attribute__((ext_vector_type(8)));  // 8 fp16 (4 VGPR)
typedef __attribute__((ext_vector_type(4))) float fx4;       // MFMA f32 acc

// fast gelu: tanh/sigmoid form, exp2-folded. Max dev from exact-erf ~5e-4.
__device__ __forceinline__ float gelu_f(float x){
    float u = x*x;
    float a = x * fmaf(-0.1029443f, u, -2.3022083f);   // -2y*log2(e)
    float e = exp2f(a);                                 // e^{-2y}
    float r = __builtin_amdgcn_rcpf(1.0f + e);          // sigmoid(2y)
    return x * r;
}
__device__ __forceinline__ unsigned short f2h(float f){
    union { _Float16 h; unsigned short u; } c;
    c.h = (_Float16)f;
    return c.u;
}
__device__ __forceinline__ float h2f(unsigned short u){
    union { unsigned short u; _Float16 h; } c;
    c.u = u;
    return (float)c.h;
}

// ---------------- workspace layout (float-slot offsets) ----------------
static const size_t OFF_XH     = 0;            // fp16 [128][64][4096]
static const size_t OFF_TABB   = 33554432;     // fp16 [64][4096]
static const size_t OFF_TABT   = 33685504;     // fp16 [4096][64] (x 1/64)
static const size_t OFF_MAH    = 33816576;     // fp16 [b][co][64]
static const size_t OFF_PWWH   = 34078720;
static const size_t OFF_W1H    = 34086912;
static const size_t OFF_COND   = 34091008;
static const size_t OFF_STATS  = 34099200;     // 16,384 (A)
static const size_t OFF_DFTP   = 34115584;     // 4,194,304
static const size_t OFF_X0     = 38309888;     // 524,288
static const size_t OFF_STATS2 = 38834176;     // 16,384 (B)
// end = 38,850,560 slots = 155.4 MB (< proven 157.4 MB footprint)

// ---------------- trig tables + weight fp16 conversion ----------------
__global__ void k_tab(unsigned short* __restrict__ tabB, unsigned short* __restrict__ tabT,
                      const float* __restrict__ pww, unsigned short* __restrict__ pwwh,
                      const float* __restrict__ pj1w, unsigned short* __restrict__ w1h){
    int t = blockIdx.x*256 + threadIdx.x;        // 262144
    if (t < 16384) pwwh[t] = f2h(pww[t]);
    if (t < 8192)  w1h[t]  = f2h(pj1w[t]);
    int m2 = t >> 12, n = t & 4095;
    int m = m2 & 31;
    int r = (m*n) & 4095;
    int r2 = (r >= 2048) ? (r - 4096) : r;       // fold to [-pi, pi)
    float a = (float)r2 * 1.5339807878856412e-3f;   // 2*pi/4096
    float v = (m2 >= 32) ? sinf(a) : cosf(a);
    tabB[(size_t)m2*4096 + n] = f2h(v);
    tabT[(size_t)n*64 + m2]   = f2h(v * 0.015625f);
}

// ---------------- conditioning MLP ----------------
__global__ __launch_bounds__(64) void k_cond(const float* __restrict__ instp,
        const float* __restrict__ w1, const float* __restrict__ b1,
        const float* __restrict__ w2, const float* __restrict__ b2,
        float* __restrict__ cond){
    int b = blockIdx.x, tid = threadIdx.x;
    __shared__ float ipl[8];
    __shared__ float tl[64];
    if (tid < 8) ipl[tid] = instp[b*8 + tid];
    __syncthreads();
    float s = b1[tid];
    #pragma unroll
    for (int k = 0; k < 8; ++k) s = fmaf(ipl[k], w1[k*64 + tid], s);
    tl[tid] = gelu_f(s);
    __syncthreads();
    float c = b2[tid];
    #pragma unroll 8
    for (int j = 0; j < 64; ++j) c = fmaf(tl[j], w2[j*64 + tid], c);
    cond[b*64 + tid] = c;
}

// ---------------- lift core: x0 = z @ lift_w + lb + cond (f32, 2 MB) ----------------
__global__ __launch_bounds__(256) void k_liftc(const float* __restrict__ z,
        const float* __restrict__ lw, const float* __restrict__ lb,
        const float* __restrict__ cond, float* __restrict__ x0){
    int b = blockIdx.x, q = blockIdx.y;
    int t = threadIdx.x;
    __shared__ float zl[128];
    if (t < 128) zl[t] = z[b*128 + t];
    __syncthreads();
    #pragma unroll
    for (int i = 0; i < 4; ++i){
        int e = q*1024 + i*256 + t;            // e = wc*64 + pos
        float s = lb[e];
        #pragma unroll 8
        for (int d = 0; d < 128; ++d)
            s = fmaf(zl[d], lw[(size_t)d*4096 + e], s);
        x0[(size_t)b*4096 + e] = s + cond[b*64 + (e >> 6)];
    }
}

// ---------------- prep: (interp | norm+gelu) -> x (LDS), fwd-DFT -> dftp --------
// MODE: 1 = norm+gelu from xh; 2 = inline linear-interp from x0 (layer 0).
template<int MODE>
__global__ __launch_bounds__(256) void k_prep(
        const unsigned short* __restrict__ xhp, const float* __restrict__ statsIn,
        const unsigned short* __restrict__ tabB, const float* __restrict__ x0,
        float* __restrict__ dftp)
{
    int b = blockIdx.x, ng = blockIdx.y;
    int t = threadIdx.x;
    int w = t >> 6, lane = t & 63;
    int lrow = lane & 15, g = lane >> 4;
    __shared__ __align__(16) unsigned short xl[2][4096];
    __shared__ float xs[(MODE == 2) ? 65*64 : 1];   // [ci][64+1 pad]
    int ci = t >> 2, nq = t & 3;
    float mu = 0.f, rs = 1.f;
    if (MODE == 1){
        float2 sr = *(const float2*)(statsIn + (size_t)(b*64+ci)*2);
        mu = sr.x * (1.f/4096.f);
        float var = fmaf(sr.y, 1.f/4096.f, -mu*mu);
        rs = rsqrtf(var + 1e-5f);
    }
    if (MODE == 2){
        const float* xb0 = x0 + (size_t)b*4096;
        #pragma unroll
        for (int i = 0; i < 16; ++i){
            int idx = i*256 + t;
            xs[(idx >> 6)*65 + (idx & 63)] = xb0[idx];
        }
        __syncthreads();
    }
    fx4 acc[4];
    #pragma unroll
    for (int i = 0; i < 4; ++i) acc[i] = (fx4){0.f,0.f,0.f,0.f};

    const unsigned short* hrow = xhp + ((size_t)(b*64+ci))*4096 + ng*512 + nq*16;

    uint4 cA, cB;
    if (MODE == 1){ cA = *(const uint4*)(hrow); cB = *(const uint4*)(hrow + 8); }
    for (int it = 0; it < 8; ++it){
        int n0 = ng*512 + it*64;
        char* xb = (char*)(&xl[it & 1][0]);
        uint4 nA, nB;
        if (MODE == 1 && it < 7){
            nA = *(const uint4*)(hrow + (it+1)*64);
            nB = *(const uint4*)(hrow + (it+1)*64 + 8);
        }
        unsigned int pk[8];
        if (MODE == 1){
            unsigned int hu[8] = {cA.x,cA.y,cA.z,cA.w,cB.x,cB.y,cB.z,cB.w};
            #pragma unroll
            for (int i = 0; i < 8; ++i){
                float f0 = h2f((unsigned short)(hu[i] & 0xFFFFu));
                float f1 = h2f((unsigned short)(hu[i] >> 16));
                f0 = gelu_f((f0 - mu)*rs);
                f1 = gelu_f((f1 - mu)*rs);
                pk[i] = (unsigned int)f2h(f0) | ((unsigned int)f2h(f1) << 16);
            }
        } else {
            const float* xr = xs + ci*65;
            #pragma unroll
            for (int i = 0; i < 8; ++i){
                float v[2];
                #pragma unroll
                for (int q = 0; q < 2; ++q){
                    int n = n0 + nq*16 + i*2 + q;
                    float src = (n + 0.5f)*0.015625f - 0.5f;
                    src = fminf(fmaxf(src, 0.0f), 63.0f);
                    int i0 = (int)src;
                    int i1 = (i0 + 1 > 63) ? 63 : (i0 + 1);
                    float wt = src - (float)i0;
                    v[q] = xr[i0] + wt*(xr[i1] - xr[i0]);
                }
                pk[i] = (unsigned int)f2h(v[0]) | ((unsigned int)f2h(v[1]) << 16);
            }
        }
        unsigned int base = (unsigned int)ci*128 + (unsigned int)nq*32;
        unsigned int sw = (unsigned int)((ci & 7) << 4);
        *(uint4*)(xb + ((base +  0) ^ sw)) = make_uint4(pk[0],pk[1],pk[2],pk[3]);
        *(uint4*)(xb + ((base + 16) ^ sw)) = make_uint4(pk[4],pk[5],pk[6],pk[7]);
        __syncthreads();

        {   // forward DFT MFMAs
            int m0 = w*16;
            #pragma unroll
            for (int ks = 0; ks < 2; ++ks){
                int kk = ks*32 + g*8;
                half8 af = *(const half8*)(tabB + (size_t)(m0 + lrow)*4096 + n0 + kk);
                #pragma unroll
                for (int ct = 0; ct < 4; ++ct){
                    int row = ct*16 + lrow;
                    unsigned int ba = ((unsigned int)row*128 + (unsigned int)kk*2)
                                      ^ (unsigned int)((row & 7) << 4);
                    half8 bf = *(const half8*)(xb + ba);
                    acc[ct] = __builtin_amdgcn_mfma_f32_16x16x32_f16(af, bf, acc[ct], 0, 0, 0);
                }
            }
        }
        if (MODE == 1 && it < 7){ cA = nA; cB = nB; }
    }
    {   // dftp [b][ng][ci][m2], float4 stores
        int m0 = w*16;
        #pragma unroll
        for (int ct = 0; ct < 4; ++ct){
            float4 v = make_float4(acc[ct][0], acc[ct][1], acc[ct][2], acc[ct][3]);
            *(float4*)(dftp + ((size_t)(b*8+ng)*64 + ct*16 + lrow)*64 + m0 + g*4) = v;
        }
    }
}

// ---------------- spectral mix (fused dftred + stats-target zero), co-split -------
__global__ __launch_bounds__(256) void k_mix(const float* __restrict__ dftp,
        const float* __restrict__ specw, unsigned short* __restrict__ mah,
        float* __restrict__ statsZero, int l){
    int b = blockIdx.x, coq = blockIdx.y, t = threadIdx.x;
    __shared__ float xm[64*64];              // [ci][64]: r | i
    if (t < 128) statsZero[b*128 + t] = 0.f;
    const float* dp = dftp + (size_t)b*8*4096;
    #pragma unroll
    for (int i = 0; i < 4; ++i){
        int e = i*1024 + t*4;
        float4 s = make_float4(0.f,0.f,0.f,0.f);
        #pragma unroll
        for (int ng = 0; ng < 8; ++ng){
            float4 v = *(const float4*)(dp + (size_t)ng*4096 + e);
            s.x += v.x; s.y += v.y; s.z += v.z; s.w += v.w;
        }
        if (e & 32){ s.x = -s.x; s.y = -s.y; s.z = -s.z; s.w = -s.w; }
        *(float4*)(xm + e) = s;
    }
    __syncthreads();
    int mq = t & 3, ciq = (t >> 2) & 3, co_l = t >> 4;
    int co = coq*16 + co_l;
    float yr[8] = {0,0,0,0,0,0,0,0}, yi[8] = {0,0,0,0,0,0,0,0};
    const float* wbase = specw + (size_t)l*262144 + (size_t)co*64 + mq*16;
    #pragma unroll 4
    for (int cil = 0; cil < 16; ++cil){
        int ci = ciq*16 + cil;
        const float* wp = wbase + (size_t)ci*4096;
        float4 w0 = *(const float4*)(wp);
        float4 w1v = *(const float4*)(wp + 4);
        float4 w2v = *(const float4*)(wp + 8);
        float4 w3v = *(const float4*)(wp + 12);
        const float* xc = xm + ci*64 + mq*8;
        float4 r0 = *(const float4*)(xc);
        float4 r1 = *(const float4*)(xc + 4);
        float4 i0 = *(const float4*)(xc + 32);
        float4 i1 = *(const float4*)(xc + 36);
        float wr[8] = {w0.x,w0.z,w1v.x,w1v.z,w2v.x,w2v.z,w3v.x,w3v.z};
        float wi[8] = {w0.y,w0.w,w1v.y,w1v.w,w2v.y,w2v.w,w3v.y,w3v.w};
        float xr[8] = {r0.x,r0.y,r0.z,r0.w,r1.x,r1.y,r1.z,r1.w};
        float xi[8] = {i0.x,i0.y,i0.z,i0.w,i1.x,i1.y,i1.z,i1.w};
        #pragma unroll
        for (int mm = 0; mm < 8; ++mm){
            yr[mm] = fmaf(xr[mm], wr[mm], fmaf(-xi[mm], wi[mm], yr[mm]));
            yi[mm] = fmaf(xr[mm], wi[mm], fmaf( xi[mm], wr[mm], yi[mm]));
        }
    }
    #pragma unroll
    for (int mm = 0; mm < 8; ++mm){
        yr[mm] += __shfl_xor(yr[mm], 4); yr[mm] += __shfl_xor(yr[mm], 8);
        yi[mm] += __shfl_xor(yi[mm], 4); yi[mm] += __shfl_xor(yi[mm], 8);
    }
    if (ciq == 0){
        unsigned short* mb = mah + (size_t)(b*64 + co)*64;
        unsigned int pr[4], pi[4];
        #pragma unroll
        for (int p = 0; p < 4; ++p){
            int m0 = mq*8 + 2*p;
            float s0 = (m0 == 0) ? 0.015625f : 0.03125f;
            pr[p] = (unsigned int)f2h(s0*yr[2*p]) | ((unsigned int)f2h(0.03125f*yr[2*p+1]) << 16);
            pi[p] = (unsigned int)f2h(-0.03125f*yi[2*p]) | ((unsigned int)f2h(-0.03125f*yi[2*p+1]) << 16);
        }
        *(uint4*)(mb + mq*8)      = make_uint4(pr[0],pr[1],pr[2],pr[3]);
        *(uint4*)(mb + 32 + mq*8) = make_uint4(pi[0],pi[1],pi[2],pi[3]);
    }
}

// ---------------- pass3: x rebuilt from xh inline, pw+iDFT MFMA -> h (in place) ----
// grid (128 b, 16 ng of 256 n), 4 iters per block.
template<int MODE>
__global__ __launch_bounds__(256, 2) void k_pass3(
        const unsigned short* __restrict__ xhp, const float* __restrict__ statsIn,
        const float* __restrict__ x0, const unsigned short* __restrict__ tabT,
        const unsigned short* __restrict__ pwwh, const float* __restrict__ pwb,
        const unsigned short* __restrict__ mah, unsigned short* __restrict__ xh,
        float* __restrict__ statsOut, int lay)
{
    int b = blockIdx.x, ng = blockIdx.y;
    int t = threadIdx.x, w = t >> 6, lane = t & 63;
    int lrow = lane & 15, g = lane >> 4;
    __shared__ __align__(16) unsigned short xl1[4096];   // [ci][n] swizzled
    __shared__ __align__(16) unsigned short xl2[4096];   // [n][ci] swizzled
    __shared__ float xs[(MODE == 2) ? 65*64 : 1];
    __shared__ float sred[2][4][64];

    int ci = t >> 2, nq = t & 3;
    float mu = 0.f, rs = 1.f;
    if (MODE == 1){
        float2 sr = *(const float2*)(statsIn + (size_t)(b*64+ci)*2);
        mu = sr.x * (1.f/4096.f);
        float var = fmaf(sr.y, 1.f/4096.f, -mu*mu);
        rs = rsqrtf(var + 1e-5f);
    }
    if (MODE == 2){
        const float* xb0 = x0 + (size_t)b*4096;
        #pragma unroll
        for (int i = 0; i < 16; ++i){
            int idx = i*256 + t;
            xs[(idx >> 6)*65 + (idx & 63)] = xb0[idx];
        }
        __syncthreads();
    }
    half8 Bv[4][4];                          // [cot][ks], held
    #pragma unroll
    for (int cot = 0; cot < 4; ++cot){
        int co = cot*16 + lrow;
        #pragma unroll
        for (int ks = 0; ks < 4; ++ks){
            int k = ks*32 + g*8;
            const unsigned short* src = (k < 64)
                ? (pwwh + ((size_t)lay*64 + co)*64 + k)
                : (mah  + ((size_t)b*64 + co)*64 + (k - 64));
            Bv[cot][ks] = *(const half8*)src;
        }
    }
    float pb[4];
    #pragma unroll
    for (int cot = 0; cot < 4; ++cot) pb[cot] = pwb[lay*64 + cot*16 + lrow];
    float sS[4] = {0,0,0,0}, sQ[4] = {0,0,0,0};

    const unsigned short* hrow = xhp + ((size_t)(b*64+ci))*4096 + ng*256 + nq*16;
    uint4 cA, cB;
    if (MODE == 1){ cA = *(const uint4*)(hrow); cB = *(const uint4*)(hrow + 8); }

    for (int it = 0; it < 4; ++it){
        int n0 = ng*256 + it*64;
        uint4 nA, nB;
        if (MODE == 1 && it < 3){
            nA = *(const uint4*)(hrow + (it+1)*64);
            nB = *(const uint4*)(hrow + (it+1)*64 + 8);
        }
        unsigned int pk[8];
        if (MODE == 1){
            unsigned int hu[8] = {cA.x,cA.y,cA.z,cA.w,cB.x,cB.y,cB.z,cB.w};
            #pragma unroll
            for (int i = 0; i < 8; ++i){
                float f0 = h2f((unsigned short)(hu[i] & 0xFFFFu));
                float f1 = h2f((unsigned short)(hu[i] >> 16));
                f0 = gelu_f((f0 - mu)*rs);
                f1 = gelu_f((f1 - mu)*rs);
                pk[i] = (unsigned int)f2h(f0) | ((unsigned int)f2h(f1) << 16);
            }
        } else {
            const float* xr = xs + ci*65;
            #pragma unroll
            for (int i = 0; i < 8; ++i){
                float v[2];
                #pragma unroll
                for (int q = 0; q < 2; ++q){
                    int n = n0 + nq*16 + i*2 + q;
                    float src = (n + 0.5f)*0.015625f - 0.5f;
                    src = fminf(fmaxf(src, 0.0f), 63.0f);
                    int i0 = (int)src;
                    int i1 = (i0 + 1 > 63) ? 63 : (i0 + 1);
                    float wt = src - (float)i0;
                    v[q] = xr[i0] + wt*(xr[i1] - xr[i0]);
                }
                pk[i] = (unsigned int)f2h(v[0]) | ((unsigned int)f2h(v[1]) << 16);
            }
        }
        unsigned int base = (unsigned int)ci*128 + (unsigned int)nq*32;
        unsigned int sw = (unsigned int)((ci & 7) << 4);
        *(uint4*)((char*)xl1 + ((base +  0) ^ sw)) = make_uint4(pk[0],pk[1],pk[2],pk[3]);
        *(uint4*)((char*)xl1 + ((base + 16) ^ sw)) = make_uint4(pk[4],pk[5],pk[6],pk[7]);
        __syncthreads();

        {   // transpose LDS1 [ci][n] -> LDS2 [n][ci] (both swizzled)
            int n = t & 63, coq = t >> 6;
            unsigned int opk[8];
            #pragma unroll
            for (int i = 0; i < 8; ++i){
                int r0 = coq*16 + 2*i, r1 = r0 + 1;
                unsigned int a0 = ((unsigned int)r0*128 + (unsigned int)n*2)
                                  ^ (unsigned int)((r0 & 7) << 4);
                unsigned int a1 = ((unsigned int)r1*128 + (unsigned int)n*2)
                                  ^ (unsigned int)((r1 & 7) << 4);
                unsigned short v0 = *(const unsigned short*)((const char*)xl1 + a0);
                unsigned short v1 = *(const unsigned short*)((const char*)xl1 + a1);
                opk[i] = (unsigned int)v0 | ((unsigned int)v1 << 16);
            }
            unsigned int b0 = (unsigned int)n*128 + (unsigned int)coq*32;
            unsigned int swn = (unsigned int)((n & 7) << 4);
            *(uint4*)((char*)xl2 + ((b0 +  0) ^ swn)) = make_uint4(opk[0],opk[1],opk[2],opk[3]);
            *(uint4*)((char*)xl2 + ((b0 + 16) ^ swn)) = make_uint4(opk[4],opk[5],opk[6],opk[7]);
        }
        __syncthreads();

        // MFMA: wave w owns n rows [w*16, w*16+16) of this 64-tile
        int nl = w*16 + lrow;
        unsigned int swa = (unsigned int)((nl & 7) << 4);
        half8 Af[4];
        Af[0] = *(const half8*)((const char*)xl2 + (((unsigned int)nl*128 +  0 + g*16) ^ swa));
        Af[1] = *(const half8*)((const char*)xl2 + (((unsigned int)nl*128 + 64 + g*16) ^ swa));
        {
            const unsigned short* tb = tabT + (size_t)(n0 + nl)*64 + g*8;
            Af[2] = *(const half8*)(tb);
            Af[3] = *(const half8*)(tb + 32);
        }
        fx4 acc[4];
        #pragma unroll
        for (int i = 0; i < 4; ++i) acc[i] = (fx4){0.f,0.f,0.f,0.f};
        #pragma unroll
        for (int ks = 0; ks < 4; ++ks)
            #pragma unroll
            for (int cot = 0; cot < 4; ++cot)
                acc[cot] = __builtin_amdgcn_mfma_f32_16x16x32_f16(Af[ks], Bv[cot][ks], acc[cot], 0, 0, 0);

        // epilogue: h = acc + bias; packed uint2 store; stats accumulate
        #pragma unroll
        for (int cot = 0; cot < 4; ++cot){
            int co = cot*16 + lrow;
            unsigned short* hr = xh + ((size_t)(b*64+co))*4096;
            float h0 = acc[cot][0] + pb[cot];
            float h1 = acc[cot][1] + pb[cot];
            float h2 = acc[cot][2] + pb[cot];
            float h3 = acc[cot][3] + pb[cot];
            uint2 pk2;
            pk2.x = (unsigned int)f2h(h0) | ((unsigned int)f2h(h1) << 16);
            pk2.y = (unsigned int)f2h(h2) | ((unsigned int)f2h(h3) << 16);
            *(uint2*)(hr + n0 + w*16 + g*4) = pk2;
            sS[cot] += (h0 + h1) + (h2 + h3);
            float q = h0*h0;
            q = fmaf(h1, h1, q); q = fmaf(h2, h2, q); q = fmaf(h3, h3, q);
            sQ[cot] += q;
        }
        if (MODE == 1 && it < 3){ cA = nA; cB = nB; }
    }
    #pragma unroll
    for (int cot = 0; cot < 4; ++cot){
        float s = sS[cot], q = sQ[cot];
        s += __shfl_xor(s, 16); q += __shfl_xor(q, 16);
        s += __shfl_xor(s, 32); q += __shfl_xor(q, 32);
        if (g == 0){
            sred[0][w][cot*16 + lrow] = s;
            sred[1][w][cot*16 + lrow] = q;
        }
    }
    __syncthreads();
    if (t < 64){
        float S = 0.f, Q = 0.f;
        #pragma unroll
        for (int ww = 0; ww < 4; ++ww){ S += sred[0][ww][t]; Q += sred[1][ww][t]; }
        atomicAdd(statsOut + (size_t)(b*64+t)*2,     S);
        atomicAdd(statsOut + (size_t)(b*64+t)*2 + 1, Q);
    }
}

// ---------------- fused norm+gelu+projection head (LDS2 transpose, vector B) -----
// grid (128 b, 16 ng of 256 n), 4 iters per block.
__global__ __launch_bounds__(256) void k_proj2(
        const unsigned short* __restrict__ xhp, const float* __restrict__ statsIn,
        const unsigned short* __restrict__ w1h, const float* __restrict__ b1,
        const float* __restrict__ w2, const float* __restrict__ b2,
        float* __restrict__ out)
{
    int b = blockIdx.x, ng = blockIdx.y;
    int t = threadIdx.x, w = t >> 6, lane = t & 63;
    int lrow = lane & 15, g = lane >> 4;
    int o2h = w & 1, nhalf = w >> 1;
    __shared__ __align__(16) unsigned short xl1[4096];
    __shared__ __align__(16) unsigned short xl2[4096];
    __shared__ float sred[2][2][2][2][16];   // [buf][nhalf][nt][o2h][lrow]

    int ci = t >> 2, nq = t & 3;
    float2 sr = *(const float2*)(statsIn + (size_t)(b*64+ci)*2);
    float mu = sr.x * (1.f/4096.f);
    float var = fmaf(sr.y, 1.f/4096.f, -mu*mu);
    float rs = rsqrtf(var + 1e-5f);
    const unsigned short* hrow = xhp + ((size_t)(b*64+ci))*4096 + ng*256 + nq*16;

    half8 A[4][2];
    #pragma unroll
    for (int ot = 0; ot < 4; ++ot)
        #pragma unroll
        for (int ks = 0; ks < 2; ++ks)
            A[ot][ks] = *(const half8*)(w1h + (size_t)(o2h*64 + ot*16 + lrow)*64 + ks*32 + g*8);
    float bb[16], wv[16];
    #pragma unroll
    for (int ot = 0; ot < 4; ++ot)
        #pragma unroll
        for (int j = 0; j < 4; ++j){
            int o2 = o2h*64 + ot*16 + g*4 + j;
            bb[ot*4+j] = b1[o2];
            wv[ot*4+j] = w2[o2];
        }
    float bias2 = b2[0];

    uint4 cA = *(const uint4*)(hrow);
    uint4 cB = *(const uint4*)(hrow + 8);
    for (int it = 0; it < 4; ++it){
        uint4 nA, nB;
        if (it < 3){
            nA = *(const uint4*)(hrow + (it+1)*64);
            nB = *(const uint4*)(hrow + (it+1)*64 + 8);
        }
        unsigned int pk[8];
        {
            unsigned int hu[8] = {cA.x,cA.y,cA.z,cA.w,cB.x,cB.y,cB.z,cB.w};
            #pragma unroll
            for (int i = 0; i < 8; ++i){
                float f0 = h2f((unsigned short)(hu[i] & 0xFFFFu));
                float f1 = h2f((unsigned short)(hu[i] >> 16));
                f0 = gelu_f((f0 - mu)*rs);
                f1 = gelu_f((f1 - mu)*rs);
                pk[i] = (unsigned int)f2h(f0) | ((unsigned int)f2h(f1) << 16);
            }
        }
        unsigned int base = (unsigned int)ci*128 + (unsigned int)nq*32;
        unsigned int sw = (unsigned int)((ci & 7) << 4);
        *(uint4*)((char*)xl1 + ((base +  0) ^ sw)) = make_uint4(pk[0],pk[1],pk[2],pk[3]);
        *(uint4*)((char*)xl1 + ((base + 16) ^ sw)) = make_uint4(pk[4],pk[5],pk[6],pk[7]);
        __syncthreads();

        {   // transpose LDS1 -> LDS2
            int n = t & 63, coq = t >> 6;
            unsigned int opk[8];
            #pragma unroll
            for (int i = 0; i < 8; ++i){
                int r0 = coq*16 + 2*i, r1 = r0 + 1;
                unsigned int a0 = ((unsigned int)r0*128 + (unsigned int)n*2)
                                  ^ (unsigned int)((r0 & 7) << 4);
                unsigned int a1 = ((unsigned int)r1*128 + (unsigned int)n*2)
                                  ^ (unsigned int)((r1 & 7) << 4);
                unsigned short v0 = *(const unsigned short*)((const char*)xl1 + a0);
                unsigned short v1 = *(const unsigned short*)((const char*)xl1 + a1);
                opk[i] = (unsigned int)v0 | ((unsigned int)v1 << 16);
            }
            unsigned int b0 = (unsigned int)n*128 + (unsigned int)coq*32;
            unsigned int swn = (unsigned int)((n & 7) << 4);
            *(uint4*)((char*)xl2 + ((b0 +  0) ^ swn)) = make_uint4(opk[0],opk[1],opk[2],opk[3]);
            *(uint4*)((char*)xl2 + ((b0 + 16) ^ swn)) = make_uint4(opk[4],opk[5],opk[6],opk[7]);
        }
        __syncthreads();

        // out-store for previous iter
        if (it > 0 && t < 64){
            int nh = t >> 5, rem = t & 31, ntf = rem >> 4, cl = rem & 15;
            out[(size_t)b*4096 + ng*256 + (it-1)*64 + t] =
                sred[(it-1)&1][nh][ntf][0][cl] + sred[(it-1)&1][nh][ntf][1][cl] + bias2;
        }

        // MFMA: vector B-frags from LDS2
        #pragma unroll
        for (int nt = 0; nt < 2; ++nt){
            int n_l = nhalf*32 + nt*16 + lrow;
            unsigned int swa = (unsigned int)((n_l & 7) << 4);
            half8 Bf[2];
            Bf[0] = *(const half8*)((const char*)xl2 + (((unsigned int)n_l*128 +  0 + g*16) ^ swa));
            Bf[1] = *(const half8*)((const char*)xl2 + (((unsigned int)n_l*128 + 64 + g*16) ^ swa));
            fx4 acc[4];
            #pragma unroll
            for (int i = 0; i < 4; ++i) acc[i] = (fx4){0.f,0.f,0.f,0.f};
            #pragma unroll
            for (int ks = 0; ks < 2; ++ks)
                #pragma unroll
                for (int ot = 0; ot < 4; ++ot)
                    acc[ot] = __builtin_amdgcn_mfma_f32_16x16x32_f16(A[ot][ks], Bf[ks], acc[ot], 0, 0, 0);
            float p = 0.f;
            #pragma unroll
            for (int ot = 0; ot < 4; ++ot)
                #pragma unroll
                for (int j = 0; j < 4; ++j)
                    p = fmaf(wv[ot*4+j], gelu_f(acc[ot][j] + bb[ot*4+j]), p);
            p += __shfl_xor(p, 16); p += __shfl_xor(p, 32);
            if (lane < 16) sred[it & 1][nhalf][nt][o2h][lane] = p;
        }
        if (it < 3){ cA = nA; cB = nB; }
    }
    __syncthreads();
    if (t < 64){
        int nh = t >> 5, rem = t & 31, ntf = rem >> 4, cl = rem & 15;
        out[(size_t)b*4096 + ng*256 + 3*64 + t] =
            sred[1][nh][ntf][0][cl] + sred[1][nh][ntf][1][cl] + bias2;
    }
}

// ---------------- launch ----------------
extern "C" void kernel_launch(void* const* d_in, const int* in_sizes, int n_in,
                              void* d_out, int out_size, void* d_ws, size_t ws_size,
                              hipStream_t stream) {
    (void)in_sizes; (void)n_in; (void)out_size; (void)ws_size;
    const float* z      = (const float*)d_in[0];
    const float* instp  = (const float*)d_in[1];
    const float* lift_w = (const float*)d_in[2];
    const float* lift_b = (const float*)d_in[3];
    const float* iw1    = (const float*)d_in[4];
    const float* ib1    = (const float*)d_in[5];
    const float* iw2    = (const float*)d_in[6];
    const float* ib2    = (const float*)d_in[7];
    const float* specw  = (const float*)d_in[8];
    const float* pww    = (const float*)d_in[9];
    const float* pwb    = (const float*)d_in[10];
    const float* pj1w   = (const float*)d_in[11];
    const float* pj1b   = (const float*)d_in[12];
    const float* pj2w   = (const float*)d_in[13];
    const float* pj2b   = (const float*)d_in[14];

    float* ws = (float*)d_ws;
    unsigned short* xh    = (unsigned short*)(ws + OFF_XH);
    unsigned short* tabB  = (unsigned short*)(ws + OFF_TABB);
    unsigned short* tabT  = (unsigned short*)(ws + OFF_TABT);
    unsigned short* mah   = (unsigned short*)(ws + OFF_MAH);
    unsigned short* pwwh  = (unsigned short*)(ws + OFF_PWWH);
    unsigned short* w1h   = (unsigned short*)(ws + OFF_W1H);
    float* cond   = ws + OFF_COND;
    float* dftp   = ws + OFF_DFTP;
    float* x0     = ws + OFF_X0;
    float* sbuf[2] = { ws + OFF_STATS, ws + OFF_STATS2 };
    float* out    = (float*)d_out;

    k_tab  <<<dim3(1024),  dim3(256), 0, stream>>>(tabB, tabT, pww, pwwh, pj1w, w1h);
    k_cond <<<dim3(128),   dim3(64),  0, stream>>>(instp, iw1, ib1, iw2, ib2, cond);
    k_liftc<<<dim3(128,4), dim3(256), 0, stream>>>(z, lift_w, lift_b, cond, x0);

    for (int l = 0; l < 4; ++l){
        float* sIn  = sbuf[l & 1];
        float* sOut = sbuf[(l + 1) & 1];
        if (l == 0)
            k_prep<2><<<dim3(128,8), dim3(256), 0, stream>>>(xh, sIn, tabB, x0, dftp);
        else
            k_prep<1><<<dim3(128,8), dim3(256), 0, stream>>>(xh, sIn, tabB, x0, dftp);
        k_mix<<<dim3(128,4), dim3(256), 0, stream>>>(dftp, specw, mah, sOut, l);
        if (l == 0)
            k_pass3<2><<<dim3(128,16), dim3(256), 0, stream>>>(xh, sIn, x0, tabT, pwwh, pwb, mah, xh, sOut, l);
        else
            k_pass3<1><<<dim3(128,16), dim3(256), 0, stream>>>(xh, sIn, x0, tabT, pwwh, pwb, mah, xh, sOut, l);
    }
    k_proj2<<<dim3(128,16), dim3(256), 0, stream>>>(xh, sbuf[0], w1h, pj1b, pj2w, pj2b, out);
}